// Round 5
// baseline (248.909 us; speedup 1.0000x reference)
//
#include <hip/hip_runtime.h>
#include <stdint.h>

typedef __attribute__((ext_vector_type(8))) short short8;
typedef __attribute__((ext_vector_type(4))) short s16x4;
typedef __attribute__((ext_vector_type(4))) float f32x4;

#define DEVI __device__ __forceinline__

#if __has_builtin(__builtin_amdgcn_mfma_f32_16x16x16_bf16)
#define MFMA16(a, b, c) __builtin_amdgcn_mfma_f32_16x16x16_bf16(a, b, c, 0, 0, 0)
#else
#define MFMA16(a, b, c) __builtin_amdgcn_mfma_f32_16x16x16bf16_1k(a, b, c, 0, 0, 0)
#endif

DEVI unsigned short f2bf(float f) {
  union { float f; uint32_t u; } v; v.f = f;
  return (unsigned short)((v.u + 0x7fffu + ((v.u >> 16) & 1u)) >> 16);
}

DEVI float bf2f(uint32_t hi16) {  // bits already in [31:16]
  union { uint32_t u; float f; } v; v.u = hi16;
  return v.f;
}

DEVI uint32_t pkbf(float a, float b) {  // fast RTN pack (positive values)
  union { float f; uint32_t u; } x, y; x.f = a; y.f = b;
  return ((x.u + 0x8000u) >> 16) | (((y.u + 0x8000u) >> 16) << 16);
}

DEVI void gload_lds16(const void* g, void* l) {
  __builtin_amdgcn_global_load_lds(
      (const __attribute__((address_space(1))) uint32_t*)g,
      (__attribute__((address_space(3))) uint32_t*)l, 16, 0, 0);
}

// ---------------- K0: positional encoding table T[256][32] + zero page (1KB) ----------------
__global__ void k_petab(float* __restrict__ T, float* __restrict__ zp) {
  int c = threadIdx.x;  // 256 threads
  zp[c] = 0.0f;         // 1KB zero page (im2col OOB target, offsets up to ~400B)
  int idx = ((c >= 128) ? c - 128 : c) >> 1;
  float freq = expf(-(float)idx * (logf(10000.0f) / 64.0f));
  for (int p = 0; p < 32; ++p) {
    float ang = (float)p * freq;
    T[c * 32 + p] = (c & 1) ? cosf(ang) : sinf(ang);
  }
}

// ---------------- K1: xpT = (x + pe) transposed to [b*1024+n][256], f32 + bf16 ----------------
__global__ __launch_bounds__(256) void k_xpt(const float* __restrict__ x,
                                             const float* __restrict__ T,
                                             unsigned short* __restrict__ xpt_bf,
                                             float* __restrict__ xpt_f) {
  __shared__ __align__(16) float tile[32][36];  // [n][c]
  const int b = blockIdx.z, c0 = blockIdx.x * 32, n0 = blockIdx.y * 32;
  const int t = threadIdx.x;
  {
    const int cl = t >> 3, ng = (t & 7) * 4;
    const int c = c0 + cl;
    float4 v = *(const float4*)(x + ((size_t)b * 256 + c) * 1024 + n0 + ng);
    float p0, p1, p2, p3;
    if (c < 128) {
      p0 = T[c * 32 + ng + 0]; p1 = T[c * 32 + ng + 1];
      p2 = T[c * 32 + ng + 2]; p3 = T[c * 32 + ng + 3];
    } else {
      p0 = p1 = p2 = p3 = T[c * 32 + (n0 >> 5)];
    }
    tile[ng + 0][cl] = v.x + p0;
    tile[ng + 1][cl] = v.y + p1;
    tile[ng + 2][cl] = v.z + p2;
    tile[ng + 3][cl] = v.w + p3;
  }
  __syncthreads();
  {
    const int nl = t >> 3, cg = (t & 7) * 4;
    float o0 = tile[nl][cg + 0], o1 = tile[nl][cg + 1];
    float o2 = tile[nl][cg + 2], o3 = tile[nl][cg + 3];
    size_t row = (size_t)b * 1024 + n0 + nl;
    *(float4*)(xpt_f + row * 256 + c0 + cg) = make_float4(o0, o1, o2, o3);
    uint32_t lo = (uint32_t)f2bf(o0) | ((uint32_t)f2bf(o1) << 16);
    uint32_t hi = (uint32_t)f2bf(o2) | ((uint32_t)f2bf(o3) << 16);
    *(uint2*)(xpt_bf + row * 256 + c0 + cg) = make_uint2(lo, hi);
  }
}

// ---------------- K2: pack conv weights -> Wpack[1536][2304] bf16 ----------------
__global__ void k_packw(const float* __restrict__ Wk, const float* __restrict__ Wq,
                        const float* __restrict__ Wv, unsigned short* __restrict__ Wpack) {
  int i = blockIdx.x * 256 + threadIdx.x;
  if (i >= 1536 * 2304) return;
  int o = i / 2304, kn = i % 2304;
  int ci = kn & 255, khw = kn >> 8;
  const float* src = (o < 512) ? Wk : ((o < 1024) ? Wq : Wv);
  int oo = o & 511;
  Wpack[i] = f2bf(src[((size_t)oo * 256 + ci) * 9 + khw]);
}

// ---------------- K3: misc packs ----------------
__global__ void k_packmisc(const float* __restrict__ bk, const float* __restrict__ bq,
                           const float* __restrict__ bv, const float* __restrict__ Wproj,
                           const float* __restrict__ W1, const float* __restrict__ W2,
                           float* __restrict__ bias_kqv, unsigned short* __restrict__ WprojP,
                           unsigned short* __restrict__ W1b, unsigned short* __restrict__ W2b) {
  int i = blockIdx.x * 256 + threadIdx.x;
  if (i < 1536)
    bias_kqv[i] = (i < 512) ? bk[i] : ((i < 1024) ? bq[i - 512] : bv[i - 1024]);
  if (i < 131072) {
    int j = i >> 9, f = i & 511;
    int h = f >> 6, c = f & 63;
    WprojP[i] = f2bf(Wproj[(size_t)j * 512 + c * 8 + h]);
  }
  if (i < 65536) {
    W1b[i] = f2bf(W1[i]);
    W2b[i] = f2bf(W2[i]);
  }
}

// ---------------- merged conv GEMM v2: C[8192][1536] = im2col(xpt) . Wpack^T ----------------
// Tile 128m x 192n, BK=64, 4 waves (2m x 2n, 64x96 each), double-buffered LDS (80KB),
// counted-vmcnt pipeline (stage next-step while computing current; vmcnt(10) not 0).
// khw-hoisted im2col addressing: tap offsets recomputed once per 4 K-steps.
// n<1024 -> kq_t[m][o]; n>=1024 -> v[b][o-1024][m] transposed store.
__global__ __launch_bounds__(256) void k_gemm_conv(const unsigned short* __restrict__ xpt,
                                                   const unsigned short* __restrict__ Wp,
                                                   unsigned short* __restrict__ kq_t,
                                                   unsigned short* __restrict__ vout,
                                                   const float* __restrict__ bias,
                                                   const char* __restrict__ zp) {
  __shared__ __align__(16) unsigned short As[2][128 * 64];
  __shared__ __align__(16) unsigned short Bs[2][192 * 64];
  const int tid = threadIdx.x, l = tid & 63, w = tid >> 6;
  const int wm = w >> 1, wn = w & 1, g = l >> 4, ln = l & 15;
  const int m0 = blockIdx.x * 128, n0 = blockIdx.y * 192;
  const int swz = (l & 7) ^ (l >> 3);

  // A-side (implicit im2col) per-seg bases: row fixed across K; only tap (dy,dx) changes.
  int rA[4];
  const char* pAbase[4];
  const char* pA[4];
#pragma unroll
  for (int j = 0; j < 4; ++j) {
    int r = m0 + (w * 4 + j) * 8 + (l >> 3);
    rA[j] = r;
    pAbase[j] = (const char*)xpt + ((size_t)r * 256 + swz * 8) * 2;
  }
  // B-side per-seg pointers, advance 128B per K-step, never reset.
  const char* pB[6];
#pragma unroll
  for (int j = 0; j < 6; ++j) {
    int r = n0 + (w * 6 + j) * 8 + (l >> 3);
    pB[j] = (const char*)Wp + ((size_t)r * 2304 + swz * 8) * 2;
  }

  f32x4 acc[4][6] = {};

  auto setA = [&](int khw) {
    int d3 = (khw * 11) >> 5;        // khw/3
    int dy = d3 - 1, dx = khw - d3 * 3 - 1;
    int off = (dy * 32 + dx) * 512;  // bytes
#pragma unroll
    for (int j = 0; j < 4; ++j) {
      int y = ((rA[j] >> 5) & 31) + dy;
      int x = (rA[j] & 31) + dx;
      pA[j] = (((unsigned)y < 32u) && ((unsigned)x < 32u)) ? (pAbase[j] + off) : zp;
    }
  };
  auto STAGE = [&](int buf) {
#pragma unroll
    for (int j = 0; j < 4; ++j) {
      gload_lds16(pA[j], (char*)As + buf * 16384 + (w * 4 + j) * 1024);
      pA[j] += 128;
    }
#pragma unroll
    for (int j = 0; j < 6; ++j) {
      gload_lds16(pB[j], (char*)Bs + buf * 24576 + (w * 6 + j) * 1024);
      pB[j] += 128;
    }
  };
  auto COMPUTE = [&](int buf) {
    const char* Ab2 = (const char*)As + buf * 16384;
    const char* Bb2 = (const char*)Bs + buf * 24576;
#pragma unroll
    for (int kk = 0; kk < 2; ++kk) {
      short8 af[4], bfr[6];
#pragma unroll
      for (int fm = 0; fm < 4; ++fm)
        af[fm] = *(const short8*)(Ab2 + (wm * 64 + fm * 16 + ln) * 128 +
                                  (((kk * 4 + g) ^ (ln & 7)) * 16));
#pragma unroll
      for (int fn = 0; fn < 6; ++fn)
        bfr[fn] = *(const short8*)(Bb2 + (wn * 96 + fn * 16 + ln) * 128 +
                                   (((kk * 4 + g) ^ (ln & 7)) * 16));
#pragma unroll
      for (int fm = 0; fm < 4; ++fm)
#pragma unroll
        for (int fn = 0; fn < 6; ++fn)
          acc[fm][fn] = __builtin_amdgcn_mfma_f32_16x16x32_bf16(af[fm], bfr[fn], acc[fm][fn], 0, 0, 0);
    }
  };

  setA(0);
  STAGE(0);  // prologue: buf0 <- step 0
  for (int it = 0; it < 18; ++it) {
    // even step 2it (buf 0): always stages step 2it+1 (same khw; (2it+1)&3 != 0)
    {
      STAGE(1);
      asm volatile("s_waitcnt vmcnt(10)" ::: "memory");
      __builtin_amdgcn_s_barrier();
      __builtin_amdgcn_sched_barrier(0);
      COMPUTE(0);
      asm volatile("s_waitcnt lgkmcnt(0)" ::: "memory");
      __builtin_amdgcn_s_barrier();
      __builtin_amdgcn_sched_barrier(0);
    }
    // odd step 2it+1 (buf 1): stages step 2it+2 (new khw when it odd)
    {
      if (2 * it + 1 < 35) {
        if (it & 1) setA((it + 1) >> 1);
        STAGE(0);
        asm volatile("s_waitcnt vmcnt(10)" ::: "memory");
      } else {
        asm volatile("s_waitcnt vmcnt(0)" ::: "memory");
      }
      __builtin_amdgcn_s_barrier();
      __builtin_amdgcn_sched_barrier(0);
      COMPUTE(1);
      asm volatile("s_waitcnt lgkmcnt(0)" ::: "memory");
      __builtin_amdgcn_s_barrier();
      __builtin_amdgcn_sched_barrier(0);
    }
  }

  // epilogue
#pragma unroll
  for (int fm = 0; fm < 4; ++fm)
#pragma unroll
    for (int fn = 0; fn < 6; ++fn) {
      int colg = n0 + wn * 96 + fn * 16 + ln;
      float bb = bias[colg];
      if (colg < 1024) {
#pragma unroll
        for (int r = 0; r < 4; ++r) {
          int row = m0 + wm * 64 + fm * 16 + g * 4 + r;
          kq_t[(size_t)row * 1024 + colg] = f2bf(acc[fm][fn][r] + bb);
        }
      } else {
        int c = colg - 1024;
        int bimg = m0 >> 10;
        int ml0 = (m0 & 1023) + wm * 64 + fm * 16 + g * 4;
#pragma unroll
        for (int r2 = 0; r2 < 2; ++r2) {
          uint32_t u = (uint32_t)f2bf(acc[fm][fn][2 * r2] + bb) |
                       ((uint32_t)f2bf(acc[fm][fn][2 * r2 + 1] + bb) << 16);
          *(uint32_t*)&vout[((size_t)bimg * 512 + c) * 1024 + ml0 + r2 * 2] = u;
        }
      }
    }
}

// ---------------- GEMM BN=64: C[M][N] = A[M][K].B[N][K]^T, tile 128x64, 4 waves ----------------
template <int EPI>
__global__ __launch_bounds__(256) void k_gemm64(const unsigned short* __restrict__ A,
                                                const unsigned short* __restrict__ B,
                                                void* __restrict__ Cout,
                                                const float* __restrict__ bias,
                                                const float* __restrict__ resid,
                                                int N, int K) {
  __shared__ __align__(16) unsigned short As[128 * 64];
  __shared__ __align__(16) unsigned short Bs[64 * 64];
  const int tid = threadIdx.x, l = tid & 63, w = tid >> 6;
  const int g = l >> 4, ln = l & 15;
  const int m0 = blockIdx.x * 128, n0 = blockIdx.y * 64;
  const int swz = (l & 7) ^ (l >> 3);
  f32x4 acc[2][4] = {};

  for (int kt = 0; kt < K; kt += 64) {
#pragma unroll
    for (int j = 0; j < 4; ++j) {
      int seg = w * 4 + j;
      int r8 = seg * 8 + (l >> 3);
      gload_lds16((const char*)A + ((size_t)(m0 + r8) * K + kt + swz * 8) * 2,
                  (char*)As + seg * 1024);
    }
#pragma unroll
    for (int j = 0; j < 2; ++j) {
      int seg = w * 2 + j;
      int r8 = seg * 8 + (l >> 3);
      gload_lds16((const char*)B + ((size_t)(n0 + r8) * K + kt + swz * 8) * 2,
                  (char*)Bs + seg * 1024);
    }
    __syncthreads();
#pragma unroll
    for (int kk = 0; kk < 2; ++kk) {
      short8 af[2], bfr[4];
#pragma unroll
      for (int fm = 0; fm < 2; ++fm)
        af[fm] = *(const short8*)((const char*)As + (w * 32 + fm * 16 + ln) * 128 +
                                  (((kk * 4 + g) ^ (ln & 7)) * 16));
#pragma unroll
      for (int fn = 0; fn < 4; ++fn)
        bfr[fn] = *(const short8*)((const char*)Bs + (fn * 16 + ln) * 128 +
                                   (((kk * 4 + g) ^ (ln & 7)) * 16));
#pragma unroll
      for (int fm = 0; fm < 2; ++fm)
#pragma unroll
        for (int fn = 0; fn < 4; ++fn)
          acc[fm][fn] = __builtin_amdgcn_mfma_f32_16x16x32_bf16(af[fm], bfr[fn], acc[fm][fn], 0, 0, 0);
    }
    __syncthreads();
  }

#pragma unroll
  for (int fm = 0; fm < 2; ++fm)
#pragma unroll
    for (int fn = 0; fn < 4; ++fn)
#pragma unroll
      for (int r = 0; r < 4; ++r) {
        int row = m0 + w * 32 + fm * 16 + g * 4 + r;
        int col = n0 + fn * 16 + ln;
        float v = acc[fm][fn][r] + bias[col];
        size_t cidx = (size_t)row * N + col;
        if (EPI == 2) {
          ((float*)Cout)[cidx] = v + resid[cidx];
        } else {
          v = (v > 0.f) ? v : 0.1f * v;
          ((unsigned short*)Cout)[cidx] = f2bf(v);
        }
      }
}

// ---------------- K5: fused attention v4 — all-heads-per-wave, in-register softmax ----------------
__global__ __launch_bounds__(256, 2) void k_attn(const unsigned short* __restrict__ kq_t,
                                                 const unsigned short* __restrict__ v,
                                                 unsigned short* __restrict__ part) {
  __shared__ __align__(16) unsigned short Qs[2][16][512];  // [buf][m][c'] XOR-swizzled chunks
  __shared__ __align__(16) unsigned short Vs[2][512][24];  // [buf][c][m(16)+pad8] 48B rows
  const int tid = threadIdx.x, l = tid & 63, w = tid >> 6;
  const int g = l >> 4, ln = l & 15;
  const int id = blockIdx.x;
  const int b = id & 7, ng = (id >> 3) & 15, ch = id >> 7;
  const int n0 = ng * 64 + w * 16;
  const int m_base = ch * 256;
  const size_t kqBase = (size_t)b << 20;
  const size_t vBase = (size_t)b * 512 * 1024;
  const float SC = 1.0f / 1024.0f;

  short8 ak[8][2];
#pragma unroll
  for (int h = 0; h < 8; ++h)
#pragma unroll
    for (int kk = 0; kk < 2; ++kk)
      ak[h][kk] = *(const short8*)&kq_t[kqBase + (size_t)(n0 + ln) * 1024 + h * 64 + kk * 32 + g * 8];

  f32x4 acc[8][4] = {};  // O[c][n]

  auto STAGE = [&](int buf, int m0s) {
#pragma unroll
    for (int i = 0; i < 4; ++i) {   // Q: 16 rows x 512 c (swizzled source)
      int mq = i * 4 + w;
      gload_lds16(kq_t + kqBase + (size_t)(m0s + mq) * 1024 + 512 + ((l ^ (mq & 7)) * 8),
                  (char*)Qs + buf * 16384 + i * 4096 + w * 1024);
    }
#pragma unroll
    for (int i = 0; i < 6; ++i) {   // V: 512 rows x 16 m into 48B rows
      int q16 = i * 256 + w * 64 + l;
      int c = (q16 * 43691) >> 17;  // q16 / 3
      int m8 = (q16 - c * 3) & 1;
      gload_lds16(v + vBase + (size_t)c * 1024 + m0s + m8 * 8,
                  (char*)Vs + buf * 24576 + i * 4096 + w * 1024);
    }
  };

  STAGE(0, m_base);
  __syncthreads();

  for (int s = 0; s < 16; ++s) {
    const int buf = s & 1;
    if (s < 15) STAGE(buf ^ 1, m_base + (s + 1) * 16);

    f32x4 sv[8];
#pragma unroll
    for (int h = 0; h < 8; ++h) sv[h] = f32x4{0.f, 0.f, 0.f, 0.f};
#pragma unroll
    for (int kk = 0; kk < 2; ++kk)
#pragma unroll
      for (int h = 0; h < 8; ++h) {
        short8 qa = *(const short8*)((const char*)Qs + buf * 16384 + ln * 1024 +
                                     (((h * 8 + kk * 4 + g) ^ (ln & 7)) * 16));
        sv[h] = __builtin_amdgcn_mfma_f32_16x16x32_bf16(qa, ak[h][kk], sv[h], 0, 0, 0);
      }

    float s0 = 0.f, s1 = 0.f, s2 = 0.f, s3 = 0.f;
#pragma unroll
    for (int h = 0; h < 8; ++h) {
      sv[h][0] = __expf(sv[h][0] * SC); s0 += sv[h][0];
      sv[h][1] = __expf(sv[h][1] * SC); s1 += sv[h][1];
      sv[h][2] = __expf(sv[h][2] * SC); s2 += sv[h][2];
      sv[h][3] = __expf(sv[h][3] * SC); s3 += sv[h][3];
    }
    float i0 = 1.0f / s0, i1 = 1.0f / s1, i2 = 1.0f / s2, i3 = 1.0f / s3;

#pragma unroll
    for (int h = 0; h < 8; ++h) {
      union { uint32_t u[2]; s16x4 v4; } pc;
      pc.u[0] = pkbf(sv[h][0] * i0, sv[h][1] * i1);
      pc.u[1] = pkbf(sv[h][2] * i2, sv[h][3] * i3);
#pragma unroll
      for (int cf = 0; cf < 4; ++cf) {
        s16x4 vf = *(const s16x4*)((const char*)Vs + buf * 24576 +
                                   (h * 64 + cf * 16 + ln) * 48 + g * 8);
        acc[h][cf] = MFMA16(vf, pc.v4, acc[h][cf]);
      }
    }
    __syncthreads();
  }

  const size_t outBase = (size_t)ch * 8192 * 512 + ((size_t)b * 1024 + n0 + ln) * 512;
#pragma unroll
  for (int h = 0; h < 8; ++h)
#pragma unroll
    for (int cf = 0; cf < 4; ++cf)
#pragma unroll
      for (int r2 = 0; r2 < 2; ++r2) {
        int c = h * 64 + cf * 16 + g * 4 + r2 * 2;
        uint32_t u = (uint32_t)f2bf(acc[h][cf][2 * r2]) |
                     ((uint32_t)f2bf(acc[h][cf][2 * r2 + 1]) << 16);
        *(uint32_t*)&part[outBase + c] = u;
      }
}

// ---------------- K5b: reduce the four m-chunk partials (bf16) -> att bf16 ----------------
__global__ __launch_bounds__(256) void k_reduce4(const unsigned short* __restrict__ part,
                                                 unsigned short* __restrict__ att) {
  size_t i8 = ((size_t)blockIdx.x * 256 + threadIdx.x) * 8;
  float o[8] = {0.f, 0.f, 0.f, 0.f, 0.f, 0.f, 0.f, 0.f};
#pragma unroll
  for (int p = 0; p < 4; ++p) {
    uint4 u = *(const uint4*)&part[(size_t)p * 8192 * 512 + i8];
    uint32_t a[4] = {u.x, u.y, u.z, u.w};
#pragma unroll
    for (int j = 0; j < 4; ++j) {
      o[2 * j] += bf2f(a[j] << 16);
      o[2 * j + 1] += bf2f(a[j] & 0xffff0000u);
    }
  }
  uint32_t r0 = (uint32_t)f2bf(o[0]) | ((uint32_t)f2bf(o[1]) << 16);
  uint32_t r1 = (uint32_t)f2bf(o[2]) | ((uint32_t)f2bf(o[3]) << 16);
  uint32_t r2 = (uint32_t)f2bf(o[4]) | ((uint32_t)f2bf(o[5]) << 16);
  uint32_t r3 = (uint32_t)f2bf(o[6]) | ((uint32_t)f2bf(o[7]) << 16);
  *(uint4*)&att[i8] = make_uint4(r0, r1, r2, r3);
}

// ---------------- K6: LayerNorm over rows of [8192][256] ----------------
template <int MODE>
__global__ __launch_bounds__(256) void k_ln(const float* __restrict__ in,
                                            const float* __restrict__ g,
                                            const float* __restrict__ bta,
                                            float* __restrict__ out_f,
                                            unsigned short* __restrict__ out_b) {
  const int l = threadIdx.x & 63, w = threadIdx.x >> 6;
  const size_t row = (size_t)blockIdx.x * 4 + w;
  float4 xv = *(const float4*)(in + row * 256 + l * 4);
  float s = xv.x + xv.y + xv.z + xv.w;
  float q = xv.x * xv.x + xv.y * xv.y + xv.z * xv.z + xv.w * xv.w;
#pragma unroll
  for (int o = 1; o < 64; o <<= 1) {
    s += __shfl_xor(s, o, 64);
    q += __shfl_xor(q, o, 64);
  }
  float mu = s * (1.0f / 256.0f);
  float var = q * (1.0f / 256.0f) - mu * mu;
  float rstd = rsqrtf(var + 1e-5f);
  float4 gv = *(const float4*)(g + l * 4);
  float4 bv = *(const float4*)(bta + l * 4);
  float o0 = (xv.x - mu) * rstd * gv.x + bv.x;
  float o1 = (xv.y - mu) * rstd * gv.y + bv.y;
  float o2 = (xv.z - mu) * rstd * gv.z + bv.z;
  float o3 = (xv.w - mu) * rstd * gv.w + bv.w;
  *(float4*)(out_f + row * 256 + l * 4) = make_float4(o0, o1, o2, o3);
  if (MODE == 0) {
    uint32_t lo = (uint32_t)f2bf(o0) | ((uint32_t)f2bf(o1) << 16);
    uint32_t hi = (uint32_t)f2bf(o2) | ((uint32_t)f2bf(o3) << 16);
    *(uint2*)(out_b + row * 256 + l * 4) = make_uint2(lo, hi);
  }
}

// ---------------- K7: transpose [b*1024+n][256] -> d_out [b][256][1024] ----------------
__global__ __launch_bounds__(256) void k_transout(const float* __restrict__ in,
                                                  float* __restrict__ out) {
  __shared__ __align__(16) float tile[32][36];
  const int b = blockIdx.z, c0 = blockIdx.x * 32, n0 = blockIdx.y * 32;
  const int t = threadIdx.x;
  {
    const int nl = t >> 3, cg = (t & 7) * 4;
    float4 v = *(const float4*)(in + ((size_t)b * 1024 + n0 + nl) * 256 + c0 + cg);
    tile[cg + 0][nl] = v.x;
    tile[cg + 1][nl] = v.y;
    tile[cg + 2][nl] = v.z;
    tile[cg + 3][nl] = v.w;
  }
  __syncthreads();
  {
    const int cl = t >> 3, ng = (t & 7) * 4;
    float4 o = make_float4(tile[cl][ng + 0], tile[cl][ng + 1], tile[cl][ng + 2], tile[cl][ng + 3]);
    *(float4*)(out + ((size_t)b * 256 + c0 + cl) * 1024 + n0 + ng) = o;
  }
}

// ---------------- host launcher ----------------
extern "C" void kernel_launch(void* const* d_in, const int* in_sizes, int n_in,
                              void* d_out, int out_size, void* d_ws, size_t ws_size,
                              hipStream_t stream) {
  const float* x     = (const float*)d_in[0];
  const float* Wk    = (const float*)d_in[1];
  const float* bk    = (const float*)d_in[2];
  const float* Wq    = (const float*)d_in[3];
  const float* bq    = (const float*)d_in[4];
  const float* Wv    = (const float*)d_in[5];
  const float* bv    = (const float*)d_in[6];
  const float* Wproj = (const float*)d_in[7];
  const float* bproj = (const float*)d_in[8];
  const float* ln_g  = (const float*)d_in[9];
  const float* ln_b  = (const float*)d_in[10];
  const float* W1    = (const float*)d_in[11];
  const float* b1    = (const float*)d_in[12];
  const float* W2    = (const float*)d_in[13];
  const float* b2    = (const float*)d_in[14];

  char* ws = (char*)d_ws;
  constexpr size_t OFF_XPTB  = 0;                                    // bf16 [8192][256]
  constexpr size_t OFF_XPTF  = OFF_XPTB  + (size_t)8192 * 256 * 2;   // f32  [8192][256]
  constexpr size_t OFF_WPACK = OFF_XPTF  + (size_t)8192 * 256 * 4;   // bf16 [1536][2304]
  constexpr size_t OFF_BIAS  = OFF_WPACK + (size_t)1536 * 2304 * 2;  // f32  [1536]
  constexpr size_t OFF_WPROJ = OFF_BIAS  + (size_t)1536 * 4;         // bf16 [256][512]
  constexpr size_t OFF_W1B   = OFF_WPROJ + (size_t)256 * 512 * 2;    // bf16 [256][256]
  constexpr size_t OFF_W2B   = OFF_W1B   + (size_t)256 * 256 * 2;    // bf16 [256][256]
  constexpr size_t OFF_PET   = OFF_W2B   + (size_t)256 * 256 * 2;    // f32  [256][32]
  constexpr size_t OFF_ZERO  = OFF_PET   + (size_t)256 * 32 * 4;     // f32  [256] zeros (1KB)
  constexpr size_t OFF_KQT   = OFF_ZERO  + 1024;                     // bf16 [8192][1024]
  constexpr size_t OFF_V     = OFF_KQT   + (size_t)8192 * 1024 * 2;  // bf16 [8][512][1024]
  constexpr size_t OFF_ATT   = OFF_V     + (size_t)8 * 512 * 1024 * 2; // bf16 [8192][512]
  constexpr size_t OFF_X     = OFF_ATT   + (size_t)8192 * 512 * 2;
  // region X: attn partials (4 x bf16 [8192][512] = 33.5MB), then FFN-phase buffers
  constexpr size_t OFF_PART  = OFF_X;
  constexpr size_t OFF_Y1    = OFF_X;                                // f32 [8192][256]
  constexpr size_t OFF_ADDNF = OFF_Y1    + (size_t)8192 * 256 * 4;   // f32
  constexpr size_t OFF_ADDNB = OFF_ADDNF + (size_t)8192 * 256 * 4;   // bf16
  constexpr size_t OFF_H1    = OFF_ADDNB + (size_t)8192 * 256 * 2;   // bf16
  constexpr size_t OFF_H2    = OFF_H1    + (size_t)8192 * 256 * 2;   // f32

  (void)in_sizes; (void)n_in; (void)out_size; (void)ws_size;

  const char* zp = (const char*)(ws + OFF_ZERO);

  k_petab<<<1, 256, 0, stream>>>((float*)(ws + OFF_PET), (float*)(ws + OFF_ZERO));
  k_xpt<<<dim3(8, 32, 8), 256, 0, stream>>>(x, (const float*)(ws + OFF_PET),
                                            (unsigned short*)(ws + OFF_XPTB),
                                            (float*)(ws + OFF_XPTF));
  k_packw<<<(1536 * 2304 + 255) / 256, 256, 0, stream>>>(Wk, Wq, Wv,
                                                         (unsigned short*)(ws + OFF_WPACK));
  k_packmisc<<<512, 256, 0, stream>>>(bk, bq, bv, Wproj, W1, W2,
                                      (float*)(ws + OFF_BIAS),
                                      (unsigned short*)(ws + OFF_WPROJ),
                                      (unsigned short*)(ws + OFF_W1B),
                                      (unsigned short*)(ws + OFF_W2B));
  // merged conv K+Q+V: C[8192][1536] (tile 128x192, 512 blocks = 2/CU balanced)
  k_gemm_conv<<<dim3(64, 8), 256, 0, stream>>>(
      (const unsigned short*)(ws + OFF_XPTB), (const unsigned short*)(ws + OFF_WPACK),
      (unsigned short*)(ws + OFF_KQT), (unsigned short*)(ws + OFF_V),
      (const float*)(ws + OFF_BIAS), zp);
  // fused attention (split-m over 4 chunks) + reduce
  k_attn<<<dim3(512), 256, 0, stream>>>((const unsigned short*)(ws + OFF_KQT),
                                        (const unsigned short*)(ws + OFF_V),
                                        (unsigned short*)(ws + OFF_PART));
  k_reduce4<<<dim3(2048), 256, 0, stream>>>((const unsigned short*)(ws + OFF_PART),
                                            (unsigned short*)(ws + OFF_ATT));
  // attproj + bias + residual(x+pe): y1 f32   (M=8192, N=256, K=512)
  k_gemm64<2><<<dim3(64, 4), 256, 0, stream>>>(
      (const unsigned short*)(ws + OFF_ATT), (const unsigned short*)(ws + OFF_WPROJ),
      ws + OFF_Y1, bproj, (const float*)(ws + OFF_XPTF), 256, 512);
  k_ln<0><<<2048, 256, 0, stream>>>((const float*)(ws + OFF_Y1), ln_g, ln_b,
                                    (float*)(ws + OFF_ADDNF), (unsigned short*)(ws + OFF_ADDNB));
  // FFN1 + LeakyReLU
  k_gemm64<3><<<dim3(64, 4), 256, 0, stream>>>(
      (const unsigned short*)(ws + OFF_ADDNB), (const unsigned short*)(ws + OFF_W1B),
      ws + OFF_H1, b1, nullptr, 256, 256);
  // FFN2 + bias + residual(addnormed)
  k_gemm64<2><<<dim3(64, 4), 256, 0, stream>>>(
      (const unsigned short*)(ws + OFF_H1), (const unsigned short*)(ws + OFF_W2B),
      ws + OFF_H2, b2, (const float*)(ws + OFF_ADDNF), 256, 256);
  k_ln<1><<<2048, 256, 0, stream>>>((const float*)(ws + OFF_H2), ln_g, ln_b,
                                    (float*)(ws + OFF_Y1), nullptr);
  k_transout<<<dim3(8, 32, 8), 256, 0, stream>>>((const float*)(ws + OFF_Y1), (float*)d_out);
}

// Round 6
// 226.351 us; speedup vs baseline: 1.0997x; 1.0997x over previous
//
#include <hip/hip_runtime.h>
#include <stdint.h>

typedef __attribute__((ext_vector_type(8))) short short8;
typedef __attribute__((ext_vector_type(4))) short s16x4;
typedef __attribute__((ext_vector_type(4))) float f32x4;

#define DEVI __device__ __forceinline__

#if __has_builtin(__builtin_amdgcn_mfma_f32_16x16x16_bf16)
#define MFMA16(a, b, c) __builtin_amdgcn_mfma_f32_16x16x16_bf16(a, b, c, 0, 0, 0)
#else
#define MFMA16(a, b, c) __builtin_amdgcn_mfma_f32_16x16x16bf16_1k(a, b, c, 0, 0, 0)
#endif

DEVI unsigned short f2bf(float f) {
  union { float f; uint32_t u; } v; v.f = f;
  return (unsigned short)((v.u + 0x7fffu + ((v.u >> 16) & 1u)) >> 16);
}

DEVI float bf2f(uint32_t hi16) {
  union { uint32_t u; float f; } v; v.u = hi16;
  return v.f;
}

DEVI uint32_t pkbf(float a, float b) {  // fast RTN pack (positive values)
  union { float f; uint32_t u; } x, y; x.f = a; y.f = b;
  return ((x.u + 0x8000u) >> 16) | (((y.u + 0x8000u) >> 16) << 16);
}

DEVI void gload_lds16(const void* g, void* l) {
  __builtin_amdgcn_global_load_lds(
      (const __attribute__((address_space(1))) uint32_t*)g,
      (__attribute__((address_space(3))) uint32_t*)l, 16, 0, 0);
}

// ---------------- K0: positional encoding table T[256][32] + zero page (1KB) ----------------
__global__ void k_petab(float* __restrict__ T, float* __restrict__ zp) {
  int c = threadIdx.x;
  zp[c] = 0.0f;
  int idx = ((c >= 128) ? c - 128 : c) >> 1;
  float freq = expf(-(float)idx * (logf(10000.0f) / 64.0f));
  for (int p = 0; p < 32; ++p) {
    float ang = (float)p * freq;
    T[c * 32 + p] = (c & 1) ? cosf(ang) : sinf(ang);
  }
}

// ---------------- K1: xpT = (x + pe) transposed to [b*1024+n][256], f32 + bf16 ----------------
__global__ __launch_bounds__(256) void k_xpt(const float* __restrict__ x,
                                             const float* __restrict__ T,
                                             unsigned short* __restrict__ xpt_bf,
                                             float* __restrict__ xpt_f) {
  __shared__ __align__(16) float tile[32][36];
  const int b = blockIdx.z, c0 = blockIdx.x * 32, n0 = blockIdx.y * 32;
  const int t = threadIdx.x;
  {
    const int cl = t >> 3, ng = (t & 7) * 4;
    const int c = c0 + cl;
    float4 v = *(const float4*)(x + ((size_t)b * 256 + c) * 1024 + n0 + ng);
    float p0, p1, p2, p3;
    if (c < 128) {
      p0 = T[c * 32 + ng + 0]; p1 = T[c * 32 + ng + 1];
      p2 = T[c * 32 + ng + 2]; p3 = T[c * 32 + ng + 3];
    } else {
      p0 = p1 = p2 = p3 = T[c * 32 + (n0 >> 5)];
    }
    tile[ng + 0][cl] = v.x + p0;
    tile[ng + 1][cl] = v.y + p1;
    tile[ng + 2][cl] = v.z + p2;
    tile[ng + 3][cl] = v.w + p3;
  }
  __syncthreads();
  {
    const int nl = t >> 3, cg = (t & 7) * 4;
    float o0 = tile[nl][cg + 0], o1 = tile[nl][cg + 1];
    float o2 = tile[nl][cg + 2], o3 = tile[nl][cg + 3];
    size_t row = (size_t)b * 1024 + n0 + nl;
    *(float4*)(xpt_f + row * 256 + c0 + cg) = make_float4(o0, o1, o2, o3);
    uint32_t lo = (uint32_t)f2bf(o0) | ((uint32_t)f2bf(o1) << 16);
    uint32_t hi = (uint32_t)f2bf(o2) | ((uint32_t)f2bf(o3) << 16);
    *(uint2*)(xpt_bf + row * 256 + c0 + cg) = make_uint2(lo, hi);
  }
}

// ---------------- K2: pack conv weights -> Wpack[1536][2304] bf16 ----------------
__global__ void k_packw(const float* __restrict__ Wk, const float* __restrict__ Wq,
                        const float* __restrict__ Wv, unsigned short* __restrict__ Wpack) {
  int i = blockIdx.x * 256 + threadIdx.x;
  if (i >= 1536 * 2304) return;
  int o = i / 2304, kn = i % 2304;
  int ci = kn & 255, khw = kn >> 8;
  const float* src = (o < 512) ? Wk : ((o < 1024) ? Wq : Wv);
  int oo = o & 511;
  Wpack[i] = f2bf(src[((size_t)oo * 256 + ci) * 9 + khw]);
}

// ---------------- K3: misc packs ----------------
__global__ void k_packmisc(const float* __restrict__ bk, const float* __restrict__ bq,
                           const float* __restrict__ bv, const float* __restrict__ Wproj,
                           const float* __restrict__ W1, const float* __restrict__ W2,
                           float* __restrict__ bias_kqv, unsigned short* __restrict__ WprojP,
                           unsigned short* __restrict__ W1b, unsigned short* __restrict__ W2b) {
  int i = blockIdx.x * 256 + threadIdx.x;
  if (i < 1536)
    bias_kqv[i] = (i < 512) ? bk[i] : ((i < 1024) ? bq[i - 512] : bv[i - 1024]);
  if (i < 131072) {
    int j = i >> 9, f = i & 511;
    int h = f >> 6, c = f & 63;
    WprojP[i] = f2bf(Wproj[(size_t)j * 512 + c * 8 + h]);
  }
  if (i < 65536) {
    W1b[i] = f2bf(W1[i]);
    W2b[i] = f2bf(W2[i]);
  }
}

// ---------------- merged conv GEMM v3: kqv[8192][1536] = im2col(xpt).Wpack^T ----------------
// Tile 128x128, 4 waves (2x2), BK=64, double-buffered 64KB LDS, counted vmcnt(8).
__global__ __launch_bounds__(256, 2) void k_gemm_conv(const unsigned short* __restrict__ xpt,
                                                      const unsigned short* __restrict__ Wp,
                                                      unsigned short* __restrict__ kqv,
                                                      const float* __restrict__ bias,
                                                      const char* __restrict__ zp) {
  __shared__ __align__(16) unsigned short As[2][128 * 64];
  __shared__ __align__(16) unsigned short Bs[2][128 * 64];
  const int tid = threadIdx.x, l = tid & 63, w = tid >> 6;
  const int wm = w >> 1, wn = w & 1, g = l >> 4, ln = l & 15;
  const int m0 = blockIdx.x * 128, n0 = blockIdx.y * 128;
  const int swz = (l & 7) ^ (l >> 3);

  int rA[4];
  const char* pAbase[4];
  const char* pA[4];
#pragma unroll
  for (int j = 0; j < 4; ++j) {
    int r = m0 + (w * 4 + j) * 8 + (l >> 3);
    rA[j] = r;
    pAbase[j] = (const char*)xpt + ((size_t)r * 256 + swz * 8) * 2;
  }
  const char* pB[4];
#pragma unroll
  for (int j = 0; j < 4; ++j) {
    int r = n0 + (w * 4 + j) * 8 + (l >> 3);
    pB[j] = (const char*)Wp + ((size_t)r * 2304 + swz * 8) * 2;
  }

  f32x4 acc[4][4] = {};

  auto setA = [&](int khw) {
    int d3 = (khw * 11) >> 5;  // khw/3
    int dy = d3 - 1, dx = khw - d3 * 3 - 1;
    int off = (dy * 32 + dx) * 512;
#pragma unroll
    for (int j = 0; j < 4; ++j) {
      int y = ((rA[j] >> 5) & 31) + dy;
      int x = (rA[j] & 31) + dx;
      pA[j] = (((unsigned)y < 32u) && ((unsigned)x < 32u)) ? (pAbase[j] + off) : zp;
    }
  };
  auto STAGE = [&](int buf) {
#pragma unroll
    for (int j = 0; j < 4; ++j) {
      gload_lds16(pA[j], (char*)As + buf * 16384 + (w * 4 + j) * 1024);
      pA[j] += 128;
    }
#pragma unroll
    for (int j = 0; j < 4; ++j) {
      gload_lds16(pB[j], (char*)Bs + buf * 16384 + (w * 4 + j) * 1024);
      pB[j] += 128;
    }
  };
  auto COMPUTE = [&](int buf) {
    const char* Ab2 = (const char*)As + buf * 16384;
    const char* Bb2 = (const char*)Bs + buf * 16384;
#pragma unroll
    for (int kk = 0; kk < 2; ++kk) {
      short8 af[4], bfr[4];
#pragma unroll
      for (int fm = 0; fm < 4; ++fm)
        af[fm] = *(const short8*)(Ab2 + (wm * 64 + fm * 16 + ln) * 128 +
                                  (((kk * 4 + g) ^ (ln & 7)) * 16));
#pragma unroll
      for (int fn = 0; fn < 4; ++fn)
        bfr[fn] = *(const short8*)(Bb2 + (wn * 64 + fn * 16 + ln) * 128 +
                                   (((kk * 4 + g) ^ (ln & 7)) * 16));
#pragma unroll
      for (int fm = 0; fm < 4; ++fm)
#pragma unroll
        for (int fn = 0; fn < 4; ++fn)
          acc[fm][fn] = __builtin_amdgcn_mfma_f32_16x16x32_bf16(af[fm], bfr[fn], acc[fm][fn], 0, 0, 0);
    }
  };

  setA(0);
  STAGE(0);
#pragma unroll
  for (int s = 0; s < 36; ++s) {
    const int buf = s & 1;
    if (s < 35) {
      if (((s + 1) & 3) == 0) setA((s + 1) >> 2);
      STAGE(buf ^ 1);
      asm volatile("s_waitcnt vmcnt(8)" ::: "memory");
    } else {
      asm volatile("s_waitcnt vmcnt(0)" ::: "memory");
    }
    __builtin_amdgcn_s_barrier();
    __builtin_amdgcn_sched_barrier(0);
    COMPUTE(buf);
    asm volatile("s_waitcnt lgkmcnt(0)" ::: "memory");
    __builtin_amdgcn_s_barrier();
    __builtin_amdgcn_sched_barrier(0);
  }

#pragma unroll
  for (int fm = 0; fm < 4; ++fm)
#pragma unroll
    for (int fn = 0; fn < 4; ++fn) {
      int col = n0 + wn * 64 + fn * 16 + ln;
      float bb = bias[col];
#pragma unroll
      for (int r = 0; r < 4; ++r) {
        int row = m0 + wm * 64 + fm * 16 + g * 4 + r;
        kqv[(size_t)row * 1536 + col] = f2bf(acc[fm][fn][r] + bb);
      }
    }
}

// ---------------- GEMM BN=64: C[M][N] = A[M][K].B[N][K]^T, tile 128x64, 4 waves ----------------
template <int EPI>
__global__ __launch_bounds__(256) void k_gemm64(const unsigned short* __restrict__ A,
                                                const unsigned short* __restrict__ B,
                                                void* __restrict__ Cout,
                                                const float* __restrict__ bias,
                                                const float* __restrict__ resid,
                                                int N, int K) {
  __shared__ __align__(16) unsigned short As[128 * 64];
  __shared__ __align__(16) unsigned short Bs[64 * 64];
  const int tid = threadIdx.x, l = tid & 63, w = tid >> 6;
  const int g = l >> 4, ln = l & 15;
  const int m0 = blockIdx.x * 128, n0 = blockIdx.y * 64;
  const int swz = (l & 7) ^ (l >> 3);
  f32x4 acc[2][4] = {};

  for (int kt = 0; kt < K; kt += 64) {
#pragma unroll
    for (int j = 0; j < 4; ++j) {
      int seg = w * 4 + j;
      int r8 = seg * 8 + (l >> 3);
      gload_lds16((const char*)A + ((size_t)(m0 + r8) * K + kt + swz * 8) * 2,
                  (char*)As + seg * 1024);
    }
#pragma unroll
    for (int j = 0; j < 2; ++j) {
      int seg = w * 2 + j;
      int r8 = seg * 8 + (l >> 3);
      gload_lds16((const char*)B + ((size_t)(n0 + r8) * K + kt + swz * 8) * 2,
                  (char*)Bs + seg * 1024);
    }
    __syncthreads();
#pragma unroll
    for (int kk = 0; kk < 2; ++kk) {
      short8 af[2], bfr[4];
#pragma unroll
      for (int fm = 0; fm < 2; ++fm)
        af[fm] = *(const short8*)((const char*)As + (w * 32 + fm * 16 + ln) * 128 +
                                  (((kk * 4 + g) ^ (ln & 7)) * 16));
#pragma unroll
      for (int fn = 0; fn < 4; ++fn)
        bfr[fn] = *(const short8*)((const char*)Bs + (fn * 16 + ln) * 128 +
                                   (((kk * 4 + g) ^ (ln & 7)) * 16));
#pragma unroll
      for (int fm = 0; fm < 2; ++fm)
#pragma unroll
        for (int fn = 0; fn < 4; ++fn)
          acc[fm][fn] = __builtin_amdgcn_mfma_f32_16x16x32_bf16(af[fm], bfr[fn], acc[fm][fn], 0, 0, 0);
    }
    __syncthreads();
  }

#pragma unroll
  for (int fm = 0; fm < 2; ++fm)
#pragma unroll
    for (int fn = 0; fn < 4; ++fn)
#pragma unroll
      for (int r = 0; r < 4; ++r) {
        int row = m0 + w * 32 + fm * 16 + g * 4 + r;
        int col = n0 + fn * 16 + ln;
        float v = acc[fm][fn][r] + bias[col];
        size_t cidx = (size_t)row * N + col;
        if (EPI == 2) {
          ((float*)Cout)[cidx] = v + resid[cidx];
        } else {
          v = (v > 0.f) ? v : 0.1f * v;
          ((unsigned short*)Cout)[cidx] = f2bf(v);
        }
      }
}

// ---------------- K5: fused attention v5 ----------------
// All-heads-per-wave in-register softmax (v4) + coalesced V staging into
// [cb][16m][16c] subtiles (source-swizzled global_load_lds) + ds_read_b64_tr_b16
// for PV A-fragments + counted-vmcnt double-buffer (no vmcnt(0) drain in loop).
// 512 blocks: id = b(&7, XCD-pinned) + 8*ngroup(16) + 128*chunk(4); 16 steps x 16m.
__global__ __launch_bounds__(256, 2) void k_attn(const unsigned short* __restrict__ kqv,
                                                 unsigned short* __restrict__ part) {
  __shared__ __align__(16) unsigned short Qs[2][16][512];   // [buf][m][c'] XOR-swizzled chunks
  __shared__ __align__(16) unsigned short Vs[2][32][16][16];// [buf][cb][m][c] tr-read subtiles
  const int tid = threadIdx.x, l = tid & 63, w = tid >> 6;
  const int g = l >> 4, ln = l & 15;
  const int id = blockIdx.x;
  const int b = id & 7, ng = (id >> 3) & 15, ch = id >> 7;
  const int n0 = ng * 64 + w * 16;
  const int m_base = ch * 256;
  const size_t rowBase = (size_t)b * 1024;
  const float SC = 1.0f / 1024.0f;

  // K fragments (B operand), resident: cols K 0..511 of kqv rows n
  short8 ak[8][2];
#pragma unroll
  for (int h = 0; h < 8; ++h)
#pragma unroll
    for (int kk = 0; kk < 2; ++kk)
      ak[h][kk] = *(const short8*)&kqv[(rowBase + n0 + ln) * 1536 + h * 64 + kk * 32 + g * 8];

  f32x4 acc[8][4] = {};  // O[c][n]

  auto STAGE = [&](int buf, int m0s) {
#pragma unroll
    for (int i = 0; i < 4; ++i) {  // Q: 16 rows x 512c, row-coalesced, chunk-XOR source swizzle
      int mq = i * 4 + w;
      gload_lds16(kqv + (rowBase + m0s + mq) * 1536 + 512 + ((l ^ (mq & 7)) * 8),
                  (char*)Qs + buf * 16384 + mq * 1024);
    }
#pragma unroll
    for (int i = 0; i < 4; ++i) {  // V: 16m x 512c into [cb][m][c] subtiles, linear dest
      int vv = w * 4 + i;
      int cb = vv * 2 + (l >> 5);
      gload_lds16(kqv + (rowBase + m0s + ((l >> 1) & 15)) * 1536 + 1024 + cb * 16 + (l & 1) * 8,
                  (char*)Vs + buf * 16384 + vv * 1024);
    }
  };

  STAGE(0, m_base);
  asm volatile("s_waitcnt vmcnt(0)" ::: "memory");
  __builtin_amdgcn_s_barrier();

  const uint32_t vsBase = (uint32_t)(uintptr_t)&Vs[0][0][0][0];

  for (int s = 0; s < 16; ++s) {
    const int buf = s & 1;
    if (s < 15) {
      STAGE(buf ^ 1, m_base + (s + 1) * 16);
      asm volatile("s_waitcnt vmcnt(8)" ::: "memory");
    } else {
      asm volatile("s_waitcnt vmcnt(0)" ::: "memory");
    }
    __builtin_amdgcn_s_barrier();
    __builtin_amdgcn_sched_barrier(0);

    // --- QK^T: S[m][n] per head, in registers ---
    f32x4 sv[8];
#pragma unroll
    for (int h = 0; h < 8; ++h) sv[h] = f32x4{0.f, 0.f, 0.f, 0.f};
#pragma unroll
    for (int kk = 0; kk < 2; ++kk)
#pragma unroll
      for (int h = 0; h < 8; ++h) {
        short8 qa = *(const short8*)((const char*)Qs + buf * 16384 + ln * 1024 +
                                     (((h * 8 + kk * 4 + g) ^ (ln & 7)) * 16));
        sv[h] = __builtin_amdgcn_mfma_f32_16x16x32_bf16(qa, ak[h][kk], sv[h], 0, 0, 0);
      }

    // --- softmax over heads, in-register (no max: |S/1024| << 1) ---
    float s0 = 0.f, s1 = 0.f, s2 = 0.f, s3 = 0.f;
#pragma unroll
    for (int h = 0; h < 8; ++h) {
      sv[h][0] = __expf(sv[h][0] * SC); s0 += sv[h][0];
      sv[h][1] = __expf(sv[h][1] * SC); s1 += sv[h][1];
      sv[h][2] = __expf(sv[h][2] * SC); s2 += sv[h][2];
      sv[h][3] = __expf(sv[h][3] * SC); s3 += sv[h][3];
    }
    float i0 = 1.0f / s0, i1 = 1.0f / s1, i2 = 1.0f / s2, i3 = 1.0f / s3;

    // --- PV: A = V^T frags via hardware transpose read; B = P from registers ---
    const uint32_t vb = vsBase + buf * 16384 + l * 8;
#pragma unroll
    for (int h = 0; h < 8; ++h) {
      s16x4 vf0, vf1, vf2, vf3;
      uint32_t ah = vb + h * 2048;
      asm volatile("ds_read_b64_tr_b16 %0, %1" : "=v"(vf0) : "v"(ah));
      asm volatile("ds_read_b64_tr_b16 %0, %1 offset:512" : "=v"(vf1) : "v"(ah));
      asm volatile("ds_read_b64_tr_b16 %0, %1 offset:1024" : "=v"(vf2) : "v"(ah));
      asm volatile("ds_read_b64_tr_b16 %0, %1 offset:1536" : "=v"(vf3) : "v"(ah));
      asm volatile("s_waitcnt lgkmcnt(0)" ::: "memory");
      __builtin_amdgcn_sched_barrier(0);
      union { uint32_t u[2]; s16x4 v4; } pc;
      pc.u[0] = pkbf(sv[h][0] * i0, sv[h][1] * i1);
      pc.u[1] = pkbf(sv[h][2] * i2, sv[h][3] * i3);
      acc[h][0] = MFMA16(vf0, pc.v4, acc[h][0]);
      acc[h][1] = MFMA16(vf1, pc.v4, acc[h][1]);
      acc[h][2] = MFMA16(vf2, pc.v4, acc[h][2]);
      acc[h][3] = MFMA16(vf3, pc.v4, acc[h][3]);
    }
    __builtin_amdgcn_s_barrier();
    __builtin_amdgcn_sched_barrier(0);
  }

  const size_t outBase = (size_t)ch * 8192 * 512 + (rowBase + n0 + ln) * 512;
#pragma unroll
  for (int h = 0; h < 8; ++h)
#pragma unroll
    for (int cf = 0; cf < 4; ++cf)
#pragma unroll
      for (int r2 = 0; r2 < 2; ++r2) {
        int c = h * 64 + cf * 16 + g * 4 + r2 * 2;
        uint32_t u = (uint32_t)f2bf(acc[h][cf][2 * r2]) |
                     ((uint32_t)f2bf(acc[h][cf][2 * r2 + 1]) << 16);
        *(uint32_t*)&part[outBase + c] = u;
      }
}

// ---------------- K5b: reduce the four m-chunk partials (bf16) -> att bf16 ----------------
__global__ __launch_bounds__(256) void k_reduce4(const unsigned short* __restrict__ part,
                                                 unsigned short* __restrict__ att) {
  size_t i8 = ((size_t)blockIdx.x * 256 + threadIdx.x) * 8;
  float o[8] = {0.f, 0.f, 0.f, 0.f, 0.f, 0.f, 0.f, 0.f};
#pragma unroll
  for (int p = 0; p < 4; ++p) {
    uint4 u = *(const uint4*)&part[(size_t)p * 8192 * 512 + i8];
    uint32_t a[4] = {u.x, u.y, u.z, u.w};
#pragma unroll
    for (int j = 0; j < 4; ++j) {
      o[2 * j] += bf2f(a[j] << 16);
      o[2 * j + 1] += bf2f(a[j] & 0xffff0000u);
    }
  }
  uint32_t r0 = (uint32_t)f2bf(o[0]) | ((uint32_t)f2bf(o[1]) << 16);
  uint32_t r1 = (uint32_t)f2bf(o[2]) | ((uint32_t)f2bf(o[3]) << 16);
  uint32_t r2 = (uint32_t)f2bf(o[4]) | ((uint32_t)f2bf(o[5]) << 16);
  uint32_t r3 = (uint32_t)f2bf(o[6]) | ((uint32_t)f2bf(o[7]) << 16);
  *(uint4*)&att[i8] = make_uint4(r0, r1, r2, r3);
}

// ---------------- K6: LayerNorm over rows of [8192][256] ----------------
template <int MODE>
__global__ __launch_bounds__(256) void k_ln(const float* __restrict__ in,
                                            const float* __restrict__ g,
                                            const float* __restrict__ bta,
                                            float* __restrict__ out_f,
                                            unsigned short* __restrict__ out_b) {
  const int l = threadIdx.x & 63, w = threadIdx.x >> 6;
  const size_t row = (size_t)blockIdx.x * 4 + w;
  float4 xv = *(const float4*)(in + row * 256 + l * 4);
  float s = xv.x + xv.y + xv.z + xv.w;
  float q = xv.x * xv.x + xv.y * xv.y + xv.z * xv.z + xv.w * xv.w;
#pragma unroll
  for (int o = 1; o < 64; o <<= 1) {
    s += __shfl_xor(s, o, 64);
    q += __shfl_xor(q, o, 64);
  }
  float mu = s * (1.0f / 256.0f);
  float var = q * (1.0f / 256.0f) - mu * mu;
  float rstd = rsqrtf(var + 1e-5f);
  float4 gv = *(const float4*)(g + l * 4);
  float4 bv = *(const float4*)(bta + l * 4);
  float o0 = (xv.x - mu) * rstd * gv.x + bv.x;
  float o1 = (xv.y - mu) * rstd * gv.y + bv.y;
  float o2 = (xv.z - mu) * rstd * gv.z + bv.z;
  float o3 = (xv.w - mu) * rstd * gv.w + bv.w;
  *(float4*)(out_f + row * 256 + l * 4) = make_float4(o0, o1, o2, o3);
  if (MODE == 0) {
    uint32_t lo = (uint32_t)f2bf(o0) | ((uint32_t)f2bf(o1) << 16);
    uint32_t hi = (uint32_t)f2bf(o2) | ((uint32_t)f2bf(o3) << 16);
    *(uint2*)(out_b + row * 256 + l * 4) = make_uint2(lo, hi);
  }
}

// ---------------- K7: transpose [b*1024+n][256] -> d_out [b][256][1024] ----------------
__global__ __launch_bounds__(256) void k_transout(const float* __restrict__ in,
                                                  float* __restrict__ out) {
  __shared__ __align__(16) float tile[32][36];
  const int b = blockIdx.z, c0 = blockIdx.x * 32, n0 = blockIdx.y * 32;
  const int t = threadIdx.x;
  {
    const int nl = t >> 3, cg = (t & 7) * 4;
    float4 v = *(const float4*)(in + ((size_t)b * 1024 + n0 + nl) * 256 + c0 + cg);
    tile[cg + 0][nl] = v.x;
    tile[cg + 1][nl] = v.y;
    tile[cg + 2][nl] = v.z;
    tile[cg + 3][nl] = v.w;
  }
  __syncthreads();
  {
    const int cl = t >> 3, ng = (t & 7) * 4;
    float4 o = make_float4(tile[cl][ng + 0], tile[cl][ng + 1], tile[cl][ng + 2], tile[cl][ng + 3]);
    *(float4*)(out + ((size_t)b * 256 + c0 + cl) * 1024 + n0 + ng) = o;
  }
}

// ---------------- host launcher ----------------
extern "C" void kernel_launch(void* const* d_in, const int* in_sizes, int n_in,
                              void* d_out, int out_size, void* d_ws, size_t ws_size,
                              hipStream_t stream) {
  const float* x     = (const float*)d_in[0];
  const float* Wk    = (const float*)d_in[1];
  const float* bk    = (const float*)d_in[2];
  const float* Wq    = (const float*)d_in[3];
  const float* bq    = (const float*)d_in[4];
  const float* Wv    = (const float*)d_in[5];
  const float* bv    = (const float*)d_in[6];
  const float* Wproj = (const float*)d_in[7];
  const float* bproj = (const float*)d_in[8];
  const float* ln_g  = (const float*)d_in[9];
  const float* ln_b  = (const float*)d_in[10];
  const float* W1    = (const float*)d_in[11];
  const float* b1    = (const float*)d_in[12];
  const float* W2    = (const float*)d_in[13];
  const float* b2    = (const float*)d_in[14];

  char* ws = (char*)d_ws;
  constexpr size_t OFF_XPTB  = 0;                                    // bf16 [8192][256]
  constexpr size_t OFF_XPTF  = OFF_XPTB  + (size_t)8192 * 256 * 2;   // f32  [8192][256]
  constexpr size_t OFF_WPACK = OFF_XPTF  + (size_t)8192 * 256 * 4;   // bf16 [1536][2304]
  constexpr size_t OFF_BIAS  = OFF_WPACK + (size_t)1536 * 2304 * 2;  // f32  [1536]
  constexpr size_t OFF_WPROJ = OFF_BIAS  + (size_t)1536 * 4;         // bf16 [256][512]
  constexpr size_t OFF_W1B   = OFF_WPROJ + (size_t)256 * 512 * 2;    // bf16 [256][256]
  constexpr size_t OFF_W2B   = OFF_W1B   + (size_t)256 * 256 * 2;    // bf16 [256][256]
  constexpr size_t OFF_PET   = OFF_W2B   + (size_t)256 * 256 * 2;    // f32  [256][32]
  constexpr size_t OFF_ZERO  = OFF_PET   + (size_t)256 * 32 * 4;     // f32  [256] zeros (1KB)
  constexpr size_t OFF_KQV   = OFF_ZERO  + 1024;                     // bf16 [8192][1536]
  constexpr size_t OFF_ATT   = OFF_KQV   + (size_t)8192 * 1536 * 2;  // bf16 [8192][512]
  constexpr size_t OFF_X     = OFF_ATT   + (size_t)8192 * 512 * 2;
  // region X: attn partials (4 x bf16 [8192][512] = 33.5MB), then FFN-phase buffers
  constexpr size_t OFF_PART  = OFF_X;
  constexpr size_t OFF_Y1    = OFF_X;                                // f32 [8192][256]
  constexpr size_t OFF_ADDNF = OFF_Y1    + (size_t)8192 * 256 * 4;   // f32
  constexpr size_t OFF_ADDNB = OFF_ADDNF + (size_t)8192 * 256 * 4;   // bf16
  constexpr size_t OFF_H1    = OFF_ADDNB + (size_t)8192 * 256 * 2;   // bf16
  constexpr size_t OFF_H2    = OFF_H1    + (size_t)8192 * 256 * 2;   // f32

  (void)in_sizes; (void)n_in; (void)out_size; (void)ws_size;

  const char* zp = (const char*)(ws + OFF_ZERO);

  k_petab<<<1, 256, 0, stream>>>((float*)(ws + OFF_PET), (float*)(ws + OFF_ZERO));
  k_xpt<<<dim3(8, 32, 8), 256, 0, stream>>>(x, (const float*)(ws + OFF_PET),
                                            (unsigned short*)(ws + OFF_XPTB),
                                            (float*)(ws + OFF_XPTF));
  k_packw<<<(1536 * 2304 + 255) / 256, 256, 0, stream>>>(Wk, Wq, Wv,
                                                         (unsigned short*)(ws + OFF_WPACK));
  k_packmisc<<<512, 256, 0, stream>>>(bk, bq, bv, Wproj, W1, W2,
                                      (float*)(ws + OFF_BIAS),
                                      (unsigned short*)(ws + OFF_WPROJ),
                                      (unsigned short*)(ws + OFF_W1B),
                                      (unsigned short*)(ws + OFF_W2B));
  // merged conv K+Q+V -> kqv[8192][1536]  (tile 128x128, 768 blocks)
  k_gemm_conv<<<dim3(64, 12), 256, 0, stream>>>(
      (const unsigned short*)(ws + OFF_XPTB), (const unsigned short*)(ws + OFF_WPACK),
      (unsigned short*)(ws + OFF_KQV), (const float*)(ws + OFF_BIAS), zp);
  // fused attention (split-m over 4 chunks) + reduce
  k_attn<<<dim3(512), 256, 0, stream>>>((const unsigned short*)(ws + OFF_KQV),
                                        (unsigned short*)(ws + OFF_PART));
  k_reduce4<<<dim3(2048), 256, 0, stream>>>((const unsigned short*)(ws + OFF_PART),
                                            (unsigned short*)(ws + OFF_ATT));
  // attproj + bias + residual(x+pe): y1 f32   (M=8192, N=256, K=512)
  k_gemm64<2><<<dim3(64, 4), 256, 0, stream>>>(
      (const unsigned short*)(ws + OFF_ATT), (const unsigned short*)(ws + OFF_WPROJ),
      ws + OFF_Y1, bproj, (const float*)(ws + OFF_XPTF), 256, 512);
  k_ln<0><<<2048, 256, 0, stream>>>((const float*)(ws + OFF_Y1), ln_g, ln_b,
                                    (float*)(ws + OFF_ADDNF), (unsigned short*)(ws + OFF_ADDNB));
  // FFN1 + LeakyReLU
  k_gemm64<3><<<dim3(64, 4), 256, 0, stream>>>(
      (const unsigned short*)(ws + OFF_ADDNB), (const unsigned short*)(ws + OFF_W1B),
      ws + OFF_H1, b1, nullptr, 256, 256);
  // FFN2 + bias + residual(addnormed)
  k_gemm64<2><<<dim3(64, 4), 256, 0, stream>>>(
      (const unsigned short*)(ws + OFF_H1), (const unsigned short*)(ws + OFF_W2B),
      ws + OFF_H2, b2, (const float*)(ws + OFF_ADDNF), 256, 256);
  k_ln<1><<<2048, 256, 0, stream>>>((const float*)(ws + OFF_H2), ln_g, ln_b,
                                    (float*)(ws + OFF_Y1), nullptr);
  k_transout<<<dim3(8, 32, 8), 256, 0, stream>>>((const float*)(ws + OFF_Y1), (float*)d_out);
}

// Round 7
// 213.117 us; speedup vs baseline: 1.1679x; 1.0621x over previous
//
#include <hip/hip_runtime.h>
#include <stdint.h>

typedef __attribute__((ext_vector_type(8))) short short8;
typedef __attribute__((ext_vector_type(4))) short s16x4;
typedef __attribute__((ext_vector_type(4))) float f32x4;

#define DEVI __device__ __forceinline__

#if __has_builtin(__builtin_amdgcn_mfma_f32_16x16x16_bf16)
#define MFMA16(a, b, c) __builtin_amdgcn_mfma_f32_16x16x16_bf16(a, b, c, 0, 0, 0)
#else
#define MFMA16(a, b, c) __builtin_amdgcn_mfma_f32_16x16x16bf16_1k(a, b, c, 0, 0, 0)
#endif

DEVI unsigned short f2bf(float f) {
  union { float f; uint32_t u; } v; v.f = f;
  return (unsigned short)((v.u + 0x7fffu + ((v.u >> 16) & 1u)) >> 16);
}

DEVI float bf2f(uint32_t hi16) {
  union { uint32_t u; float f; } v; v.u = hi16;
  return v.f;
}

DEVI uint32_t pkbf(float a, float b) {  // fast RTN pack (positive values)
  union { float f; uint32_t u; } x, y; x.f = a; y.f = b;
  return ((x.u + 0x8000u) >> 16) | (((y.u + 0x8000u) >> 16) << 16);
}

DEVI void gload_lds16(const void* g, void* l) {
  __builtin_amdgcn_global_load_lds(
      (const __attribute__((address_space(1))) uint32_t*)g,
      (__attribute__((address_space(3))) uint32_t*)l, 16, 0, 0);
}

// ---------------- K0: positional encoding table T[256][32] + zero page (1KB) ----------------
__global__ void k_petab(float* __restrict__ T, float* __restrict__ zp) {
  int c = threadIdx.x;
  zp[c] = 0.0f;
  int idx = ((c >= 128) ? c - 128 : c) >> 1;
  float freq = expf(-(float)idx * (logf(10000.0f) / 64.0f));
  for (int p = 0; p < 32; ++p) {
    float ang = (float)p * freq;
    T[c * 32 + p] = (c & 1) ? cosf(ang) : sinf(ang);
  }
}

// ---------------- K1: xpT = (x + pe) transposed to [b*1024+n][256], f32 + bf16 ----------------
__global__ __launch_bounds__(256) void k_xpt(const float* __restrict__ x,
                                             const float* __restrict__ T,
                                             unsigned short* __restrict__ xpt_bf,
                                             float* __restrict__ xpt_f) {
  __shared__ __align__(16) float tile[32][36];
  const int b = blockIdx.z, c0 = blockIdx.x * 32, n0 = blockIdx.y * 32;
  const int t = threadIdx.x;
  {
    const int cl = t >> 3, ng = (t & 7) * 4;
    const int c = c0 + cl;
    float4 v = *(const float4*)(x + ((size_t)b * 256 + c) * 1024 + n0 + ng);
    float p0, p1, p2, p3;
    if (c < 128) {
      p0 = T[c * 32 + ng + 0]; p1 = T[c * 32 + ng + 1];
      p2 = T[c * 32 + ng + 2]; p3 = T[c * 32 + ng + 3];
    } else {
      p0 = p1 = p2 = p3 = T[c * 32 + (n0 >> 5)];
    }
    tile[ng + 0][cl] = v.x + p0;
    tile[ng + 1][cl] = v.y + p1;
    tile[ng + 2][cl] = v.z + p2;
    tile[ng + 3][cl] = v.w + p3;
  }
  __syncthreads();
  {
    const int nl = t >> 3, cg = (t & 7) * 4;
    float o0 = tile[nl][cg + 0], o1 = tile[nl][cg + 1];
    float o2 = tile[nl][cg + 2], o3 = tile[nl][cg + 3];
    size_t row = (size_t)b * 1024 + n0 + nl;
    *(float4*)(xpt_f + row * 256 + c0 + cg) = make_float4(o0, o1, o2, o3);
    uint32_t lo = (uint32_t)f2bf(o0) | ((uint32_t)f2bf(o1) << 16);
    uint32_t hi = (uint32_t)f2bf(o2) | ((uint32_t)f2bf(o3) << 16);
    *(uint2*)(xpt_bf + row * 256 + c0 + cg) = make_uint2(lo, hi);
  }
}

// ---------------- K2: pack conv weights -> Wpack[1536][2304] bf16 ----------------
__global__ void k_packw(const float* __restrict__ Wk, const float* __restrict__ Wq,
                        const float* __restrict__ Wv, unsigned short* __restrict__ Wpack) {
  int i = blockIdx.x * 256 + threadIdx.x;
  if (i >= 1536 * 2304) return;
  int o = i / 2304, kn = i % 2304;
  int ci = kn & 255, khw = kn >> 8;
  const float* src = (o < 512) ? Wk : ((o < 1024) ? Wq : Wv);
  int oo = o & 511;
  Wpack[i] = f2bf(src[((size_t)oo * 256 + ci) * 9 + khw]);
}

// ---------------- K3: misc packs ----------------
__global__ void k_packmisc(const float* __restrict__ bk, const float* __restrict__ bq,
                           const float* __restrict__ bv, const float* __restrict__ Wproj,
                           const float* __restrict__ W1, const float* __restrict__ W2,
                           float* __restrict__ bias_kqv, unsigned short* __restrict__ WprojP,
                           unsigned short* __restrict__ W1b, unsigned short* __restrict__ W2b) {
  int i = blockIdx.x * 256 + threadIdx.x;
  if (i < 1536)
    bias_kqv[i] = (i < 512) ? bk[i] : ((i < 1024) ? bq[i - 512] : bv[i - 1024]);
  if (i < 131072) {
    int j = i >> 9, f = i & 511;
    int h = f >> 6, c = f & 63;
    WprojP[i] = f2bf(Wproj[(size_t)j * 512 + c * 8 + h]);
  }
  if (i < 65536) {
    W1b[i] = f2bf(W1[i]);
    W2b[i] = f2bf(W2[i]);
  }
}

// ---------------- merged conv GEMM v3: kqv[8192][1536] = im2col(xpt).Wpack^T ----------------
__global__ __launch_bounds__(256, 2) void k_gemm_conv(const unsigned short* __restrict__ xpt,
                                                      const unsigned short* __restrict__ Wp,
                                                      unsigned short* __restrict__ kqv,
                                                      const float* __restrict__ bias,
                                                      const char* __restrict__ zp) {
  __shared__ __align__(16) unsigned short As[2][128 * 64];
  __shared__ __align__(16) unsigned short Bs[2][128 * 64];
  const int tid = threadIdx.x, l = tid & 63, w = tid >> 6;
  const int wm = w >> 1, wn = w & 1, g = l >> 4, ln = l & 15;
  const int m0 = blockIdx.x * 128, n0 = blockIdx.y * 128;
  const int swz = (l & 7) ^ (l >> 3);

  int rA[4];
  const char* pAbase[4];
  const char* pA[4];
#pragma unroll
  for (int j = 0; j < 4; ++j) {
    int r = m0 + (w * 4 + j) * 8 + (l >> 3);
    rA[j] = r;
    pAbase[j] = (const char*)xpt + ((size_t)r * 256 + swz * 8) * 2;
  }
  const char* pB[4];
#pragma unroll
  for (int j = 0; j < 4; ++j) {
    int r = n0 + (w * 4 + j) * 8 + (l >> 3);
    pB[j] = (const char*)Wp + ((size_t)r * 2304 + swz * 8) * 2;
  }

  f32x4 acc[4][4] = {};

  auto setA = [&](int khw) {
    int d3 = (khw * 11) >> 5;
    int dy = d3 - 1, dx = khw - d3 * 3 - 1;
    int off = (dy * 32 + dx) * 512;
#pragma unroll
    for (int j = 0; j < 4; ++j) {
      int y = ((rA[j] >> 5) & 31) + dy;
      int x = (rA[j] & 31) + dx;
      pA[j] = (((unsigned)y < 32u) && ((unsigned)x < 32u)) ? (pAbase[j] + off) : zp;
    }
  };
  auto STAGE = [&](int buf) {
#pragma unroll
    for (int j = 0; j < 4; ++j) {
      gload_lds16(pA[j], (char*)As + buf * 16384 + (w * 4 + j) * 1024);
      pA[j] += 128;
    }
#pragma unroll
    for (int j = 0; j < 4; ++j) {
      gload_lds16(pB[j], (char*)Bs + buf * 16384 + (w * 4 + j) * 1024);
      pB[j] += 128;
    }
  };
  auto COMPUTE = [&](int buf) {
    const char* Ab2 = (const char*)As + buf * 16384;
    const char* Bb2 = (const char*)Bs + buf * 16384;
#pragma unroll
    for (int kk = 0; kk < 2; ++kk) {
      short8 af[4], bfr[4];
#pragma unroll
      for (int fm = 0; fm < 4; ++fm)
        af[fm] = *(const short8*)(Ab2 + (wm * 64 + fm * 16 + ln) * 128 +
                                  (((kk * 4 + g) ^ (ln & 7)) * 16));
#pragma unroll
      for (int fn = 0; fn < 4; ++fn)
        bfr[fn] = *(const short8*)(Bb2 + (wn * 64 + fn * 16 + ln) * 128 +
                                   (((kk * 4 + g) ^ (ln & 7)) * 16));
#pragma unroll
      for (int fm = 0; fm < 4; ++fm)
#pragma unroll
        for (int fn = 0; fn < 4; ++fn)
          acc[fm][fn] = __builtin_amdgcn_mfma_f32_16x16x32_bf16(af[fm], bfr[fn], acc[fm][fn], 0, 0, 0);
    }
  };

  setA(0);
  STAGE(0);
#pragma unroll
  for (int s = 0; s < 36; ++s) {
    const int buf = s & 1;
    if (s < 35) {
      if (((s + 1) & 3) == 0) setA((s + 1) >> 2);
      STAGE(buf ^ 1);
      asm volatile("s_waitcnt vmcnt(8)" ::: "memory");
    } else {
      asm volatile("s_waitcnt vmcnt(0)" ::: "memory");
    }
    __builtin_amdgcn_s_barrier();
    __builtin_amdgcn_sched_barrier(0);
    COMPUTE(buf);
    asm volatile("s_waitcnt lgkmcnt(0)" ::: "memory");
    __builtin_amdgcn_s_barrier();
    __builtin_amdgcn_sched_barrier(0);
  }

#pragma unroll
  for (int fm = 0; fm < 4; ++fm)
#pragma unroll
    for (int fn = 0; fn < 4; ++fn) {
      int col = n0 + wn * 64 + fn * 16 + ln;
      float bb = bias[col];
#pragma unroll
      for (int r = 0; r < 4; ++r) {
        int row = m0 + wm * 64 + fm * 16 + g * 4 + r;
        kqv[(size_t)row * 1536 + col] = f2bf(acc[fm][fn][r] + bb);
      }
    }
}

// ---------------- GEMM BN=64: C[M][N] = A[M][K].B[N][K]^T, tile 128x64, 4 waves ----------------
template <int EPI>
__global__ __launch_bounds__(256) void k_gemm64(const unsigned short* __restrict__ A,
                                                const unsigned short* __restrict__ B,
                                                void* __restrict__ Cout,
                                                const float* __restrict__ bias,
                                                const float* __restrict__ resid,
                                                int N, int K) {
  __shared__ __align__(16) unsigned short As[128 * 64];
  __shared__ __align__(16) unsigned short Bs[64 * 64];
  const int tid = threadIdx.x, l = tid & 63, w = tid >> 6;
  const int g = l >> 4, ln = l & 15;
  const int m0 = blockIdx.x * 128, n0 = blockIdx.y * 64;
  const int swz = (l & 7) ^ (l >> 3);
  f32x4 acc[2][4] = {};

  for (int kt = 0; kt < K; kt += 64) {
#pragma unroll
    for (int j = 0; j < 4; ++j) {
      int seg = w * 4 + j;
      int r8 = seg * 8 + (l >> 3);
      gload_lds16((const char*)A + ((size_t)(m0 + r8) * K + kt + swz * 8) * 2,
                  (char*)As + seg * 1024);
    }
#pragma unroll
    for (int j = 0; j < 2; ++j) {
      int seg = w * 2 + j;
      int r8 = seg * 8 + (l >> 3);
      gload_lds16((const char*)B + ((size_t)(n0 + r8) * K + kt + swz * 8) * 2,
                  (char*)Bs + seg * 1024);
    }
    __syncthreads();
#pragma unroll
    for (int kk = 0; kk < 2; ++kk) {
      short8 af[2], bfr[4];
#pragma unroll
      for (int fm = 0; fm < 2; ++fm)
        af[fm] = *(const short8*)((const char*)As + (w * 32 + fm * 16 + ln) * 128 +
                                  (((kk * 4 + g) ^ (ln & 7)) * 16));
#pragma unroll
      for (int fn = 0; fn < 4; ++fn)
        bfr[fn] = *(const short8*)((const char*)Bs + (fn * 16 + ln) * 128 +
                                   (((kk * 4 + g) ^ (ln & 7)) * 16));
#pragma unroll
      for (int fm = 0; fm < 2; ++fm)
#pragma unroll
        for (int fn = 0; fn < 4; ++fn)
          acc[fm][fn] = __builtin_amdgcn_mfma_f32_16x16x32_bf16(af[fm], bfr[fn], acc[fm][fn], 0, 0, 0);
    }
    __syncthreads();
  }

#pragma unroll
  for (int fm = 0; fm < 2; ++fm)
#pragma unroll
    for (int fn = 0; fn < 4; ++fn)
#pragma unroll
      for (int r = 0; r < 4; ++r) {
        int row = m0 + w * 32 + fm * 16 + g * 4 + r;
        int col = n0 + fn * 16 + ln;
        float v = acc[fm][fn][r] + bias[col];
        size_t cidx = (size_t)row * N + col;
        if (EPI == 2) {
          ((float*)Cout)[cidx] = v + resid[cidx];
        } else {
          v = (v > 0.f) ? v : 0.1f * v;
          ((unsigned short*)Cout)[cidx] = f2bf(v);
        }
      }
}

// ---------------- K5: fused attention v6 — head-split waves, 16 waves/CU ----------------
// Wave = (nt in 2 n-subtiles, hg in 4 head-groups x 2 heads). In-register exp; per-lane
// partial exp-sums exchanged across the 4 hg-waves via 8KB LDS (softmax over heads).
// Coalesced Q/V staging (1KB-row glds, XOR source swizzle); in-LDS transpose builds the
// tr-read V subtiles; PV via 8 batched ds_read_b64_tr_b16 + MFMA16 with P from registers.
// Single-buffered LDS (56KB => 2 blocks/CU); 2 raw barriers/step; split-m 2.
// 512 blocks: id = b(&7, XCD-pinned) + 8*ng(32) + 256*ch(2); 32 steps x 16m.
__global__ __launch_bounds__(512, 4) void k_attn(const unsigned short* __restrict__ kqv,
                                                 unsigned short* __restrict__ part) {
  __shared__ __align__(16) unsigned short Qs[16][512];    // [m][c-chunk XOR-swz by m&7]
  __shared__ __align__(16) unsigned short Vlin[16][512];  // [m][c-chunk XOR-swz by m&7]
  __shared__ __align__(16) unsigned short Vs[32][16][16]; // [cb][m][c] tr-read subtiles
  __shared__ __align__(16) float sums[4][2][64][4];       // [hg][nt][lane][m-pos]
  const int tid = threadIdx.x, l = tid & 63, w = tid >> 6;
  const int g = l >> 4, ln = l & 15;
  const int nt = w & 1, hg = w >> 1;          // 2 n-subtiles x 4 head-groups
  const int id = blockIdx.x;
  const int b = id & 7, ng = (id >> 3) & 31, ch = id >> 8;
  const int n0 = ng * 32 + nt * 16;
  const int m_base = ch * 512;
  const size_t rowBase = (size_t)b * 1024;
  const float SC = 1.0f / 1024.0f;

  // K fragments for this wave's 2 heads (B operand of QK)
  short8 ak[2][2];
#pragma unroll
  for (int hl = 0; hl < 2; ++hl)
#pragma unroll
    for (int kk = 0; kk < 2; ++kk)
      ak[hl][kk] = *(const short8*)&kqv[(rowBase + n0 + ln) * 1536 +
                                        (hg * 2 + hl) * 64 + kk * 32 + g * 8];

  f32x4 acc[2][4] = {};  // O[c][n] for 2 heads x 64c

  auto STAGE = [&](int m0s) {
#pragma unroll
    for (int i = 0; i < 2; ++i) {  // each wave stages rows w*2, w*2+1 (Q and V), coalesced
      int row = w * 2 + i;
      const unsigned short* src = kqv + (rowBase + m0s + row) * 1536;
      gload_lds16(src + 512 + ((l ^ (row & 7)) * 8), (char*)Qs + row * 1024);
      gload_lds16(src + 1024 + ((l ^ (row & 7)) * 8), (char*)Vlin + row * 1024);
    }
  };

  STAGE(m_base);
  asm volatile("s_waitcnt vmcnt(0)" ::: "memory");
  __builtin_amdgcn_s_barrier();
  __builtin_amdgcn_sched_barrier(0);

  const uint32_t vsBase = (uint32_t)(uintptr_t)&Vs[0][0][0] + l * 8;

  for (int s = 0; s < 32; ++s) {
    // --- transpose Vlin -> Vs subtiles (2 b128 read+write per thread) ---
    {
      const int tm = l & 15;
#pragma unroll
      for (int i = 0; i < 2; ++i) {
        int tch = (l >> 4) + w * 4 + i * 32;  // 0..63 c-chunks
        short8 tv = *(const short8*)((const char*)Vlin + tm * 1024 +
                                     ((tch ^ (tm & 7)) * 16));
        *(short8*)((char*)Vs + (tch >> 1) * 512 + tm * 32 + (tch & 1) * 16) = tv;
      }
    }

    // --- QK^T for this wave's 2 heads: S[m][n], in registers ---
    f32x4 sv[2] = {};
#pragma unroll
    for (int kk = 0; kk < 2; ++kk)
#pragma unroll
      for (int hl = 0; hl < 2; ++hl) {
        int chq = (hg * 2 + hl) * 8 + kk * 4 + g;
        short8 qa = *(const short8*)((const char*)Qs + ln * 1024 +
                                     ((chq ^ (ln & 7)) * 16));
        sv[hl] = __builtin_amdgcn_mfma_f32_16x16x32_bf16(qa, ak[hl][kk], sv[hl], 0, 0, 0);
      }

    // --- exp + partial sums; write to exchange buffer ---
    f32x4 e0, e1, ps;
#pragma unroll
    for (int j = 0; j < 4; ++j) {
      e0[j] = __expf(sv[0][j] * SC);
      e1[j] = __expf(sv[1][j] * SC);
      ps[j] = e0[j] + e1[j];
    }
    *(f32x4*)&sums[hg][nt][l][0] = ps;
    asm volatile("s_waitcnt lgkmcnt(0)" ::: "memory");
    __builtin_amdgcn_s_barrier();       // B3: sums + Vs transpose visible
    __builtin_amdgcn_sched_barrier(0);

    // --- issue next-step staging early (overlaps sums-read/softmax/PV) ---
    if (s < 31) STAGE(m_base + (s + 1) * 16);

    // --- total over all 8 heads; normalize ---
    f32x4 tot = ps;
#pragma unroll
    for (int d = 1; d < 4; ++d) {
      f32x4 o = *(const f32x4*)&sums[(hg + d) & 3][nt][l][0];
      tot[0] += o[0]; tot[1] += o[1]; tot[2] += o[2]; tot[3] += o[3];
    }
    f32x4 inv;
#pragma unroll
    for (int j = 0; j < 4; ++j) inv[j] = 1.0f / tot[j];

    // --- PV: batched tr_reads (V^T frags), P from registers as B operand ---
    s16x4 vf[8];
#pragma unroll
    for (int hl = 0; hl < 2; ++hl) {
      uint32_t ah = vsBase + (hg * 2 + hl) * 2048;
      asm volatile("ds_read_b64_tr_b16 %0, %1" : "=v"(vf[hl * 4 + 0]) : "v"(ah));
      asm volatile("ds_read_b64_tr_b16 %0, %1 offset:512" : "=v"(vf[hl * 4 + 1]) : "v"(ah));
      asm volatile("ds_read_b64_tr_b16 %0, %1 offset:1024" : "=v"(vf[hl * 4 + 2]) : "v"(ah));
      asm volatile("ds_read_b64_tr_b16 %0, %1 offset:1536" : "=v"(vf[hl * 4 + 3]) : "v"(ah));
    }
    asm volatile("s_waitcnt lgkmcnt(0)" ::: "memory");
    __builtin_amdgcn_sched_barrier(0);
    union { uint32_t u[2]; s16x4 v4; } pc0, pc1;
    pc0.u[0] = pkbf(e0[0] * inv[0], e0[1] * inv[1]);
    pc0.u[1] = pkbf(e0[2] * inv[2], e0[3] * inv[3]);
    pc1.u[0] = pkbf(e1[0] * inv[0], e1[1] * inv[1]);
    pc1.u[1] = pkbf(e1[2] * inv[2], e1[3] * inv[3]);
#pragma unroll
    for (int cf = 0; cf < 4; ++cf) {
      acc[0][cf] = MFMA16(vf[cf], pc0.v4, acc[0][cf]);
      acc[1][cf] = MFMA16(vf[4 + cf], pc1.v4, acc[1][cf]);
    }

    asm volatile("s_waitcnt vmcnt(0)" ::: "memory");
    __builtin_amdgcn_s_barrier();       // B1: staging landed; all PV/sums reads done
    __builtin_amdgcn_sched_barrier(0);
  }

  // partial O (bf16) for this m-chunk
  const size_t outBase = (size_t)ch * 8192 * 512 + (rowBase + n0 + ln) * 512;
#pragma unroll
  for (int hl = 0; hl < 2; ++hl)
#pragma unroll
    for (int cf = 0; cf < 4; ++cf)
#pragma unroll
      for (int r2 = 0; r2 < 2; ++r2) {
        int c = (hg * 2 + hl) * 64 + cf * 16 + g * 4 + r2 * 2;
        uint32_t u = (uint32_t)f2bf(acc[hl][cf][2 * r2]) |
                     ((uint32_t)f2bf(acc[hl][cf][2 * r2 + 1]) << 16);
        *(uint32_t*)&part[outBase + c] = u;
      }
}

// ---------------- K5b: reduce the two m-chunk partials (bf16) -> att bf16 ----------------
__global__ __launch_bounds__(256) void k_reduce2(const unsigned short* __restrict__ part,
                                                 unsigned short* __restrict__ att) {
  size_t i8 = ((size_t)blockIdx.x * 256 + threadIdx.x) * 8;
  float o[8] = {0.f, 0.f, 0.f, 0.f, 0.f, 0.f, 0.f, 0.f};
#pragma unroll
  for (int p = 0; p < 2; ++p) {
    uint4 u = *(const uint4*)&part[(size_t)p * 8192 * 512 + i8];
    uint32_t a[4] = {u.x, u.y, u.z, u.w};
#pragma unroll
    for (int j = 0; j < 4; ++j) {
      o[2 * j] += bf2f(a[j] << 16);
      o[2 * j + 1] += bf2f(a[j] & 0xffff0000u);
    }
  }
  uint32_t r0 = (uint32_t)f2bf(o[0]) | ((uint32_t)f2bf(o[1]) << 16);
  uint32_t r1 = (uint32_t)f2bf(o[2]) | ((uint32_t)f2bf(o[3]) << 16);
  uint32_t r2 = (uint32_t)f2bf(o[4]) | ((uint32_t)f2bf(o[5]) << 16);
  uint32_t r3 = (uint32_t)f2bf(o[6]) | ((uint32_t)f2bf(o[7]) << 16);
  *(uint4*)&att[i8] = make_uint4(r0, r1, r2, r3);
}

// ---------------- K6: LayerNorm over rows of [8192][256] ----------------
template <int MODE>
__global__ __launch_bounds__(256) void k_ln(const float* __restrict__ in,
                                            const float* __restrict__ g,
                                            const float* __restrict__ bta,
                                            float* __restrict__ out_f,
                                            unsigned short* __restrict__ out_b) {
  const int l = threadIdx.x & 63, w = threadIdx.x >> 6;
  const size_t row = (size_t)blockIdx.x * 4 + w;
  float4 xv = *(const float4*)(in + row * 256 + l * 4);
  float s = xv.x + xv.y + xv.z + xv.w;
  float q = xv.x * xv.x + xv.y * xv.y + xv.z * xv.z + xv.w * xv.w;
#pragma unroll
  for (int o = 1; o < 64; o <<= 1) {
    s += __shfl_xor(s, o, 64);
    q += __shfl_xor(q, o, 64);
  }
  float mu = s * (1.0f / 256.0f);
  float var = q * (1.0f / 256.0f) - mu * mu;
  float rstd = rsqrtf(var + 1e-5f);
  float4 gv = *(const float4*)(g + l * 4);
  float4 bv = *(const float4*)(bta + l * 4);
  float o0 = (xv.x - mu) * rstd * gv.x + bv.x;
  float o1 = (xv.y - mu) * rstd * gv.y + bv.y;
  float o2 = (xv.z - mu) * rstd * gv.z + bv.z;
  float o3 = (xv.w - mu) * rstd * gv.w + bv.w;
  *(float4*)(out_f + row * 256 + l * 4) = make_float4(o0, o1, o2, o3);
  if (MODE == 0) {
    uint32_t lo = (uint32_t)f2bf(o0) | ((uint32_t)f2bf(o1) << 16);
    uint32_t hi = (uint32_t)f2bf(o2) | ((uint32_t)f2bf(o3) << 16);
    *(uint2*)(out_b + row * 256 + l * 4) = make_uint2(lo, hi);
  }
}

// ---------------- K7: transpose [b*1024+n][256] -> d_out [b][256][1024] ----------------
__global__ __launch_bounds__(256) void k_transout(const float* __restrict__ in,
                                                  float* __restrict__ out) {
  __shared__ __align__(16) float tile[32][36];
  const int b = blockIdx.z, c0 = blockIdx.x * 32, n0 = blockIdx.y * 32;
  const int t = threadIdx.x;
  {
    const int nl = t >> 3, cg = (t & 7) * 4;
    float4 v = *(const float4*)(in + ((size_t)b * 1024 + n0 + nl) * 256 + c0 + cg);
    tile[cg + 0][nl] = v.x;
    tile[cg + 1][nl] = v.y;
    tile[cg + 2][nl] = v.z;
    tile[cg + 3][nl] = v.w;
  }
  __syncthreads();
  {
    const int cl = t >> 3, ng = (t & 7) * 4;
    float4 o = make_float4(tile[cl][ng + 0], tile[cl][ng + 1], tile[cl][ng + 2], tile[cl][ng + 3]);
    *(float4*)(out + ((size_t)b * 256 + c0 + cl) * 1024 + n0 + ng) = o;
  }
}

// ---------------- host launcher ----------------
extern "C" void kernel_launch(void* const* d_in, const int* in_sizes, int n_in,
                              void* d_out, int out_size, void* d_ws, size_t ws_size,
                              hipStream_t stream) {
  const float* x     = (const float*)d_in[0];
  const float* Wk    = (const float*)d_in[1];
  const float* bk    = (const float*)d_in[2];
  const float* Wq    = (const float*)d_in[3];
  const float* bq    = (const float*)d_in[4];
  const float* Wv    = (const float*)d_in[5];
  const float* bv    = (const float*)d_in[6];
  const float* Wproj = (const float*)d_in[7];
  const float* bproj = (const float*)d_in[8];
  const float* ln_g  = (const float*)d_in[9];
  const float* ln_b  = (const float*)d_in[10];
  const float* W1    = (const float*)d_in[11];
  const float* b1    = (const float*)d_in[12];
  const float* W2    = (const float*)d_in[13];
  const float* b2    = (const float*)d_in[14];

  char* ws = (char*)d_ws;
  constexpr size_t OFF_XPTB  = 0;                                    // bf16 [8192][256]
  constexpr size_t OFF_XPTF  = OFF_XPTB  + (size_t)8192 * 256 * 2;   // f32  [8192][256]
  constexpr size_t OFF_WPACK = OFF_XPTF  + (size_t)8192 * 256 * 4;   // bf16 [1536][2304]
  constexpr size_t OFF_BIAS  = OFF_WPACK + (size_t)1536 * 2304 * 2;  // f32  [1536]
  constexpr size_t OFF_WPROJ = OFF_BIAS  + (size_t)1536 * 4;         // bf16 [256][512]
  constexpr size_t OFF_W1B   = OFF_WPROJ + (size_t)256 * 512 * 2;    // bf16 [256][256]
  constexpr size_t OFF_W2B   = OFF_W1B   + (size_t)256 * 256 * 2;    // bf16 [256][256]
  constexpr size_t OFF_PET   = OFF_W2B   + (size_t)256 * 256 * 2;    // f32  [256][32]
  constexpr size_t OFF_ZERO  = OFF_PET   + (size_t)256 * 32 * 4;     // f32  [256] zeros (1KB)
  constexpr size_t OFF_KQV   = OFF_ZERO  + 1024;                     // bf16 [8192][1536]
  constexpr size_t OFF_ATT   = OFF_KQV   + (size_t)8192 * 1536 * 2;  // bf16 [8192][512]
  constexpr size_t OFF_X     = OFF_ATT   + (size_t)8192 * 512 * 2;
  // region X: attn partials (2 x bf16 [8192][512] = 16.7MB), then FFN-phase buffers
  constexpr size_t OFF_PART  = OFF_X;
  constexpr size_t OFF_Y1    = OFF_X;                                // f32 [8192][256]
  constexpr size_t OFF_ADDNF = OFF_Y1    + (size_t)8192 * 256 * 4;   // f32
  constexpr size_t OFF_ADDNB = OFF_ADDNF + (size_t)8192 * 256 * 4;   // bf16
  constexpr size_t OFF_H1    = OFF_ADDNB + (size_t)8192 * 256 * 2;   // bf16
  constexpr size_t OFF_H2    = OFF_H1    + (size_t)8192 * 256 * 2;   // f32

  (void)in_sizes; (void)n_in; (void)out_size; (void)ws_size;

  const char* zp = (const char*)(ws + OFF_ZERO);

  k_petab<<<1, 256, 0, stream>>>((float*)(ws + OFF_PET), (float*)(ws + OFF_ZERO));
  k_xpt<<<dim3(8, 32, 8), 256, 0, stream>>>(x, (const float*)(ws + OFF_PET),
                                            (unsigned short*)(ws + OFF_XPTB),
                                            (float*)(ws + OFF_XPTF));
  k_packw<<<(1536 * 2304 + 255) / 256, 256, 0, stream>>>(Wk, Wq, Wv,
                                                         (unsigned short*)(ws + OFF_WPACK));
  k_packmisc<<<512, 256, 0, stream>>>(bk, bq, bv, Wproj, W1, W2,
                                      (float*)(ws + OFF_BIAS),
                                      (unsigned short*)(ws + OFF_WPROJ),
                                      (unsigned short*)(ws + OFF_W1B),
                                      (unsigned short*)(ws + OFF_W2B));
  // merged conv K+Q+V -> kqv[8192][1536]  (tile 128x128, 768 blocks)
  k_gemm_conv<<<dim3(64, 12), 256, 0, stream>>>(
      (const unsigned short*)(ws + OFF_XPTB), (const unsigned short*)(ws + OFF_WPACK),
      (unsigned short*)(ws + OFF_KQV), (const float*)(ws + OFF_BIAS), zp);
  // fused attention (split-m over 2 chunks) + reduce
  k_attn<<<dim3(512), 512, 0, stream>>>((const unsigned short*)(ws + OFF_KQV),
                                        (unsigned short*)(ws + OFF_PART));
  k_reduce2<<<dim3(2048), 256, 0, stream>>>((const unsigned short*)(ws + OFF_PART),
                                            (unsigned short*)(ws + OFF_ATT));
  // attproj + bias + residual(x+pe): y1 f32   (M=8192, N=256, K=512)
  k_gemm64<2><<<dim3(64, 4), 256, 0, stream>>>(
      (const unsigned short*)(ws + OFF_ATT), (const unsigned short*)(ws + OFF_WPROJ),
      ws + OFF_Y1, bproj, (const float*)(ws + OFF_XPTF), 256, 512);
  k_ln<0><<<2048, 256, 0, stream>>>((const float*)(ws + OFF_Y1), ln_g, ln_b,
                                    (float*)(ws + OFF_ADDNF), (unsigned short*)(ws + OFF_ADDNB));
  // FFN1 + LeakyReLU
  k_gemm64<3><<<dim3(64, 4), 256, 0, stream>>>(
      (const unsigned short*)(ws + OFF_ADDNB), (const unsigned short*)(ws + OFF_W1B),
      ws + OFF_H1, b1, nullptr, 256, 256);
  // FFN2 + bias + residual(addnormed)
  k_gemm64<2><<<dim3(64, 4), 256, 0, stream>>>(
      (const unsigned short*)(ws + OFF_H1), (const unsigned short*)(ws + OFF_W2B),
      ws + OFF_H2, b2, (const float*)(ws + OFF_ADDNF), 256, 256);
  k_ln<1><<<2048, 256, 0, stream>>>((const float*)(ws + OFF_H2), ln_g, ln_b,
                                    (float*)(ws + OFF_Y1), nullptr);
  k_transout<<<dim3(8, 32, 8), 256, 0, stream>>>((const float*)(ws + OFF_Y1), (float*)d_out);
}

// Round 8
// 206.227 us; speedup vs baseline: 1.2070x; 1.0334x over previous
//
#include <hip/hip_runtime.h>
#include <stdint.h>

typedef __attribute__((ext_vector_type(8))) short short8;
typedef __attribute__((ext_vector_type(4))) short s16x4;
typedef __attribute__((ext_vector_type(4))) float f32x4;

#define DEVI __device__ __forceinline__

#if __has_builtin(__builtin_amdgcn_mfma_f32_16x16x16_bf16)
#define MFMA16(a, b, c) __builtin_amdgcn_mfma_f32_16x16x16_bf16(a, b, c, 0, 0, 0)
#else
#define MFMA16(a, b, c) __builtin_amdgcn_mfma_f32_16x16x16bf16_1k(a, b, c, 0, 0, 0)
#endif

DEVI unsigned short f2bf(float f) {
  union { float f; uint32_t u; } v; v.f = f;
  return (unsigned short)((v.u + 0x7fffu + ((v.u >> 16) & 1u)) >> 16);
}

DEVI float bf2f(uint32_t hi16) {
  union { uint32_t u; float f; } v; v.u = hi16;
  return v.f;
}

DEVI uint32_t pkbf(float a, float b) {  // fast RTN pack (positive values)
  union { float f; uint32_t u; } x, y; x.f = a; y.f = b;
  return ((x.u + 0x8000u) >> 16) | (((y.u + 0x8000u) >> 16) << 16);
}

DEVI void gload_lds16(const void* g, void* l) {
  __builtin_amdgcn_global_load_lds(
      (const __attribute__((address_space(1))) uint32_t*)g,
      (__attribute__((address_space(3))) uint32_t*)l, 16, 0, 0);
}

// ---------------- K0: positional encoding table T[256][32] + zero page (1KB) ----------------
__global__ void k_petab(float* __restrict__ T, float* __restrict__ zp) {
  int c = threadIdx.x;
  zp[c] = 0.0f;
  int idx = ((c >= 128) ? c - 128 : c) >> 1;
  float freq = expf(-(float)idx * (logf(10000.0f) / 64.0f));
  for (int p = 0; p < 32; ++p) {
    float ang = (float)p * freq;
    T[c * 32 + p] = (c & 1) ? cosf(ang) : sinf(ang);
  }
}

// ---------------- K1: xpT = (x + pe) transposed to [b*1024+n][256], f32 + bf16 ----------------
__global__ __launch_bounds__(256) void k_xpt(const float* __restrict__ x,
                                             const float* __restrict__ T,
                                             unsigned short* __restrict__ xpt_bf,
                                             float* __restrict__ xpt_f) {
  __shared__ __align__(16) float tile[32][36];
  const int b = blockIdx.z, c0 = blockIdx.x * 32, n0 = blockIdx.y * 32;
  const int t = threadIdx.x;
  {
    const int cl = t >> 3, ng = (t & 7) * 4;
    const int c = c0 + cl;
    float4 v = *(const float4*)(x + ((size_t)b * 256 + c) * 1024 + n0 + ng);
    float p0, p1, p2, p3;
    if (c < 128) {
      p0 = T[c * 32 + ng + 0]; p1 = T[c * 32 + ng + 1];
      p2 = T[c * 32 + ng + 2]; p3 = T[c * 32 + ng + 3];
    } else {
      p0 = p1 = p2 = p3 = T[c * 32 + (n0 >> 5)];
    }
    tile[ng + 0][cl] = v.x + p0;
    tile[ng + 1][cl] = v.y + p1;
    tile[ng + 2][cl] = v.z + p2;
    tile[ng + 3][cl] = v.w + p3;
  }
  __syncthreads();
  {
    const int nl = t >> 3, cg = (t & 7) * 4;
    float o0 = tile[nl][cg + 0], o1 = tile[nl][cg + 1];
    float o2 = tile[nl][cg + 2], o3 = tile[nl][cg + 3];
    size_t row = (size_t)b * 1024 + n0 + nl;
    *(float4*)(xpt_f + row * 256 + c0 + cg) = make_float4(o0, o1, o2, o3);
    uint32_t lo = (uint32_t)f2bf(o0) | ((uint32_t)f2bf(o1) << 16);
    uint32_t hi = (uint32_t)f2bf(o2) | ((uint32_t)f2bf(o3) << 16);
    *(uint2*)(xpt_bf + row * 256 + c0 + cg) = make_uint2(lo, hi);
  }
}

// ---------------- K2: all weight packs in one kernel ----------------
// blocks [0,13824): Wpack[1536][2304]; blocks [13824,14336): bias concat + WprojP2 + W1b/W2b
__global__ void k_packall(const float* __restrict__ Wk, const float* __restrict__ Wq,
                          const float* __restrict__ Wv, const float* __restrict__ bk,
                          const float* __restrict__ bq, const float* __restrict__ bv,
                          const float* __restrict__ Wproj, const float* __restrict__ W1,
                          const float* __restrict__ W2, unsigned short* __restrict__ Wpack,
                          float* __restrict__ bias_kqv, unsigned short* __restrict__ WprojP,
                          unsigned short* __restrict__ W1b, unsigned short* __restrict__ W2b) {
  int bid = blockIdx.x;
  if (bid < 13824) {
    int i = bid * 256 + threadIdx.x;
    if (i >= 1536 * 2304) return;
    int o = i / 2304, kn = i % 2304;
    int ci = kn & 255, khw = kn >> 8;
    const float* src = (o < 512) ? Wk : ((o < 1024) ? Wq : Wv);
    int oo = o & 511;
    Wpack[i] = f2bf(src[((size_t)oo * 256 + ci) * 9 + khw]);
  } else {
    int i = (bid - 13824) * 256 + threadIdx.x;  // [0, 131072)
    if (i < 1536)
      bias_kqv[i] = (i < 512) ? bk[i] : ((i < 1024) ? bq[i - 512] : bv[i - 1024]);
    {
      int j = i >> 9, f = i & 511;
      int h = f >> 6, c = f & 63;
      unsigned short v = f2bf(Wproj[(size_t)j * 512 + c * 8 + h]);
      WprojP[(size_t)j * 1024 + f] = v;        // K-chunk 0
      WprojP[(size_t)j * 1024 + 512 + f] = v;  // K-chunk 1 (duplicated: O = O0 + O1)
    }
    if (i < 65536) {
      W1b[i] = f2bf(W1[i]);
      W2b[i] = f2bf(W2[i]);
    }
  }
}

// ---------------- merged conv GEMM: kqv[8192][1536] = im2col(xpt).Wpack^T ----------------
__global__ __launch_bounds__(256, 2) void k_gemm_conv(const unsigned short* __restrict__ xpt,
                                                      const unsigned short* __restrict__ Wp,
                                                      unsigned short* __restrict__ kqv,
                                                      const float* __restrict__ bias,
                                                      const char* __restrict__ zp) {
  __shared__ __align__(16) unsigned short As[2][128 * 64];
  __shared__ __align__(16) unsigned short Bs[2][128 * 64];
  const int tid = threadIdx.x, l = tid & 63, w = tid >> 6;
  const int wm = w >> 1, wn = w & 1, g = l >> 4, ln = l & 15;
  const int m0 = blockIdx.x * 128, n0 = blockIdx.y * 128;
  const int swz = (l & 7) ^ (l >> 3);

  int rA[4];
  const char* pAbase[4];
  const char* pA[4];
#pragma unroll
  for (int j = 0; j < 4; ++j) {
    int r = m0 + (w * 4 + j) * 8 + (l >> 3);
    rA[j] = r;
    pAbase[j] = (const char*)xpt + ((size_t)r * 256 + swz * 8) * 2;
  }
  const char* pB[4];
#pragma unroll
  for (int j = 0; j < 4; ++j) {
    int r = n0 + (w * 4 + j) * 8 + (l >> 3);
    pB[j] = (const char*)Wp + ((size_t)r * 2304 + swz * 8) * 2;
  }

  f32x4 acc[4][4] = {};

  auto setA = [&](int khw) {
    int d3 = (khw * 11) >> 5;
    int dy = d3 - 1, dx = khw - d3 * 3 - 1;
    int off = (dy * 32 + dx) * 512;
#pragma unroll
    for (int j = 0; j < 4; ++j) {
      int y = ((rA[j] >> 5) & 31) + dy;
      int x = (rA[j] & 31) + dx;
      pA[j] = (((unsigned)y < 32u) && ((unsigned)x < 32u)) ? (pAbase[j] + off) : zp;
    }
  };
  auto STAGE = [&](int buf) {
#pragma unroll
    for (int j = 0; j < 4; ++j) {
      gload_lds16(pA[j], (char*)As + buf * 16384 + (w * 4 + j) * 1024);
      pA[j] += 128;
    }
#pragma unroll
    for (int j = 0; j < 4; ++j) {
      gload_lds16(pB[j], (char*)Bs + buf * 16384 + (w * 4 + j) * 1024);
      pB[j] += 128;
    }
  };
  auto COMPUTE = [&](int buf) {
    const char* Ab2 = (const char*)As + buf * 16384;
    const char* Bb2 = (const char*)Bs + buf * 16384;
#pragma unroll
    for (int kk = 0; kk < 2; ++kk) {
      short8 af[4], bfr[4];
#pragma unroll
      for (int fm = 0; fm < 4; ++fm)
        af[fm] = *(const short8*)(Ab2 + (wm * 64 + fm * 16 + ln) * 128 +
                                  (((kk * 4 + g) ^ (ln & 7)) * 16));
#pragma unroll
      for (int fn = 0; fn < 4; ++fn)
        bfr[fn] = *(const short8*)(Bb2 + (wn * 64 + fn * 16 + ln) * 128 +
                                   (((kk * 4 + g) ^ (ln & 7)) * 16));
#pragma unroll
      for (int fm = 0; fm < 4; ++fm)
#pragma unroll
        for (int fn = 0; fn < 4; ++fn)
          acc[fm][fn] = __builtin_amdgcn_mfma_f32_16x16x32_bf16(af[fm], bfr[fn], acc[fm][fn], 0, 0, 0);
    }
  };

  setA(0);
  STAGE(0);
#pragma unroll
  for (int s = 0; s < 36; ++s) {
    const int buf = s & 1;
    if (s < 35) {
      if (((s + 1) & 3) == 0) setA((s + 1) >> 2);
      STAGE(buf ^ 1);
      asm volatile("s_waitcnt vmcnt(8)" ::: "memory");
    } else {
      asm volatile("s_waitcnt vmcnt(0)" ::: "memory");
    }
    __builtin_amdgcn_s_barrier();
    __builtin_amdgcn_sched_barrier(0);
    COMPUTE(buf);
    asm volatile("s_waitcnt lgkmcnt(0)" ::: "memory");
    __builtin_amdgcn_s_barrier();
    __builtin_amdgcn_sched_barrier(0);
  }

#pragma unroll
  for (int fm = 0; fm < 4; ++fm)
#pragma unroll
    for (int fn = 0; fn < 4; ++fn) {
      int col = n0 + wn * 64 + fn * 16 + ln;
      float bb = bias[col];
#pragma unroll
      for (int r = 0; r < 4; ++r) {
        int row = m0 + wm * 64 + fm * 16 + g * 4 + r;
        kqv[(size_t)row * 1536 + col] = f2bf(acc[fm][fn][r] + bb);
      }
    }
}

// ---------------- GEMM BN=64: C[M][N] = A[M][K].B[N][K]^T, tile 128x64, 4 waves ----------------
// ASPLIT: A is the attn partials [2][8192][512], K-chunk ch = kt>>9 (row stride 512).
// EPI 2: f32 out, + bias[col] + resid;  EPI 3: bf16 out, + bias[col], LeakyReLU(0.1)
template <int EPI, bool ASPLIT>
__global__ __launch_bounds__(256) void k_gemm64(const unsigned short* __restrict__ A,
                                                const unsigned short* __restrict__ B,
                                                void* __restrict__ Cout,
                                                const float* __restrict__ bias,
                                                const float* __restrict__ resid,
                                                int N, int K) {
  __shared__ __align__(16) unsigned short As[128 * 64];
  __shared__ __align__(16) unsigned short Bs[64 * 64];
  const int tid = threadIdx.x, l = tid & 63, w = tid >> 6;
  const int g = l >> 4, ln = l & 15;
  const int m0 = blockIdx.x * 128, n0 = blockIdx.y * 64;
  const int swz = (l & 7) ^ (l >> 3);
  f32x4 acc[2][4] = {};

  for (int kt = 0; kt < K; kt += 64) {
#pragma unroll
    for (int j = 0; j < 4; ++j) {
      int seg = w * 4 + j;
      int r8 = seg * 8 + (l >> 3);
      const char* src;
      if (ASPLIT)
        src = (const char*)A + (((size_t)(kt >> 9) * 8192 * 512) +
                                (size_t)(m0 + r8) * 512 + (kt & 511) + swz * 8) * 2;
      else
        src = (const char*)A + ((size_t)(m0 + r8) * K + kt + swz * 8) * 2;
      gload_lds16(src, (char*)As + seg * 1024);
    }
#pragma unroll
    for (int j = 0; j < 2; ++j) {
      int seg = w * 2 + j;
      int r8 = seg * 8 + (l >> 3);
      gload_lds16((const char*)B + ((size_t)(n0 + r8) * K + kt + swz * 8) * 2,
                  (char*)Bs + seg * 1024);
    }
    __syncthreads();
#pragma unroll
    for (int kk = 0; kk < 2; ++kk) {
      short8 af[2], bfr[4];
#pragma unroll
      for (int fm = 0; fm < 2; ++fm)
        af[fm] = *(const short8*)((const char*)As + (w * 32 + fm * 16 + ln) * 128 +
                                  (((kk * 4 + g) ^ (ln & 7)) * 16));
#pragma unroll
      for (int fn = 0; fn < 4; ++fn)
        bfr[fn] = *(const short8*)((const char*)Bs + (fn * 16 + ln) * 128 +
                                   (((kk * 4 + g) ^ (ln & 7)) * 16));
#pragma unroll
      for (int fm = 0; fm < 2; ++fm)
#pragma unroll
        for (int fn = 0; fn < 4; ++fn)
          acc[fm][fn] = __builtin_amdgcn_mfma_f32_16x16x32_bf16(af[fm], bfr[fn], acc[fm][fn], 0, 0, 0);
    }
    __syncthreads();
  }

#pragma unroll
  for (int fm = 0; fm < 2; ++fm)
#pragma unroll
    for (int fn = 0; fn < 4; ++fn)
#pragma unroll
      for (int r = 0; r < 4; ++r) {
        int row = m0 + w * 32 + fm * 16 + g * 4 + r;
        int col = n0 + fn * 16 + ln;
        float v = acc[fm][fn][r] + bias[col];
        size_t cidx = (size_t)row * N + col;
        if (EPI == 2) {
          ((float*)Cout)[cidx] = v + resid[cidx];
        } else {
          v = (v > 0.f) ? v : 0.1f * v;
          ((unsigned short*)Cout)[cidx] = f2bf(v);
        }
      }
}

// ---------------- K5: fused attention v6 — head-split waves (unchanged from R7) ----------------
__global__ __launch_bounds__(512, 4) void k_attn(const unsigned short* __restrict__ kqv,
                                                 unsigned short* __restrict__ part) {
  __shared__ __align__(16) unsigned short Qs[16][512];
  __shared__ __align__(16) unsigned short Vlin[16][512];
  __shared__ __align__(16) unsigned short Vs[32][16][16];
  __shared__ __align__(16) float sums[4][2][64][4];
  const int tid = threadIdx.x, l = tid & 63, w = tid >> 6;
  const int g = l >> 4, ln = l & 15;
  const int nt = w & 1, hg = w >> 1;
  const int id = blockIdx.x;
  const int b = id & 7, ng = (id >> 3) & 31, ch = id >> 8;
  const int n0 = ng * 32 + nt * 16;
  const int m_base = ch * 512;
  const size_t rowBase = (size_t)b * 1024;
  const float SC = 1.0f / 1024.0f;

  short8 ak[2][2];
#pragma unroll
  for (int hl = 0; hl < 2; ++hl)
#pragma unroll
    for (int kk = 0; kk < 2; ++kk)
      ak[hl][kk] = *(const short8*)&kqv[(rowBase + n0 + ln) * 1536 +
                                        (hg * 2 + hl) * 64 + kk * 32 + g * 8];

  f32x4 acc[2][4] = {};

  auto STAGE = [&](int m0s) {
#pragma unroll
    for (int i = 0; i < 2; ++i) {
      int row = w * 2 + i;
      const unsigned short* src = kqv + (rowBase + m0s + row) * 1536;
      gload_lds16(src + 512 + ((l ^ (row & 7)) * 8), (char*)Qs + row * 1024);
      gload_lds16(src + 1024 + ((l ^ (row & 7)) * 8), (char*)Vlin + row * 1024);
    }
  };

  STAGE(m_base);
  asm volatile("s_waitcnt vmcnt(0)" ::: "memory");
  __builtin_amdgcn_s_barrier();
  __builtin_amdgcn_sched_barrier(0);

  const uint32_t vsBase = (uint32_t)(uintptr_t)&Vs[0][0][0] + l * 8;

  for (int s = 0; s < 32; ++s) {
    {
      const int tm = l & 15;
#pragma unroll
      for (int i = 0; i < 2; ++i) {
        int tch = (l >> 4) + w * 4 + i * 32;
        short8 tv = *(const short8*)((const char*)Vlin + tm * 1024 +
                                     ((tch ^ (tm & 7)) * 16));
        *(short8*)((char*)Vs + (tch >> 1) * 512 + tm * 32 + (tch & 1) * 16) = tv;
      }
    }

    f32x4 sv[2] = {};
#pragma unroll
    for (int kk = 0; kk < 2; ++kk)
#pragma unroll
      for (int hl = 0; hl < 2; ++hl) {
        int chq = (hg * 2 + hl) * 8 + kk * 4 + g;
        short8 qa = *(const short8*)((const char*)Qs + ln * 1024 +
                                     ((chq ^ (ln & 7)) * 16));
        sv[hl] = __builtin_amdgcn_mfma_f32_16x16x32_bf16(qa, ak[hl][kk], sv[hl], 0, 0, 0);
      }

    f32x4 e0, e1, ps;
#pragma unroll
    for (int j = 0; j < 4; ++j) {
      e0[j] = __expf(sv[0][j] * SC);
      e1[j] = __expf(sv[1][j] * SC);
      ps[j] = e0[j] + e1[j];
    }
    *(f32x4*)&sums[hg][nt][l][0] = ps;
    asm volatile("s_waitcnt lgkmcnt(0)" ::: "memory");
    __builtin_amdgcn_s_barrier();
    __builtin_amdgcn_sched_barrier(0);

    if (s < 31) STAGE(m_base + (s + 1) * 16);

    f32x4 tot = ps;
#pragma unroll
    for (int d = 1; d < 4; ++d) {
      f32x4 o = *(const f32x4*)&sums[(hg + d) & 3][nt][l][0];
      tot[0] += o[0]; tot[1] += o[1]; tot[2] += o[2]; tot[3] += o[3];
    }
    f32x4 inv;
#pragma unroll
    for (int j = 0; j < 4; ++j) inv[j] = 1.0f / tot[j];

    s16x4 vf[8];
#pragma unroll
    for (int hl = 0; hl < 2; ++hl) {
      uint32_t ah = vsBase + (hg * 2 + hl) * 2048;
      asm volatile("ds_read_b64_tr_b16 %0, %1" : "=v"(vf[hl * 4 + 0]) : "v"(ah));
      asm volatile("ds_read_b64_tr_b16 %0, %1 offset:512" : "=v"(vf[hl * 4 + 1]) : "v"(ah));
      asm volatile("ds_read_b64_tr_b16 %0, %1 offset:1024" : "=v"(vf[hl * 4 + 2]) : "v"(ah));
      asm volatile("ds_read_b64_tr_b16 %0, %1 offset:1536" : "=v"(vf[hl * 4 + 3]) : "v"(ah));
    }
    asm volatile("s_waitcnt lgkmcnt(0)" ::: "memory");
    __builtin_amdgcn_sched_barrier(0);
    union { uint32_t u[2]; s16x4 v4; } pc0, pc1;
    pc0.u[0] = pkbf(e0[0] * inv[0], e0[1] * inv[1]);
    pc0.u[1] = pkbf(e0[2] * inv[2], e0[3] * inv[3]);
    pc1.u[0] = pkbf(e1[0] * inv[0], e1[1] * inv[1]);
    pc1.u[1] = pkbf(e1[2] * inv[2], e1[3] * inv[3]);
#pragma unroll
    for (int cf = 0; cf < 4; ++cf) {
      acc[0][cf] = MFMA16(vf[cf], pc0.v4, acc[0][cf]);
      acc[1][cf] = MFMA16(vf[4 + cf], pc1.v4, acc[1][cf]);
    }

    asm volatile("s_waitcnt vmcnt(0)" ::: "memory");
    __builtin_amdgcn_s_barrier();
    __builtin_amdgcn_sched_barrier(0);
  }

  const size_t outBase = (size_t)ch * 8192 * 512 + (rowBase + n0 + ln) * 512;
#pragma unroll
  for (int hl = 0; hl < 2; ++hl)
#pragma unroll
    for (int cf = 0; cf < 4; ++cf)
#pragma unroll
      for (int r2 = 0; r2 < 2; ++r2) {
        int c = (hg * 2 + hl) * 64 + cf * 16 + g * 4 + r2 * 2;
        uint32_t u = (uint32_t)f2bf(acc[hl][cf][2 * r2]) |
                     ((uint32_t)f2bf(acc[hl][cf][2 * r2 + 1]) << 16);
        *(uint32_t*)&part[outBase + c] = u;
      }
}

// ---------------- K6: LayerNorm over rows of [8192][256] -> f32 + bf16 ----------------
__global__ __launch_bounds__(256) void k_ln0(const float* __restrict__ in,
                                             const float* __restrict__ g,
                                             const float* __restrict__ bta,
                                             float* __restrict__ out_f,
                                             unsigned short* __restrict__ out_b) {
  const int l = threadIdx.x & 63, w = threadIdx.x >> 6;
  const size_t row = (size_t)blockIdx.x * 4 + w;
  float4 xv = *(const float4*)(in + row * 256 + l * 4);
  float s = xv.x + xv.y + xv.z + xv.w;
  float q = xv.x * xv.x + xv.y * xv.y + xv.z * xv.z + xv.w * xv.w;
#pragma unroll
  for (int o = 1; o < 64; o <<= 1) {
    s += __shfl_xor(s, o, 64);
    q += __shfl_xor(q, o, 64);
  }
  float mu = s * (1.0f / 256.0f);
  float var = q * (1.0f / 256.0f) - mu * mu;
  float rstd = rsqrtf(var + 1e-5f);
  float4 gv = *(const float4*)(g + l * 4);
  float4 bv = *(const float4*)(bta + l * 4);
  float o0 = (xv.x - mu) * rstd * gv.x + bv.x;
  float o1 = (xv.y - mu) * rstd * gv.y + bv.y;
  float o2 = (xv.z - mu) * rstd * gv.z + bv.z;
  float o3 = (xv.w - mu) * rstd * gv.w + bv.w;
  *(float4*)(out_f + row * 256 + l * 4) = make_float4(o0, o1, o2, o3);
  uint32_t lo = (uint32_t)f2bf(o0) | ((uint32_t)f2bf(o1) << 16);
  uint32_t hi = (uint32_t)f2bf(o2) | ((uint32_t)f2bf(o3) << 16);
  *(uint2*)(out_b + row * 256 + l * 4) = make_uint2(lo, hi);
}

// ---------------- K7: fused FFN2 + bias + resid + LayerNorm + transposed output ----------------
// Tile 32 rows x 256 cols (full row per block -> LN local). Grid 256 blocks.
// h2 = h1 @ W2^T + b2 + addnf; out = LN(h2) written transposed to d_out [8][256][1024].
__global__ __launch_bounds__(256) void k_ffn2out(const unsigned short* __restrict__ h1,
                                                 const unsigned short* __restrict__ W2b,
                                                 const float* __restrict__ b2,
                                                 const float* __restrict__ addnf,
                                                 const float* __restrict__ lg,
                                                 const float* __restrict__ lb,
                                                 float* __restrict__ out) {
  __shared__ __align__(16) unsigned short As[32 * 64];    // 4KB
  __shared__ __align__(16) unsigned short Bs[256 * 64];   // 32KB
  __shared__ __align__(16) float Tt[256][33];             // 33.8KB transpose staging
  __shared__ float rsum[4][32][2];                        // cross-wave LN partials
  const int tid = threadIdx.x, l = tid & 63, w = tid >> 6;
  const int g4 = l >> 4, ln = l & 15;
  const int m0 = blockIdx.x * 32;
  const int swz = (l & 7) ^ (l >> 3);
  f32x4 acc[2][4] = {};

  for (int kt = 0; kt < 256; kt += 64) {
    // A: 32 rows x 64 k (1 gload/thread)
    gload_lds16((const char*)h1 + ((size_t)(m0 + w * 8 + (l >> 3)) * 256 + kt + swz * 8) * 2,
                (char*)As + w * 1024);
    // B: 256 rows x 64 k (8 gloads/thread)
#pragma unroll
    for (int j = 0; j < 8; ++j) {
      int seg = w * 8 + j;
      gload_lds16((const char*)W2b + ((size_t)(seg * 8 + (l >> 3)) * 256 + kt + swz * 8) * 2,
                  (char*)Bs + seg * 1024);
    }
    __syncthreads();
#pragma unroll
    for (int kk = 0; kk < 2; ++kk) {
      short8 af[2], bfr[4];
#pragma unroll
      for (int fm = 0; fm < 2; ++fm)
        af[fm] = *(const short8*)((const char*)As + (fm * 16 + ln) * 128 +
                                  (((kk * 4 + g4) ^ (ln & 7)) * 16));
#pragma unroll
      for (int fn = 0; fn < 4; ++fn)
        bfr[fn] = *(const short8*)((const char*)Bs + (w * 64 + fn * 16 + ln) * 128 +
                                   (((kk * 4 + g4) ^ (ln & 7)) * 16));
#pragma unroll
      for (int fm = 0; fm < 2; ++fm)
#pragma unroll
        for (int fn = 0; fn < 4; ++fn)
          acc[fm][fn] = __builtin_amdgcn_mfma_f32_16x16x32_bf16(af[fm], bfr[fn], acc[fm][fn], 0, 0, 0);
    }
    __syncthreads();
  }

  // bias + residual; per-row partial sums; cross-lane (16) + cross-wave (4) reduce
  float vals[2][4][4];  // [fm][fn][r]
#pragma unroll
  for (int fm = 0; fm < 2; ++fm)
#pragma unroll
    for (int r = 0; r < 4; ++r) {
      int row_l = fm * 16 + g4 * 4 + r;
      float s = 0.f, q = 0.f;
#pragma unroll
      for (int fn = 0; fn < 4; ++fn) {
        int col = w * 64 + fn * 16 + ln;
        float v = acc[fm][fn][r] + b2[col] + addnf[(size_t)(m0 + row_l) * 256 + col];
        vals[fm][fn][r] = v;
        s += v;
        q += v * v;
      }
#pragma unroll
      for (int o = 1; o < 16; o <<= 1) {
        s += __shfl_xor(s, o, 64);
        q += __shfl_xor(q, o, 64);
      }
      if (ln == 0) {
        rsum[w][row_l][0] = s;
        rsum[w][row_l][1] = q;
      }
    }
  __syncthreads();

#pragma unroll
  for (int fm = 0; fm < 2; ++fm)
#pragma unroll
    for (int r = 0; r < 4; ++r) {
      int row_l = fm * 16 + g4 * 4 + r;
      float s = rsum[0][row_l][0] + rsum[1][row_l][0] + rsum[2][row_l][0] + rsum[3][row_l][0];
      float q = rsum[0][row_l][1] + rsum[1][row_l][1] + rsum[2][row_l][1] + rsum[3][row_l][1];
      float mu = s * (1.0f / 256.0f);
      float rstd = rsqrtf(q * (1.0f / 256.0f) - mu * mu + 1e-5f);
#pragma unroll
      for (int fn = 0; fn < 4; ++fn) {
        int col = w * 64 + fn * 16 + ln;
        Tt[col][row_l] = (vals[fm][fn][r] - mu) * rstd * lg[col] + lb[col];
      }
    }
  __syncthreads();

  // transposed coalesced write: out[b][c][n0..n0+32)
  const int bimg = m0 >> 10, nn0 = m0 & 1023;
#pragma unroll
  for (int i = 0; i < 8; ++i) {
    int c = i * 32 + (tid >> 3);
    int ng = (tid & 7) * 4;
    float4 o = make_float4(Tt[c][ng], Tt[c][ng + 1], Tt[c][ng + 2], Tt[c][ng + 3]);
    *(float4*)&out[((size_t)bimg * 256 + c) * 1024 + nn0 + ng] = o;
  }
}

// ---------------- host launcher ----------------
extern "C" void kernel_launch(void* const* d_in, const int* in_sizes, int n_in,
                              void* d_out, int out_size, void* d_ws, size_t ws_size,
                              hipStream_t stream) {
  const float* x     = (const float*)d_in[0];
  const float* Wk    = (const float*)d_in[1];
  const float* bk    = (const float*)d_in[2];
  const float* Wq    = (const float*)d_in[3];
  const float* bq    = (const float*)d_in[4];
  const float* Wv    = (const float*)d_in[5];
  const float* bv    = (const float*)d_in[6];
  const float* Wproj = (const float*)d_in[7];
  const float* bproj = (const float*)d_in[8];
  const float* ln_g  = (const float*)d_in[9];
  const float* ln_b  = (const float*)d_in[10];
  const float* W1    = (const float*)d_in[11];
  const float* b1    = (const float*)d_in[12];
  const float* W2    = (const float*)d_in[13];
  const float* b2    = (const float*)d_in[14];

  char* ws = (char*)d_ws;
  constexpr size_t OFF_XPTB  = 0;                                    // bf16 [8192][256]
  constexpr size_t OFF_XPTF  = OFF_XPTB  + (size_t)8192 * 256 * 2;   // f32  [8192][256]
  constexpr size_t OFF_WPACK = OFF_XPTF  + (size_t)8192 * 256 * 4;   // bf16 [1536][2304]
  constexpr size_t OFF_BIAS  = OFF_WPACK + (size_t)1536 * 2304 * 2;  // f32  [1536]
  constexpr size_t OFF_WPROJ = OFF_BIAS  + (size_t)1536 * 4;         // bf16 [256][1024] (dup K)
  constexpr size_t OFF_W1B   = OFF_WPROJ + (size_t)256 * 1024 * 2;   // bf16 [256][256]
  constexpr size_t OFF_W2B   = OFF_W1B   + (size_t)256 * 256 * 2;    // bf16 [256][256]
  constexpr size_t OFF_PET   = OFF_W2B   + (size_t)256 * 256 * 2;    // f32  [256][32]
  constexpr size_t OFF_ZERO  = OFF_PET   + (size_t)256 * 32 * 4;     // f32  [256] zeros (1KB)
  constexpr size_t OFF_KQV   = OFF_ZERO  + 1024;                     // bf16 [8192][1536]
  constexpr size_t OFF_PART  = OFF_KQV   + (size_t)8192 * 1536 * 2;  // bf16 [2][8192][512]
  constexpr size_t OFF_Y1    = OFF_PART  + (size_t)2 * 8192 * 512 * 2; // f32 [8192][256]
  constexpr size_t OFF_ADDNF = OFF_Y1    + (size_t)8192 * 256 * 4;   // f32
  constexpr size_t OFF_ADDNB = OFF_ADDNF + (size_t)8192 * 256 * 4;   // bf16
  constexpr size_t OFF_H1    = OFF_ADDNB + (size_t)8192 * 256 * 2;   // bf16

  (void)in_sizes; (void)n_in; (void)out_size; (void)ws_size;

  const char* zp = (const char*)(ws + OFF_ZERO);

  k_petab<<<1, 256, 0, stream>>>((float*)(ws + OFF_PET), (float*)(ws + OFF_ZERO));
  k_xpt<<<dim3(8, 32, 8), 256, 0, stream>>>(x, (const float*)(ws + OFF_PET),
                                            (unsigned short*)(ws + OFF_XPTB),
                                            (float*)(ws + OFF_XPTF));
  k_packall<<<14336, 256, 0, stream>>>(Wk, Wq, Wv, bk, bq, bv, Wproj, W1, W2,
                                       (unsigned short*)(ws + OFF_WPACK),
                                       (float*)(ws + OFF_BIAS),
                                       (unsigned short*)(ws + OFF_WPROJ),
                                       (unsigned short*)(ws + OFF_W1B),
                                       (unsigned short*)(ws + OFF_W2B));
  // merged conv K+Q+V -> kqv[8192][1536]
  k_gemm_conv<<<dim3(64, 12), 256, 0, stream>>>(
      (const unsigned short*)(ws + OFF_XPTB), (const unsigned short*)(ws + OFF_WPACK),
      (unsigned short*)(ws + OFF_KQV), (const float*)(ws + OFF_BIAS), zp);
  // fused attention -> partials [2][8192][512]
  k_attn<<<dim3(512), 512, 0, stream>>>((const unsigned short*)(ws + OFF_KQV),
                                        (unsigned short*)(ws + OFF_PART));
  // attproj directly from partials: K=1024 (dup W), + bias + resid(x+pe) -> y1 f32
  k_gemm64<2, true><<<dim3(64, 4), 256, 0, stream>>>(
      (const unsigned short*)(ws + OFF_PART), (const unsigned short*)(ws + OFF_WPROJ),
      ws + OFF_Y1, bproj, (const float*)(ws + OFF_XPTF), 256, 1024);
  k_ln0<<<2048, 256, 0, stream>>>((const float*)(ws + OFF_Y1), ln_g, ln_b,
                                  (float*)(ws + OFF_ADDNF), (unsigned short*)(ws + OFF_ADDNB));
  // FFN1 + LeakyReLU
  k_gemm64<3, false><<<dim3(64, 4), 256, 0, stream>>>(
      (const unsigned short*)(ws + OFF_ADDNB), (const unsigned short*)(ws + OFF_W1B),
      ws + OFF_H1, b1, nullptr, 256, 256);
  // FFN2 + bias + resid + LN + transposed output
  k_ffn2out<<<256, 256, 0, stream>>>((const unsigned short*)(ws + OFF_H1),
                                     (const unsigned short*)(ws + OFF_W2B), b2,
                                     (const float*)(ws + OFF_ADDNF), ln_g, ln_b,
                                     (float*)d_out);
}

// Round 9
// 192.825 us; speedup vs baseline: 1.2909x; 1.0695x over previous
//
#include <hip/hip_runtime.h>
#include <stdint.h>

typedef __attribute__((ext_vector_type(8))) short short8;
typedef __attribute__((ext_vector_type(4))) short s16x4;
typedef __attribute__((ext_vector_type(4))) float f32x4;

#define DEVI __device__ __forceinline__

#if __has_builtin(__builtin_amdgcn_mfma_f32_16x16x16_bf16)
#define MFMA16(a, b, c) __builtin_amdgcn_mfma_f32_16x16x16_bf16(a, b, c, 0, 0, 0)
#else
#define MFMA16(a, b, c) __builtin_amdgcn_mfma_f32_16x16x16bf16_1k(a, b, c, 0, 0, 0)
#endif

DEVI unsigned short f2bf(float f) {
  union { float f; uint32_t u; } v; v.f = f;
  return (unsigned short)((v.u + 0x7fffu + ((v.u >> 16) & 1u)) >> 16);
}

DEVI float bf2f(uint32_t hi16) {
  union { uint32_t u; float f; } v; v.u = hi16;
  return v.f;
}

DEVI uint32_t pkbf(float a, float b) {  // fast RTN pack (positive values)
  union { float f; uint32_t u; } x, y; x.f = a; y.f = b;
  return ((x.u + 0x8000u) >> 16) | (((y.u + 0x8000u) >> 16) << 16);
}

DEVI void gload_lds16(const void* g, void* l) {
  __builtin_amdgcn_global_load_lds(
      (const __attribute__((address_space(1))) uint32_t*)g,
      (__attribute__((address_space(3))) uint32_t*)l, 16, 0, 0);
}

// ---------------- K0: positional encoding table T[256][32] + zero page (1KB) ----------------
__global__ void k_petab(float* __restrict__ T, float* __restrict__ zp) {
  int c = threadIdx.x;
  zp[c] = 0.0f;
  int idx = ((c >= 128) ? c - 128 : c) >> 1;
  float freq = expf(-(float)idx * (logf(10000.0f) / 64.0f));
  for (int p = 0; p < 32; ++p) {
    float ang = (float)p * freq;
    T[c * 32 + p] = (c & 1) ? cosf(ang) : sinf(ang);
  }
}

// ---------------- K1: xpT = (x + pe) transposed to [b*1024+n][256], f32 + bf16 ----------------
__global__ __launch_bounds__(256) void k_xpt(const float* __restrict__ x,
                                             const float* __restrict__ T,
                                             unsigned short* __restrict__ xpt_bf,
                                             float* __restrict__ xpt_f) {
  __shared__ __align__(16) float tile[32][36];
  const int b = blockIdx.z, c0 = blockIdx.x * 32, n0 = blockIdx.y * 32;
  const int t = threadIdx.x;
  {
    const int cl = t >> 3, ng = (t & 7) * 4;
    const int c = c0 + cl;
    float4 v = *(const float4*)(x + ((size_t)b * 256 + c) * 1024 + n0 + ng);
    float p0, p1, p2, p3;
    if (c < 128) {
      p0 = T[c * 32 + ng + 0]; p1 = T[c * 32 + ng + 1];
      p2 = T[c * 32 + ng + 2]; p3 = T[c * 32 + ng + 3];
    } else {
      p0 = p1 = p2 = p3 = T[c * 32 + (n0 >> 5)];
    }
    tile[ng + 0][cl] = v.x + p0;
    tile[ng + 1][cl] = v.y + p1;
    tile[ng + 2][cl] = v.z + p2;
    tile[ng + 3][cl] = v.w + p3;
  }
  __syncthreads();
  {
    const int nl = t >> 3, cg = (t & 7) * 4;
    float o0 = tile[nl][cg + 0], o1 = tile[nl][cg + 1];
    float o2 = tile[nl][cg + 2], o3 = tile[nl][cg + 3];
    size_t row = (size_t)b * 1024 + n0 + nl;
    *(float4*)(xpt_f + row * 256 + c0 + cg) = make_float4(o0, o1, o2, o3);
    uint32_t lo = (uint32_t)f2bf(o0) | ((uint32_t)f2bf(o1) << 16);
    uint32_t hi = (uint32_t)f2bf(o2) | ((uint32_t)f2bf(o3) << 16);
    *(uint2*)(xpt_bf + row * 256 + c0 + cg) = make_uint2(lo, hi);
  }
}

// ---------------- K2: all weight packs in one kernel ----------------
__global__ void k_packall(const float* __restrict__ Wk, const float* __restrict__ Wq,
                          const float* __restrict__ Wv, const float* __restrict__ bk,
                          const float* __restrict__ bq, const float* __restrict__ bv,
                          const float* __restrict__ Wproj, const float* __restrict__ W1,
                          const float* __restrict__ W2, unsigned short* __restrict__ Wpack,
                          float* __restrict__ bias_kqv, unsigned short* __restrict__ WprojP,
                          unsigned short* __restrict__ W1b, unsigned short* __restrict__ W2b) {
  int bid = blockIdx.x;
  if (bid < 13824) {
    int i = bid * 256 + threadIdx.x;
    if (i >= 1536 * 2304) return;
    int o = i / 2304, kn = i % 2304;
    int ci = kn & 255, khw = kn >> 8;
    const float* src = (o < 512) ? Wk : ((o < 1024) ? Wq : Wv);
    int oo = o & 511;
    Wpack[i] = f2bf(src[((size_t)oo * 256 + ci) * 9 + khw]);
  } else {
    int i = (bid - 13824) * 256 + threadIdx.x;  // [0, 131072)
    if (i < 1536)
      bias_kqv[i] = (i < 512) ? bk[i] : ((i < 1024) ? bq[i - 512] : bv[i - 1024]);
    {
      int j = i >> 9, f = i & 511;
      int h = f >> 6, c = f & 63;
      unsigned short v = f2bf(Wproj[(size_t)j * 512 + c * 8 + h]);
      WprojP[(size_t)j * 1024 + f] = v;        // K-chunk 0
      WprojP[(size_t)j * 1024 + 512 + f] = v;  // K-chunk 1 (duplicated: O = O0 + O1)
    }
    if (i < 65536) {
      W1b[i] = f2bf(W1[i]);
      W2b[i] = f2bf(W2[i]);
    }
  }
}

// ---------------- merged conv GEMM v4: kqv[8192][1536] = im2col(xpt).Wpack^T ----------------
// Tile 128m x 192n, BK=64, 4 waves (2x2, 64x96 each), 80KB dbuf LDS (2 blocks/CU),
// grid 64x8 = 512 blocks = exactly 2/CU. Slim addressing: 1 B-base + uniform adds,
// A = pAbase[4] + per-tap validity mask (cndmask to zero page). Counted vmcnt(10).
__global__ __launch_bounds__(256, 2) void k_gemm_conv(const unsigned short* __restrict__ xpt,
                                                      const unsigned short* __restrict__ Wp,
                                                      unsigned short* __restrict__ kqv,
                                                      const float* __restrict__ bias,
                                                      const char* __restrict__ zp) {
  __shared__ __align__(16) unsigned short As[2][128 * 64];  // 32KB
  __shared__ __align__(16) unsigned short Bs[2][192 * 64];  // 48KB
  const int tid = threadIdx.x, l = tid & 63, w = tid >> 6;
  const int wm = w >> 1, wn = w & 1, g = l >> 4, ln = l & 15;
  const int m0 = blockIdx.x * 128, n0 = blockIdx.y * 192;
  const int swz = (l & 7) ^ (l >> 3);

  const char* pAbase[4];
#pragma unroll
  for (int j = 0; j < 4; ++j) {
    int r = m0 + (w * 4 + j) * 8 + (l >> 3);
    pAbase[j] = (const char*)xpt + ((size_t)r * 256 + swz * 8) * 2;
  }
  const char* pB0 = (const char*)Wp +
                    ((size_t)(n0 + w * 48 + (l >> 3)) * 2304 + swz * 8) * 2;

  f32x4 acc[4][6] = {};
  int vmask = 0;
  int aoff = 0;

  auto setTap = [&](int tap) {
    int d3 = (tap * 11) >> 5;  // tap/3
    int dy = d3 - 1, dx = tap - d3 * 3 - 1;
    aoff = (dy * 32 + dx) * 512;
    int m = 0;
#pragma unroll
    for (int j = 0; j < 4; ++j) {
      int r = m0 + (w * 4 + j) * 8 + (l >> 3);
      int y = ((r >> 5) & 31) + dy;
      int x = (r & 31) + dx;
      if (((unsigned)y < 32u) && ((unsigned)x < 32u)) m |= (1 << j);
    }
    vmask = m;
  };

  auto STAGE = [&](int buf, int kb) {
#pragma unroll
    for (int j = 0; j < 4; ++j) {
      const char* a = (vmask & (1 << j)) ? (pAbase[j] + aoff) : zp;
      gload_lds16(a, (char*)As + buf * 16384 + (w * 4 + j) * 1024);
    }
#pragma unroll
    for (int j = 0; j < 6; ++j) {
      gload_lds16(pB0 + j * 36864 + kb, (char*)Bs + buf * 24576 + (w * 6 + j) * 1024);
    }
  };

  auto COMPUTE = [&](int buf) {
    const char* Ab2 = (const char*)As + buf * 16384;
    const char* Bb2 = (const char*)Bs + buf * 24576;
#pragma unroll
    for (int kk = 0; kk < 2; ++kk) {
      short8 af[4], bfr[6];
#pragma unroll
      for (int fm = 0; fm < 4; ++fm)
        af[fm] = *(const short8*)(Ab2 + (wm * 64 + fm * 16 + ln) * 128 +
                                  (((kk * 4 + g) ^ (ln & 7)) * 16));
#pragma unroll
      for (int fn = 0; fn < 6; ++fn)
        bfr[fn] = *(const short8*)(Bb2 + (wn * 96 + fn * 16 + ln) * 128 +
                                   (((kk * 4 + g) ^ (ln & 7)) * 16));
#pragma unroll
      for (int fm = 0; fm < 4; ++fm)
#pragma unroll
        for (int fn = 0; fn < 6; ++fn)
          acc[fm][fn] = __builtin_amdgcn_mfma_f32_16x16x32_bf16(af[fm], bfr[fn], acc[fm][fn], 0, 0, 0);
    }
  };

  setTap(0);
  STAGE(0, 0);
  aoff += 128;
  int kb = 128;
  for (int s = 0; s < 36; ++s) {
    const int buf = s & 1;
    if (s < 35) {
      if (((s + 1) & 3) == 0) setTap((s + 1) >> 2);
      STAGE(buf ^ 1, kb);
      kb += 128;
      aoff += 128;
      asm volatile("s_waitcnt vmcnt(10)" ::: "memory");
    } else {
      asm volatile("s_waitcnt vmcnt(0)" ::: "memory");
    }
    __builtin_amdgcn_s_barrier();
    __builtin_amdgcn_sched_barrier(0);
    COMPUTE(buf);
    asm volatile("s_waitcnt lgkmcnt(0)" ::: "memory");
    __builtin_amdgcn_s_barrier();
    __builtin_amdgcn_sched_barrier(0);
  }

#pragma unroll
  for (int fm = 0; fm < 4; ++fm)
#pragma unroll
    for (int fn = 0; fn < 6; ++fn) {
      int col = n0 + wn * 96 + fn * 16 + ln;
      float bb = bias[col];
#pragma unroll
      for (int r = 0; r < 4; ++r) {
        int row = m0 + wm * 64 + fm * 16 + g * 4 + r;
        kqv[(size_t)row * 1536 + col] = f2bf(acc[fm][fn][r] + bb);
      }
    }
}

// ---------------- GEMM BN=64 (FFN1): bf16 out, + bias[col], LeakyReLU(0.1) ----------------
__global__ __launch_bounds__(256) void k_ffn1(const unsigned short* __restrict__ A,
                                              const unsigned short* __restrict__ B,
                                              unsigned short* __restrict__ Cout,
                                              const float* __restrict__ bias) {
  __shared__ __align__(16) unsigned short As[128 * 64];
  __shared__ __align__(16) unsigned short Bs[64 * 64];
  const int tid = threadIdx.x, l = tid & 63, w = tid >> 6;
  const int g = l >> 4, ln = l & 15;
  const int m0 = blockIdx.x * 128, n0 = blockIdx.y * 64;
  const int swz = (l & 7) ^ (l >> 3);
  f32x4 acc[2][4] = {};

  for (int kt = 0; kt < 256; kt += 64) {
#pragma unroll
    for (int j = 0; j < 4; ++j) {
      int seg = w * 4 + j;
      int r8 = seg * 8 + (l >> 3);
      gload_lds16((const char*)A + ((size_t)(m0 + r8) * 256 + kt + swz * 8) * 2,
                  (char*)As + seg * 1024);
    }
#pragma unroll
    for (int j = 0; j < 2; ++j) {
      int seg = w * 2 + j;
      int r8 = seg * 8 + (l >> 3);
      gload_lds16((const char*)B + ((size_t)(n0 + r8) * 256 + kt + swz * 8) * 2,
                  (char*)Bs + seg * 1024);
    }
    __syncthreads();
#pragma unroll
    for (int kk = 0; kk < 2; ++kk) {
      short8 af[2], bfr[4];
#pragma unroll
      for (int fm = 0; fm < 2; ++fm)
        af[fm] = *(const short8*)((const char*)As + (w * 32 + fm * 16 + ln) * 128 +
                                  (((kk * 4 + g) ^ (ln & 7)) * 16));
#pragma unroll
      for (int fn = 0; fn < 4; ++fn)
        bfr[fn] = *(const short8*)((const char*)Bs + (fn * 16 + ln) * 128 +
                                   (((kk * 4 + g) ^ (ln & 7)) * 16));
#pragma unroll
      for (int fm = 0; fm < 2; ++fm)
#pragma unroll
        for (int fn = 0; fn < 4; ++fn)
          acc[fm][fn] = __builtin_amdgcn_mfma_f32_16x16x32_bf16(af[fm], bfr[fn], acc[fm][fn], 0, 0, 0);
    }
    __syncthreads();
  }

#pragma unroll
  for (int fm = 0; fm < 2; ++fm)
#pragma unroll
    for (int fn = 0; fn < 4; ++fn)
#pragma unroll
      for (int r = 0; r < 4; ++r) {
        int row = m0 + w * 32 + fm * 16 + g * 4 + r;
        int col = n0 + fn * 16 + ln;
        float v = acc[fm][fn][r] + bias[col];
        v = (v > 0.f) ? v : 0.1f * v;
        Cout[(size_t)row * 256 + col] = f2bf(v);
      }
}

// ---------------- K5: fused attention v6 — head-split waves (unchanged) ----------------
__global__ __launch_bounds__(512, 4) void k_attn(const unsigned short* __restrict__ kqv,
                                                 unsigned short* __restrict__ part) {
  __shared__ __align__(16) unsigned short Qs[16][512];
  __shared__ __align__(16) unsigned short Vlin[16][512];
  __shared__ __align__(16) unsigned short Vs[32][16][16];
  __shared__ __align__(16) float sums[4][2][64][4];
  const int tid = threadIdx.x, l = tid & 63, w = tid >> 6;
  const int g = l >> 4, ln = l & 15;
  const int nt = w & 1, hg = w >> 1;
  const int id = blockIdx.x;
  const int b = id & 7, ng = (id >> 3) & 31, ch = id >> 8;
  const int n0 = ng * 32 + nt * 16;
  const int m_base = ch * 512;
  const size_t rowBase = (size_t)b * 1024;
  const float SC = 1.0f / 1024.0f;

  short8 ak[2][2];
#pragma unroll
  for (int hl = 0; hl < 2; ++hl)
#pragma unroll
    for (int kk = 0; kk < 2; ++kk)
      ak[hl][kk] = *(const short8*)&kqv[(rowBase + n0 + ln) * 1536 +
                                        (hg * 2 + hl) * 64 + kk * 32 + g * 8];

  f32x4 acc[2][4] = {};

  auto STAGE = [&](int m0s) {
#pragma unroll
    for (int i = 0; i < 2; ++i) {
      int row = w * 2 + i;
      const unsigned short* src = kqv + (rowBase + m0s + row) * 1536;
      gload_lds16(src + 512 + ((l ^ (row & 7)) * 8), (char*)Qs + row * 1024);
      gload_lds16(src + 1024 + ((l ^ (row & 7)) * 8), (char*)Vlin + row * 1024);
    }
  };

  STAGE(m_base);
  asm volatile("s_waitcnt vmcnt(0)" ::: "memory");
  __builtin_amdgcn_s_barrier();
  __builtin_amdgcn_sched_barrier(0);

  const uint32_t vsBase = (uint32_t)(uintptr_t)&Vs[0][0][0] + l * 8;

  for (int s = 0; s < 32; ++s) {
    {
      const int tm = l & 15;
#pragma unroll
      for (int i = 0; i < 2; ++i) {
        int tch = (l >> 4) + w * 4 + i * 32;
        short8 tv = *(const short8*)((const char*)Vlin + tm * 1024 +
                                     ((tch ^ (tm & 7)) * 16));
        *(short8*)((char*)Vs + (tch >> 1) * 512 + tm * 32 + (tch & 1) * 16) = tv;
      }
    }

    f32x4 sv[2] = {};
#pragma unroll
    for (int kk = 0; kk < 2; ++kk)
#pragma unroll
      for (int hl = 0; hl < 2; ++hl) {
        int chq = (hg * 2 + hl) * 8 + kk * 4 + g;
        short8 qa = *(const short8*)((const char*)Qs + ln * 1024 +
                                     ((chq ^ (ln & 7)) * 16));
        sv[hl] = __builtin_amdgcn_mfma_f32_16x16x32_bf16(qa, ak[hl][kk], sv[hl], 0, 0, 0);
      }

    f32x4 e0, e1, ps;
#pragma unroll
    for (int j = 0; j < 4; ++j) {
      e0[j] = __expf(sv[0][j] * SC);
      e1[j] = __expf(sv[1][j] * SC);
      ps[j] = e0[j] + e1[j];
    }
    *(f32x4*)&sums[hg][nt][l][0] = ps;
    asm volatile("s_waitcnt lgkmcnt(0)" ::: "memory");
    __builtin_amdgcn_s_barrier();
    __builtin_amdgcn_sched_barrier(0);

    if (s < 31) STAGE(m_base + (s + 1) * 16);

    f32x4 tot = ps;
#pragma unroll
    for (int d = 1; d < 4; ++d) {
      f32x4 o = *(const f32x4*)&sums[(hg + d) & 3][nt][l][0];
      tot[0] += o[0]; tot[1] += o[1]; tot[2] += o[2]; tot[3] += o[3];
    }
    f32x4 inv;
#pragma unroll
    for (int j = 0; j < 4; ++j) inv[j] = 1.0f / tot[j];

    s16x4 vf[8];
#pragma unroll
    for (int hl = 0; hl < 2; ++hl) {
      uint32_t ah = vsBase + (hg * 2 + hl) * 2048;
      asm volatile("ds_read_b64_tr_b16 %0, %1" : "=v"(vf[hl * 4 + 0]) : "v"(ah));
      asm volatile("ds_read_b64_tr_b16 %0, %1 offset:512" : "=v"(vf[hl * 4 + 1]) : "v"(ah));
      asm volatile("ds_read_b64_tr_b16 %0, %1 offset:1024" : "=v"(vf[hl * 4 + 2]) : "v"(ah));
      asm volatile("ds_read_b64_tr_b16 %0, %1 offset:1536" : "=v"(vf[hl * 4 + 3]) : "v"(ah));
    }
    asm volatile("s_waitcnt lgkmcnt(0)" ::: "memory");
    __builtin_amdgcn_sched_barrier(0);
    union { uint32_t u[2]; s16x4 v4; } pc0, pc1;
    pc0.u[0] = pkbf(e0[0] * inv[0], e0[1] * inv[1]);
    pc0.u[1] = pkbf(e0[2] * inv[2], e0[3] * inv[3]);
    pc1.u[0] = pkbf(e1[0] * inv[0], e1[1] * inv[1]);
    pc1.u[1] = pkbf(e1[2] * inv[2], e1[3] * inv[3]);
#pragma unroll
    for (int cf = 0; cf < 4; ++cf) {
      acc[0][cf] = MFMA16(vf[cf], pc0.v4, acc[0][cf]);
      acc[1][cf] = MFMA16(vf[4 + cf], pc1.v4, acc[1][cf]);
    }

    asm volatile("s_waitcnt vmcnt(0)" ::: "memory");
    __builtin_amdgcn_s_barrier();
    __builtin_amdgcn_sched_barrier(0);
  }

  const size_t outBase = (size_t)ch * 8192 * 512 + (rowBase + n0 + ln) * 512;
#pragma unroll
  for (int hl = 0; hl < 2; ++hl)
#pragma unroll
    for (int cf = 0; cf < 4; ++cf)
#pragma unroll
      for (int r2 = 0; r2 < 2; ++r2) {
        int c = (hg * 2 + hl) * 64 + cf * 16 + g * 4 + r2 * 2;
        uint32_t u = (uint32_t)f2bf(acc[hl][cf][2 * r2]) |
                     ((uint32_t)f2bf(acc[hl][cf][2 * r2 + 1]) << 16);
        *(uint32_t*)&part[outBase + c] = u;
      }
}

// ---------------- K6: fused attproj + bias + resid(x+pe) + LayerNorm -> addnf f32 + addnb bf16 ----
// Tile 32 rows x 256 cols (full row per block -> LN local), K=1024 from attn partials (split).
__global__ __launch_bounds__(256) void k_projln(const unsigned short* __restrict__ part,
                                                const unsigned short* __restrict__ Wp,
                                                const float* __restrict__ bias,
                                                const float* __restrict__ resid,
                                                const float* __restrict__ lg,
                                                const float* __restrict__ lb,
                                                float* __restrict__ out_f,
                                                unsigned short* __restrict__ out_b) {
  __shared__ __align__(16) unsigned short As[32 * 64];
  __shared__ __align__(16) unsigned short Bs[256 * 64];
  __shared__ float rsum[4][32][2];
  const int tid = threadIdx.x, l = tid & 63, w = tid >> 6;
  const int g4 = l >> 4, ln = l & 15;
  const int m0 = blockIdx.x * 32;
  const int swz = (l & 7) ^ (l >> 3);
  f32x4 acc[2][4] = {};

  for (int kt = 0; kt < 1024; kt += 64) {
    gload_lds16((const char*)part + (((size_t)(kt >> 9) * 8192 * 512) +
                                     (size_t)(m0 + w * 8 + (l >> 3)) * 512 +
                                     (kt & 511) + swz * 8) * 2,
                (char*)As + w * 1024);
#pragma unroll
    for (int j = 0; j < 8; ++j) {
      int seg = w * 8 + j;
      gload_lds16((const char*)Wp + ((size_t)(seg * 8 + (l >> 3)) * 1024 + kt + swz * 8) * 2,
                  (char*)Bs + seg * 1024);
    }
    __syncthreads();
#pragma unroll
    for (int kk = 0; kk < 2; ++kk) {
      short8 af[2], bfr[4];
#pragma unroll
      for (int fm = 0; fm < 2; ++fm)
        af[fm] = *(const short8*)((const char*)As + (fm * 16 + ln) * 128 +
                                  (((kk * 4 + g4) ^ (ln & 7)) * 16));
#pragma unroll
      for (int fn = 0; fn < 4; ++fn)
        bfr[fn] = *(const short8*)((const char*)Bs + (w * 64 + fn * 16 + ln) * 128 +
                                   (((kk * 4 + g4) ^ (ln & 7)) * 16));
#pragma unroll
      for (int fm = 0; fm < 2; ++fm)
#pragma unroll
        for (int fn = 0; fn < 4; ++fn)
          acc[fm][fn] = __builtin_amdgcn_mfma_f32_16x16x32_bf16(af[fm], bfr[fn], acc[fm][fn], 0, 0, 0);
    }
    __syncthreads();
  }

  float vals[2][4][4];
#pragma unroll
  for (int fm = 0; fm < 2; ++fm)
#pragma unroll
    for (int r = 0; r < 4; ++r) {
      int row_l = fm * 16 + g4 * 4 + r;
      float s = 0.f, q = 0.f;
#pragma unroll
      for (int fn = 0; fn < 4; ++fn) {
        int col = w * 64 + fn * 16 + ln;
        float v = acc[fm][fn][r] + bias[col] + resid[(size_t)(m0 + row_l) * 256 + col];
        vals[fm][fn][r] = v;
        s += v;
        q += v * v;
      }
#pragma unroll
      for (int o = 1; o < 16; o <<= 1) {
        s += __shfl_xor(s, o, 64);
        q += __shfl_xor(q, o, 64);
      }
      if (ln == 0) {
        rsum[w][row_l][0] = s;
        rsum[w][row_l][1] = q;
      }
    }
  __syncthreads();

#pragma unroll
  for (int fm = 0; fm < 2; ++fm)
#pragma unroll
    for (int r = 0; r < 4; ++r) {
      int row_l = fm * 16 + g4 * 4 + r;
      float s = rsum[0][row_l][0] + rsum[1][row_l][0] + rsum[2][row_l][0] + rsum[3][row_l][0];
      float q = rsum[0][row_l][1] + rsum[1][row_l][1] + rsum[2][row_l][1] + rsum[3][row_l][1];
      float mu = s * (1.0f / 256.0f);
      float rstd = rsqrtf(q * (1.0f / 256.0f) - mu * mu + 1e-5f);
      size_t rowOff = (size_t)(m0 + row_l) * 256;
#pragma unroll
      for (int fn = 0; fn < 4; ++fn) {
        int col = w * 64 + fn * 16 + ln;
        float o = (vals[fm][fn][r] - mu) * rstd * lg[col] + lb[col];
        out_f[rowOff + col] = o;
        out_b[rowOff + col] = f2bf(o);
      }
    }
}

// ---------------- K7: fused FFN2 + bias + resid + LayerNorm + transposed output ----------------
__global__ __launch_bounds__(256) void k_ffn2out(const unsigned short* __restrict__ h1,
                                                 const unsigned short* __restrict__ W2b,
                                                 const float* __restrict__ b2,
                                                 const float* __restrict__ addnf,
                                                 const float* __restrict__ lg,
                                                 const float* __restrict__ lb,
                                                 float* __restrict__ out) {
  __shared__ __align__(16) unsigned short As[32 * 64];
  __shared__ __align__(16) unsigned short Bs[256 * 64];
  __shared__ __align__(16) float Tt[256][33];
  __shared__ float rsum[4][32][2];
  const int tid = threadIdx.x, l = tid & 63, w = tid >> 6;
  const int g4 = l >> 4, ln = l & 15;
  const int m0 = blockIdx.x * 32;
  const int swz = (l & 7) ^ (l >> 3);
  f32x4 acc[2][4] = {};

  for (int kt = 0; kt < 256; kt += 64) {
    gload_lds16((const char*)h1 + ((size_t)(m0 + w * 8 + (l >> 3)) * 256 + kt + swz * 8) * 2,
                (char*)As + w * 1024);
#pragma unroll
    for (int j = 0; j < 8; ++j) {
      int seg = w * 8 + j;
      gload_lds16((const char*)W2b + ((size_t)(seg * 8 + (l >> 3)) * 256 + kt + swz * 8) * 2,
                  (char*)Bs + seg * 1024);
    }
    __syncthreads();
#pragma unroll
    for (int kk = 0; kk < 2; ++kk) {
      short8 af[2], bfr[4];
#pragma unroll
      for (int fm = 0; fm < 2; ++fm)
        af[fm] = *(const short8*)((const char*)As + (fm * 16 + ln) * 128 +
                                  (((kk * 4 + g4) ^ (ln & 7)) * 16));
#pragma unroll
      for (int fn = 0; fn < 4; ++fn)
        bfr[fn] = *(const short8*)((const char*)Bs + (w * 64 + fn * 16 + ln) * 128 +
                                   (((kk * 4 + g4) ^ (ln & 7)) * 16));
#pragma unroll
      for (int fm = 0; fm < 2; ++fm)
#pragma unroll
        for (int fn = 0; fn < 4; ++fn)
          acc[fm][fn] = __builtin_amdgcn_mfma_f32_16x16x32_bf16(af[fm], bfr[fn], acc[fm][fn], 0, 0, 0);
    }
    __syncthreads();
  }

  float vals[2][4][4];
#pragma unroll
  for (int fm = 0; fm < 2; ++fm)
#pragma unroll
    for (int r = 0; r < 4; ++r) {
      int row_l = fm * 16 + g4 * 4 + r;
      float s = 0.f, q = 0.f;
#pragma unroll
      for (int fn = 0; fn < 4; ++fn) {
        int col = w * 64 + fn * 16 + ln;
        float v = acc[fm][fn][r] + b2[col] + addnf[(size_t)(m0 + row_l) * 256 + col];
        vals[fm][fn][r] = v;
        s += v;
        q += v * v;
      }
#pragma unroll
      for (int o = 1; o < 16; o <<= 1) {
        s += __shfl_xor(s, o, 64);
        q += __shfl_xor(q, o, 64);
      }
      if (ln == 0) {
        rsum[w][row_l][0] = s;
        rsum[w][row_l][1] = q;
      }
    }
  __syncthreads();

#pragma unroll
  for (int fm = 0; fm < 2; ++fm)
#pragma unroll
    for (int r = 0; r < 4; ++r) {
      int row_l = fm * 16 + g4 * 4 + r;
      float s = rsum[0][row_l][0] + rsum[1][row_l][0] + rsum[2][row_l][0] + rsum[3][row_l][0];
      float q = rsum[0][row_l][1] + rsum[1][row_l][1] + rsum[2][row_l][1] + rsum[3][row_l][1];
      float mu = s * (1.0f / 256.0f);
      float rstd = rsqrtf(q * (1.0f / 256.0f) - mu * mu + 1e-5f);
#pragma unroll
      for (int fn = 0; fn < 4; ++fn) {
        int col = w * 64 + fn * 16 + ln;
        Tt[col][row_l] = (vals[fm][fn][r] - mu) * rstd * lg[col] + lb[col];
      }
    }
  __syncthreads();

  const int bimg = m0 >> 10, nn0 = m0 & 1023;
#pragma unroll
  for (int i = 0; i < 8; ++i) {
    int c = i * 32 + (tid >> 3);
    int ng = (tid & 7) * 4;
    float4 o = make_float4(Tt[c][ng], Tt[c][ng + 1], Tt[c][ng + 2], Tt[c][ng + 3]);
    *(float4*)&out[((size_t)bimg * 256 + c) * 1024 + nn0 + ng] = o;
  }
}

// ---------------- host launcher ----------------
extern "C" void kernel_launch(void* const* d_in, const int* in_sizes, int n_in,
                              void* d_out, int out_size, void* d_ws, size_t ws_size,
                              hipStream_t stream) {
  const float* x     = (const float*)d_in[0];
  const float* Wk    = (const float*)d_in[1];
  const float* bk    = (const float*)d_in[2];
  const float* Wq    = (const float*)d_in[3];
  const float* bq    = (const float*)d_in[4];
  const float* Wv    = (const float*)d_in[5];
  const float* bv    = (const float*)d_in[6];
  const float* Wproj = (const float*)d_in[7];
  const float* bproj = (const float*)d_in[8];
  const float* ln_g  = (const float*)d_in[9];
  const float* ln_b  = (const float*)d_in[10];
  const float* W1    = (const float*)d_in[11];
  const float* b1    = (const float*)d_in[12];
  const float* W2    = (const float*)d_in[13];
  const float* b2    = (const float*)d_in[14];

  char* ws = (char*)d_ws;
  constexpr size_t OFF_XPTB  = 0;                                    // bf16 [8192][256]
  constexpr size_t OFF_XPTF  = OFF_XPTB  + (size_t)8192 * 256 * 2;   // f32  [8192][256]
  constexpr size_t OFF_WPACK = OFF_XPTF  + (size_t)8192 * 256 * 4;   // bf16 [1536][2304]
  constexpr size_t OFF_BIAS  = OFF_WPACK + (size_t)1536 * 2304 * 2;  // f32  [1536]
  constexpr size_t OFF_WPROJ = OFF_BIAS  + (size_t)1536 * 4;         // bf16 [256][1024] (dup K)
  constexpr size_t OFF_W1B   = OFF_WPROJ + (size_t)256 * 1024 * 2;   // bf16 [256][256]
  constexpr size_t OFF_W2B   = OFF_W1B   + (size_t)256 * 256 * 2;    // bf16 [256][256]
  constexpr size_t OFF_PET   = OFF_W2B   + (size_t)256 * 256 * 2;    // f32  [256][32]
  constexpr size_t OFF_ZERO  = OFF_PET   + (size_t)256 * 32 * 4;     // f32  [256] zeros (1KB)
  constexpr size_t OFF_KQV   = OFF_ZERO  + 1024;                     // bf16 [8192][1536]
  constexpr size_t OFF_PART  = OFF_KQV   + (size_t)8192 * 1536 * 2;  // bf16 [2][8192][512]
  constexpr size_t OFF_ADDNF = OFF_PART  + (size_t)2 * 8192 * 512 * 2; // f32
  constexpr size_t OFF_ADDNB = OFF_ADDNF + (size_t)8192 * 256 * 4;   // bf16
  constexpr size_t OFF_H1    = OFF_ADDNB + (size_t)8192 * 256 * 2;   // bf16

  (void)in_sizes; (void)n_in; (void)out_size; (void)ws_size;

  const char* zp = (const char*)(ws + OFF_ZERO);

  k_petab<<<1, 256, 0, stream>>>((float*)(ws + OFF_PET), (float*)(ws + OFF_ZERO));
  k_xpt<<<dim3(8, 32, 8), 256, 0, stream>>>(x, (const float*)(ws + OFF_PET),
                                            (unsigned short*)(ws + OFF_XPTB),
                                            (float*)(ws + OFF_XPTF));
  k_packall<<<14336, 256, 0, stream>>>(Wk, Wq, Wv, bk, bq, bv, Wproj, W1, W2,
                                       (unsigned short*)(ws + OFF_WPACK),
                                       (float*)(ws + OFF_BIAS),
                                       (unsigned short*)(ws + OFF_WPROJ),
                                       (unsigned short*)(ws + OFF_W1B),
                                       (unsigned short*)(ws + OFF_W2B));
  // merged conv K+Q+V -> kqv[8192][1536]  (tile 128x192, 512 blocks = 2/CU balanced)
  k_gemm_conv<<<dim3(64, 8), 256, 0, stream>>>(
      (const unsigned short*)(ws + OFF_XPTB), (const unsigned short*)(ws + OFF_WPACK),
      (unsigned short*)(ws + OFF_KQV), (const float*)(ws + OFF_BIAS), zp);
  // fused attention -> partials [2][8192][512]
  k_attn<<<dim3(512), 512, 0, stream>>>((const unsigned short*)(ws + OFF_KQV),
                                        (unsigned short*)(ws + OFF_PART));
  // attproj + bias + resid + LN (fused) -> addnf f32 + addnb bf16
  k_projln<<<256, 256, 0, stream>>>((const unsigned short*)(ws + OFF_PART),
                                    (const unsigned short*)(ws + OFF_WPROJ), bproj,
                                    (const float*)(ws + OFF_XPTF), ln_g, ln_b,
                                    (float*)(ws + OFF_ADDNF), (unsigned short*)(ws + OFF_ADDNB));
  // FFN1 + LeakyReLU
  k_ffn1<<<dim3(64, 4), 256, 0, stream>>>(
      (const unsigned short*)(ws + OFF_ADDNB), (const unsigned short*)(ws + OFF_W1B),
      (unsigned short*)(ws + OFF_H1), b1);
  // FFN2 + bias + resid + LN + transposed output
  k_ffn2out<<<256, 256, 0, stream>>>((const unsigned short*)(ws + OFF_H1),
                                     (const unsigned short*)(ws + OFF_W2B), b2,
                                     (const float*)(ws + OFF_ADDNF), ln_g, ln_b,
                                     (float*)d_out);
}

// Round 10
// 187.566 us; speedup vs baseline: 1.3271x; 1.0280x over previous
//
#include <hip/hip_runtime.h>
#include <stdint.h>

typedef __attribute__((ext_vector_type(8))) short short8;
typedef __attribute__((ext_vector_type(4))) short s16x4;
typedef __attribute__((ext_vector_type(4))) float f32x4;

#define DEVI __device__ __forceinline__

#if __has_builtin(__builtin_amdgcn_mfma_f32_16x16x16_bf16)
#define MFMA16(a, b, c) __builtin_amdgcn_mfma_f32_16x16x16_bf16(a, b, c, 0, 0, 0)
#else
#define MFMA16(a, b, c) __builtin_amdgcn_mfma_f32_16x16x16bf16_1k(a, b, c, 0, 0, 0)
#endif

DEVI unsigned short f2bf(float f) {
  union { float f; uint32_t u; } v; v.f = f;
  return (unsigned short)((v.u + 0x7fffu + ((v.u >> 16) & 1u)) >> 16);
}

DEVI float bf2f(uint32_t hi16) {
  union { uint32_t u; float f; } v; v.u = hi16;
  return v.f;
}

DEVI uint32_t pkbf(float a, float b) {  // fast RTN pack (positive values)
  union { float f; uint32_t u; } x, y; x.f = a; y.f = b;
  return ((x.u + 0x8000u) >> 16) | (((y.u + 0x8000u) >> 16) << 16);
}

DEVI void gload_lds16(const void* g, void* l) {
  __builtin_amdgcn_global_load_lds(
      (const __attribute__((address_space(1))) uint32_t*)g,
      (__attribute__((address_space(3))) uint32_t*)l, 16, 0, 0);
}

// ---------------- K0: positional encoding table T[256][32] + zero page (1KB) ----------------
__global__ void k_petab(float* __restrict__ T, float* __restrict__ zp) {
  int c = threadIdx.x;
  zp[c] = 0.0f;
  int idx = ((c >= 128) ? c - 128 : c) >> 1;
  float freq = expf(-(float)idx * (logf(10000.0f) / 64.0f));
  for (int p = 0; p < 32; ++p) {
    float ang = (float)p * freq;
    T[c * 32 + p] = (c & 1) ? cosf(ang) : sinf(ang);
  }
}

// ---------------- K1: xpT = (x + pe) transposed to [b*1024+n][256], f32 + bf16 ----------------
__global__ __launch_bounds__(256) void k_xpt(const float* __restrict__ x,
                                             const float* __restrict__ T,
                                             unsigned short* __restrict__ xpt_bf,
                                             float* __restrict__ xpt_f) {
  __shared__ __align__(16) float tile[32][36];
  const int b = blockIdx.z, c0 = blockIdx.x * 32, n0 = blockIdx.y * 32;
  const int t = threadIdx.x;
  {
    const int cl = t >> 3, ng = (t & 7) * 4;
    const int c = c0 + cl;
    float4 v = *(const float4*)(x + ((size_t)b * 256 + c) * 1024 + n0 + ng);
    float p0, p1, p2, p3;
    if (c < 128) {
      p0 = T[c * 32 + ng + 0]; p1 = T[c * 32 + ng + 1];
      p2 = T[c * 32 + ng + 2]; p3 = T[c * 32 + ng + 3];
    } else {
      p0 = p1 = p2 = p3 = T[c * 32 + (n0 >> 5)];
    }
    tile[ng + 0][cl] = v.x + p0;
    tile[ng + 1][cl] = v.y + p1;
    tile[ng + 2][cl] = v.z + p2;
    tile[ng + 3][cl] = v.w + p3;
  }
  __syncthreads();
  {
    const int nl = t >> 3, cg = (t & 7) * 4;
    float o0 = tile[nl][cg + 0], o1 = tile[nl][cg + 1];
    float o2 = tile[nl][cg + 2], o3 = tile[nl][cg + 3];
    size_t row = (size_t)b * 1024 + n0 + nl;
    *(float4*)(xpt_f + row * 256 + c0 + cg) = make_float4(o0, o1, o2, o3);
    uint32_t lo = (uint32_t)f2bf(o0) | ((uint32_t)f2bf(o1) << 16);
    uint32_t hi = (uint32_t)f2bf(o2) | ((uint32_t)f2bf(o3) << 16);
    *(uint2*)(xpt_bf + row * 256 + c0 + cg) = make_uint2(lo, hi);
  }
}

// ---------------- K2: all weight packs in one kernel ----------------
__global__ void k_packall(const float* __restrict__ Wk, const float* __restrict__ Wq,
                          const float* __restrict__ Wv, const float* __restrict__ bk,
                          const float* __restrict__ bq, const float* __restrict__ bv,
                          const float* __restrict__ Wproj, const float* __restrict__ W1,
                          const float* __restrict__ W2, unsigned short* __restrict__ Wpack,
                          float* __restrict__ bias_kqv, unsigned short* __restrict__ WprojP,
                          unsigned short* __restrict__ W1b, unsigned short* __restrict__ W2b) {
  int bid = blockIdx.x;
  if (bid < 13824) {
    int i = bid * 256 + threadIdx.x;
    if (i >= 1536 * 2304) return;
    int o = i / 2304, kn = i % 2304;
    int ci = kn & 255, khw = kn >> 8;
    const float* src = (o < 512) ? Wk : ((o < 1024) ? Wq : Wv);
    int oo = o & 511;
    Wpack[i] = f2bf(src[((size_t)oo * 256 + ci) * 9 + khw]);
  } else {
    int i = (bid - 13824) * 256 + threadIdx.x;  // [0, 131072)
    if (i < 1536)
      bias_kqv[i] = (i < 512) ? bk[i] : ((i < 1024) ? bq[i - 512] : bv[i - 1024]);
    {
      int j = i >> 9, f = i & 511;
      int h = f >> 6, c = f & 63;
      unsigned short v = f2bf(Wproj[(size_t)j * 512 + c * 8 + h]);
      WprojP[(size_t)j * 1024 + f] = v;        // K-chunk 0
      WprojP[(size_t)j * 1024 + 512 + f] = v;  // K-chunk 1 (duplicated: O = O0 + O1)
    }
    if (i < 65536) {
      W1b[i] = f2bf(W1[i]);
      W2b[i] = f2bf(W2[i]);
    }
  }
}

// ---------------- merged conv GEMM v4: kqv[8192][1536] = im2col(xpt).Wpack^T ----------------
__global__ __launch_bounds__(256, 2) void k_gemm_conv(const unsigned short* __restrict__ xpt,
                                                      const unsigned short* __restrict__ Wp,
                                                      unsigned short* __restrict__ kqv,
                                                      const float* __restrict__ bias,
                                                      const char* __restrict__ zp) {
  __shared__ __align__(16) unsigned short As[2][128 * 64];  // 32KB
  __shared__ __align__(16) unsigned short Bs[2][192 * 64];  // 48KB
  const int tid = threadIdx.x, l = tid & 63, w = tid >> 6;
  const int wm = w >> 1, wn = w & 1, g = l >> 4, ln = l & 15;
  const int m0 = blockIdx.x * 128, n0 = blockIdx.y * 192;
  const int swz = (l & 7) ^ (l >> 3);

  const char* pAbase[4];
#pragma unroll
  for (int j = 0; j < 4; ++j) {
    int r = m0 + (w * 4 + j) * 8 + (l >> 3);
    pAbase[j] = (const char*)xpt + ((size_t)r * 256 + swz * 8) * 2;
  }
  const char* pB0 = (const char*)Wp +
                    ((size_t)(n0 + w * 48 + (l >> 3)) * 2304 + swz * 8) * 2;

  f32x4 acc[4][6] = {};
  int vmask = 0;
  int aoff = 0;

  auto setTap = [&](int tap) {
    int d3 = (tap * 11) >> 5;  // tap/3
    int dy = d3 - 1, dx = tap - d3 * 3 - 1;
    aoff = (dy * 32 + dx) * 512;
    int m = 0;
#pragma unroll
    for (int j = 0; j < 4; ++j) {
      int r = m0 + (w * 4 + j) * 8 + (l >> 3);
      int y = ((r >> 5) & 31) + dy;
      int x = (r & 31) + dx;
      if (((unsigned)y < 32u) && ((unsigned)x < 32u)) m |= (1 << j);
    }
    vmask = m;
  };

  auto STAGE = [&](int buf, int kb) {
#pragma unroll
    for (int j = 0; j < 4; ++j) {
      const char* a = (vmask & (1 << j)) ? (pAbase[j] + aoff) : zp;
      gload_lds16(a, (char*)As + buf * 16384 + (w * 4 + j) * 1024);
    }
#pragma unroll
    for (int j = 0; j < 6; ++j) {
      gload_lds16(pB0 + j * 36864 + kb, (char*)Bs + buf * 24576 + (w * 6 + j) * 1024);
    }
  };

  auto COMPUTE = [&](int buf) {
    const char* Ab2 = (const char*)As + buf * 16384;
    const char* Bb2 = (const char*)Bs + buf * 24576;
#pragma unroll
    for (int kk = 0; kk < 2; ++kk) {
      short8 af[4], bfr[6];
#pragma unroll
      for (int fm = 0; fm < 4; ++fm)
        af[fm] = *(const short8*)(Ab2 + (wm * 64 + fm * 16 + ln) * 128 +
                                  (((kk * 4 + g) ^ (ln & 7)) * 16));
#pragma unroll
      for (int fn = 0; fn < 6; ++fn)
        bfr[fn] = *(const short8*)(Bb2 + (wn * 96 + fn * 16 + ln) * 128 +
                                   (((kk * 4 + g) ^ (ln & 7)) * 16));
#pragma unroll
      for (int fm = 0; fm < 4; ++fm)
#pragma unroll
        for (int fn = 0; fn < 6; ++fn)
          acc[fm][fn] = __builtin_amdgcn_mfma_f32_16x16x32_bf16(af[fm], bfr[fn], acc[fm][fn], 0, 0, 0);
    }
  };

  setTap(0);
  STAGE(0, 0);
  aoff += 128;
  int kb = 128;
  for (int s = 0; s < 36; ++s) {
    const int buf = s & 1;
    if (s < 35) {
      if (((s + 1) & 3) == 0) setTap((s + 1) >> 2);
      STAGE(buf ^ 1, kb);
      kb += 128;
      aoff += 128;
      asm volatile("s_waitcnt vmcnt(10)" ::: "memory");
    } else {
      asm volatile("s_waitcnt vmcnt(0)" ::: "memory");
    }
    __builtin_amdgcn_s_barrier();
    __builtin_amdgcn_sched_barrier(0);
    COMPUTE(buf);
    asm volatile("s_waitcnt lgkmcnt(0)" ::: "memory");
    __builtin_amdgcn_s_barrier();
    __builtin_amdgcn_sched_barrier(0);
  }

#pragma unroll
  for (int fm = 0; fm < 4; ++fm)
#pragma unroll
    for (int fn = 0; fn < 6; ++fn) {
      int col = n0 + wn * 96 + fn * 16 + ln;
      float bb = bias[col];
#pragma unroll
      for (int r = 0; r < 4; ++r) {
        int row = m0 + wm * 64 + fm * 16 + g * 4 + r;
        kqv[(size_t)row * 1536 + col] = f2bf(acc[fm][fn][r] + bb);
      }
    }
}

// ---------------- GEMM BN=64 (FFN1): bf16 out, + bias[col], LeakyReLU(0.1) ----------------
__global__ __launch_bounds__(256) void k_ffn1(const unsigned short* __restrict__ A,
                                              const unsigned short* __restrict__ B,
                                              unsigned short* __restrict__ Cout,
                                              const float* __restrict__ bias) {
  __shared__ __align__(16) unsigned short As[128 * 64];
  __shared__ __align__(16) unsigned short Bs[64 * 64];
  const int tid = threadIdx.x, l = tid & 63, w = tid >> 6;
  const int g = l >> 4, ln = l & 15;
  const int m0 = blockIdx.x * 128, n0 = blockIdx.y * 64;
  const int swz = (l & 7) ^ (l >> 3);
  f32x4 acc[2][4] = {};

  for (int kt = 0; kt < 256; kt += 64) {
#pragma unroll
    for (int j = 0; j < 4; ++j) {
      int seg = w * 4 + j;
      int r8 = seg * 8 + (l >> 3);
      gload_lds16((const char*)A + ((size_t)(m0 + r8) * 256 + kt + swz * 8) * 2,
                  (char*)As + seg * 1024);
    }
#pragma unroll
    for (int j = 0; j < 2; ++j) {
      int seg = w * 2 + j;
      int r8 = seg * 8 + (l >> 3);
      gload_lds16((const char*)B + ((size_t)(n0 + r8) * 256 + kt + swz * 8) * 2,
                  (char*)Bs + seg * 1024);
    }
    __syncthreads();
#pragma unroll
    for (int kk = 0; kk < 2; ++kk) {
      short8 af[2], bfr[4];
#pragma unroll
      for (int fm = 0; fm < 2; ++fm)
        af[fm] = *(const short8*)((const char*)As + (w * 32 + fm * 16 + ln) * 128 +
                                  (((kk * 4 + g) ^ (ln & 7)) * 16));
#pragma unroll
      for (int fn = 0; fn < 4; ++fn)
        bfr[fn] = *(const short8*)((const char*)Bs + (fn * 16 + ln) * 128 +
                                   (((kk * 4 + g) ^ (ln & 7)) * 16));
#pragma unroll
      for (int fm = 0; fm < 2; ++fm)
#pragma unroll
        for (int fn = 0; fn < 4; ++fn)
          acc[fm][fn] = __builtin_amdgcn_mfma_f32_16x16x32_bf16(af[fm], bfr[fn], acc[fm][fn], 0, 0, 0);
    }
    __syncthreads();
  }

#pragma unroll
  for (int fm = 0; fm < 2; ++fm)
#pragma unroll
    for (int fn = 0; fn < 4; ++fn)
#pragma unroll
      for (int r = 0; r < 4; ++r) {
        int row = m0 + w * 32 + fm * 16 + g * 4 + r;
        int col = n0 + fn * 16 + ln;
        float v = acc[fm][fn][r] + bias[col];
        v = (v > 0.f) ? v : 0.1f * v;
        Cout[(size_t)row * 256 + col] = f2bf(v);
      }
}

// ---------------- K5: fused attention v7 — reg-staged async pipeline ----------------
// v6 head-split structure + T14 async-STAGE: global_load_dwordx4 issued at step START
// (for s+1), ds_write at step END after PV -> HBM/L2 latency hidden under the step and
// B1 drains only LDS writes. Pointer-increment addressing; rcpf for softmax reciprocal.
__global__ __launch_bounds__(512, 4) void k_attn(const unsigned short* __restrict__ kqv,
                                                 unsigned short* __restrict__ part) {
  __shared__ __align__(16) unsigned short Qs[16][512];
  __shared__ __align__(16) unsigned short Vlin[16][512];
  __shared__ __align__(16) unsigned short Vs[32][16][16];
  __shared__ __align__(16) float sums[4][2][64][4];
  const int tid = threadIdx.x, l = tid & 63, w = tid >> 6;
  const int g = l >> 4, ln = l & 15;
  const int nt = w & 1, hg = w >> 1;
  const int id = blockIdx.x;
  const int b = id & 7, ng = (id >> 3) & 31, ch = id >> 8;
  const int n0 = ng * 32 + nt * 16;
  const int m_base = ch * 512;
  const size_t rowBase = (size_t)b * 1024;
  const float SC = 1.0f / 1024.0f;

  short8 ak[2][2];
#pragma unroll
  for (int hl = 0; hl < 2; ++hl)
#pragma unroll
    for (int kk = 0; kk < 2; ++kk)
      ak[hl][kk] = *(const short8*)&kqv[(rowBase + n0 + ln) * 1536 +
                                        (hg * 2 + hl) * 64 + kk * 32 + g * 8];

  f32x4 acc[2][4] = {};

  // reg-staging: rows r0 = w*2, r1 = w*2+1; lane l carries chunk l (16B) of Q and V.
  const int r0 = w * 2, r1 = w * 2 + 1;
  const char* pRow = (const char*)kqv +
                     (size_t)(rowBase + m_base + r0) * 3072 + 1024 + (size_t)l * 16;
  uint4 q0, q1, v0, v1;

  auto LOADREGS = [&]() {
    q0 = *(const uint4*)pRow;
    v0 = *(const uint4*)(pRow + 1024);
    q1 = *(const uint4*)(pRow + 3072);
    v1 = *(const uint4*)(pRow + 4096);
    pRow += 49152;  // 16 rows * 3072B
  };
  // LDS slot (l ^ (r&7)) holds global chunk l  (same map as the old source-swizzled glds)
  char* const dQ0 = (char*)Qs + r0 * 1024 + ((l ^ (r0 & 7)) * 16);
  char* const dV0 = (char*)Vlin + r0 * 1024 + ((l ^ (r0 & 7)) * 16);
  char* const dQ1 = (char*)Qs + r1 * 1024 + ((l ^ (r1 & 7)) * 16);
  char* const dV1 = (char*)Vlin + r1 * 1024 + ((l ^ (r1 & 7)) * 16);
  auto DSW = [&]() {
    *(uint4*)dQ0 = q0;
    *(uint4*)dV0 = v0;
    *(uint4*)dQ1 = q1;
    *(uint4*)dV1 = v1;
  };

  // prologue: stage step 0
  LOADREGS();
  asm volatile("s_waitcnt vmcnt(0)" ::: "memory");
  DSW();
  asm volatile("s_waitcnt lgkmcnt(0)" ::: "memory");
  __builtin_amdgcn_s_barrier();
  __builtin_amdgcn_sched_barrier(0);

  const uint32_t vsBase = (uint32_t)(uintptr_t)&Vs[0][0][0] + l * 8;

  for (int s = 0; s < 32; ++s) {
    if (s < 31) LOADREGS();  // issue loads for s+1 early; consumed at end of step

    // --- transpose Vlin -> Vs subtiles ---
    {
      const int tm = l & 15;
#pragma unroll
      for (int i = 0; i < 2; ++i) {
        int tch = (l >> 4) + w * 4 + i * 32;
        short8 tv = *(const short8*)((const char*)Vlin + tm * 1024 +
                                     ((tch ^ (tm & 7)) * 16));
        *(short8*)((char*)Vs + (tch >> 1) * 512 + tm * 32 + (tch & 1) * 16) = tv;
      }
    }

    // --- QK^T for this wave's 2 heads ---
    f32x4 sv[2] = {};
#pragma unroll
    for (int kk = 0; kk < 2; ++kk)
#pragma unroll
      for (int hl = 0; hl < 2; ++hl) {
        int chq = (hg * 2 + hl) * 8 + kk * 4 + g;
        short8 qa = *(const short8*)((const char*)Qs + ln * 1024 +
                                     ((chq ^ (ln & 7)) * 16));
        sv[hl] = __builtin_amdgcn_mfma_f32_16x16x32_bf16(qa, ak[hl][kk], sv[hl], 0, 0, 0);
      }

    // --- exp + partial sums ---
    f32x4 e0, e1, ps;
#pragma unroll
    for (int j = 0; j < 4; ++j) {
      e0[j] = __expf(sv[0][j] * SC);
      e1[j] = __expf(sv[1][j] * SC);
      ps[j] = e0[j] + e1[j];
    }
    *(f32x4*)&sums[hg][nt][l][0] = ps;
    asm volatile("s_waitcnt lgkmcnt(0)" ::: "memory");
    __builtin_amdgcn_s_barrier();  // B3: sums + Vs transpose visible
    __builtin_amdgcn_sched_barrier(0);

    // --- total over 8 heads; normalize (raw rcp: 1ulp, fine for softmax) ---
    f32x4 tot = ps;
#pragma unroll
    for (int d = 1; d < 4; ++d) {
      f32x4 o = *(const f32x4*)&sums[(hg + d) & 3][nt][l][0];
      tot[0] += o[0]; tot[1] += o[1]; tot[2] += o[2]; tot[3] += o[3];
    }
    f32x4 inv;
#pragma unroll
    for (int j = 0; j < 4; ++j) inv[j] = __builtin_amdgcn_rcpf(tot[j]);

    // --- PV: batched tr_reads + MFMA16 with P from registers ---
    s16x4 vf[8];
#pragma unroll
    for (int hl = 0; hl < 2; ++hl) {
      uint32_t ah = vsBase + (hg * 2 + hl) * 2048;
      asm volatile("ds_read_b64_tr_b16 %0, %1" : "=v"(vf[hl * 4 + 0]) : "v"(ah));
      asm volatile("ds_read_b64_tr_b16 %0, %1 offset:512" : "=v"(vf[hl * 4 + 1]) : "v"(ah));
      asm volatile("ds_read_b64_tr_b16 %0, %1 offset:1024" : "=v"(vf[hl * 4 + 2]) : "v"(ah));
      asm volatile("ds_read_b64_tr_b16 %0, %1 offset:1536" : "=v"(vf[hl * 4 + 3]) : "v"(ah));
    }
    asm volatile("s_waitcnt lgkmcnt(0)" ::: "memory");
    __builtin_amdgcn_sched_barrier(0);
    union { uint32_t u[2]; s16x4 v4; } pc0, pc1;
    pc0.u[0] = pkbf(e0[0] * inv[0], e0[1] * inv[1]);
    pc0.u[1] = pkbf(e0[2] * inv[2], e0[3] * inv[3]);
    pc1.u[0] = pkbf(e1[0] * inv[0], e1[1] * inv[1]);
    pc1.u[1] = pkbf(e1[2] * inv[2], e1[3] * inv[3]);
#pragma unroll
    for (int cf = 0; cf < 4; ++cf) {
      acc[0][cf] = MFMA16(vf[cf], pc0.v4, acc[0][cf]);
      acc[1][cf] = MFMA16(vf[4 + cf], pc1.v4, acc[1][cf]);
    }

    // --- write staged regs for s+1 into Qs/Vlin (loads have had the whole step) ---
    if (s < 31) {
      asm volatile("s_waitcnt vmcnt(0)" ::: "memory");
      DSW();
    }
    asm volatile("s_waitcnt lgkmcnt(0)" ::: "memory");
    __builtin_amdgcn_s_barrier();  // B1: next step's Qs/Vlin ready
    __builtin_amdgcn_sched_barrier(0);
  }

  const size_t outBase = (size_t)ch * 8192 * 512 + (rowBase + n0 + ln) * 512;
#pragma unroll
  for (int hl = 0; hl < 2; ++hl)
#pragma unroll
    for (int cf = 0; cf < 4; ++cf)
#pragma unroll
      for (int r2 = 0; r2 < 2; ++r2) {
        int c = (hg * 2 + hl) * 64 + cf * 16 + g * 4 + r2 * 2;
        uint32_t u = (uint32_t)f2bf(acc[hl][cf][2 * r2]) |
                     ((uint32_t)f2bf(acc[hl][cf][2 * r2 + 1]) << 16);
        *(uint32_t*)&part[outBase + c] = u;
      }
}

// ---------------- K6: fused attproj + bias + resid(x+pe) + LayerNorm ----------------
__global__ __launch_bounds__(256) void k_projln(const unsigned short* __restrict__ part,
                                                const unsigned short* __restrict__ Wp,
                                                const float* __restrict__ bias,
                                                const float* __restrict__ resid,
                                                const float* __restrict__ lg,
                                                const float* __restrict__ lb,
                                                float* __restrict__ out_f,
                                                unsigned short* __restrict__ out_b) {
  __shared__ __align__(16) unsigned short As[32 * 64];
  __shared__ __align__(16) unsigned short Bs[256 * 64];
  __shared__ float rsum[4][32][2];
  const int tid = threadIdx.x, l = tid & 63, w = tid >> 6;
  const int g4 = l >> 4, ln = l & 15;
  const int m0 = blockIdx.x * 32;
  const int swz = (l & 7) ^ (l >> 3);
  f32x4 acc[2][4] = {};

  for (int kt = 0; kt < 1024; kt += 64) {
    gload_lds16((const char*)part + (((size_t)(kt >> 9) * 8192 * 512) +
                                     (size_t)(m0 + w * 8 + (l >> 3)) * 512 +
                                     (kt & 511) + swz * 8) * 2,
                (char*)As + w * 1024);
#pragma unroll
    for (int j = 0; j < 8; ++j) {
      int seg = w * 8 + j;
      gload_lds16((const char*)Wp + ((size_t)(seg * 8 + (l >> 3)) * 1024 + kt + swz * 8) * 2,
                  (char*)Bs + seg * 1024);
    }
    __syncthreads();
#pragma unroll
    for (int kk = 0; kk < 2; ++kk) {
      short8 af[2], bfr[4];
#pragma unroll
      for (int fm = 0; fm < 2; ++fm)
        af[fm] = *(const short8*)((const char*)As + (fm * 16 + ln) * 128 +
                                  (((kk * 4 + g4) ^ (ln & 7)) * 16));
#pragma unroll
      for (int fn = 0; fn < 4; ++fn)
        bfr[fn] = *(const short8*)((const char*)Bs + (w * 64 + fn * 16 + ln) * 128 +
                                   (((kk * 4 + g4) ^ (ln & 7)) * 16));
#pragma unroll
      for (int fm = 0; fm < 2; ++fm)
#pragma unroll
        for (int fn = 0; fn < 4; ++fn)
          acc[fm][fn] = __builtin_amdgcn_mfma_f32_16x16x32_bf16(af[fm], bfr[fn], acc[fm][fn], 0, 0, 0);
    }
    __syncthreads();
  }

  float vals[2][4][4];
#pragma unroll
  for (int fm = 0; fm < 2; ++fm)
#pragma unroll
    for (int r = 0; r < 4; ++r) {
      int row_l = fm * 16 + g4 * 4 + r;
      float s = 0.f, q = 0.f;
#pragma unroll
      for (int fn = 0; fn < 4; ++fn) {
        int col = w * 64 + fn * 16 + ln;
        float v = acc[fm][fn][r] + bias[col] + resid[(size_t)(m0 + row_l) * 256 + col];
        vals[fm][fn][r] = v;
        s += v;
        q += v * v;
      }
#pragma unroll
      for (int o = 1; o < 16; o <<= 1) {
        s += __shfl_xor(s, o, 64);
        q += __shfl_xor(q, o, 64);
      }
      if (ln == 0) {
        rsum[w][row_l][0] = s;
        rsum[w][row_l][1] = q;
      }
    }
  __syncthreads();

#pragma unroll
  for (int fm = 0; fm < 2; ++fm)
#pragma unroll
    for (int r = 0; r < 4; ++r) {
      int row_l = fm * 16 + g4 * 4 + r;
      float s = rsum[0][row_l][0] + rsum[1][row_l][0] + rsum[2][row_l][0] + rsum[3][row_l][0];
      float q = rsum[0][row_l][1] + rsum[1][row_l][1] + rsum[2][row_l][1] + rsum[3][row_l][1];
      float mu = s * (1.0f / 256.0f);
      float rstd = rsqrtf(q * (1.0f / 256.0f) - mu * mu + 1e-5f);
      size_t rowOff = (size_t)(m0 + row_l) * 256;
#pragma unroll
      for (int fn = 0; fn < 4; ++fn) {
        int col = w * 64 + fn * 16 + ln;
        float o = (vals[fm][fn][r] - mu) * rstd * lg[col] + lb[col];
        out_f[rowOff + col] = o;
        out_b[rowOff + col] = f2bf(o);
      }
    }
}

// ---------------- K7: fused FFN2 + bias + resid + LayerNorm + transposed output ----------------
__global__ __launch_bounds__(256) void k_ffn2out(const unsigned short* __restrict__ h1,
                                                 const unsigned short* __restrict__ W2b,
                                                 const float* __restrict__ b2,
                                                 const float* __restrict__ addnf,
                                                 const float* __restrict__ lg,
                                                 const float* __restrict__ lb,
                                                 float* __restrict__ out) {
  __shared__ __align__(16) unsigned short As[32 * 64];
  __shared__ __align__(16) unsigned short Bs[256 * 64];
  __shared__ __align__(16) float Tt[256][33];
  __shared__ float rsum[4][32][2];
  const int tid = threadIdx.x, l = tid & 63, w = tid >> 6;
  const int g4 = l >> 4, ln = l & 15;
  const int m0 = blockIdx.x * 32;
  const int swz = (l & 7) ^ (l >> 3);
  f32x4 acc[2][4] = {};

  for (int kt = 0; kt < 256; kt += 64) {
    gload_lds16((const char*)h1 + ((size_t)(m0 + w * 8 + (l >> 3)) * 256 + kt + swz * 8) * 2,
                (char*)As + w * 1024);
#pragma unroll
    for (int j = 0; j < 8; ++j) {
      int seg = w * 8 + j;
      gload_lds16((const char*)W2b + ((size_t)(seg * 8 + (l >> 3)) * 256 + kt + swz * 8) * 2,
                  (char*)Bs + seg * 1024);
    }
    __syncthreads();
#pragma unroll
    for (int kk = 0; kk < 2; ++kk) {
      short8 af[2], bfr[4];
#pragma unroll
      for (int fm = 0; fm < 2; ++fm)
        af[fm] = *(const short8*)((const char*)As + (fm * 16 + ln) * 128 +
                                  (((kk * 4 + g4) ^ (ln & 7)) * 16));
#pragma unroll
      for (int fn = 0; fn < 4; ++fn)
        bfr[fn] = *(const short8*)((const char*)Bs + (w * 64 + fn * 16 + ln) * 128 +
                                   (((kk * 4 + g4) ^ (ln & 7)) * 16));
#pragma unroll
      for (int fm = 0; fm < 2; ++fm)
#pragma unroll
        for (int fn = 0; fn < 4; ++fn)
          acc[fm][fn] = __builtin_amdgcn_mfma_f32_16x16x32_bf16(af[fm], bfr[fn], acc[fm][fn], 0, 0, 0);
    }
    __syncthreads();
  }

  float vals[2][4][4];
#pragma unroll
  for (int fm = 0; fm < 2; ++fm)
#pragma unroll
    for (int r = 0; r < 4; ++r) {
      int row_l = fm * 16 + g4 * 4 + r;
      float s = 0.f, q = 0.f;
#pragma unroll
      for (int fn = 0; fn < 4; ++fn) {
        int col = w * 64 + fn * 16 + ln;
        float v = acc[fm][fn][r] + b2[col] + addnf[(size_t)(m0 + row_l) * 256 + col];
        vals[fm][fn][r] = v;
        s += v;
        q += v * v;
      }
#pragma unroll
      for (int o = 1; o < 16; o <<= 1) {
        s += __shfl_xor(s, o, 64);
        q += __shfl_xor(q, o, 64);
      }
      if (ln == 0) {
        rsum[w][row_l][0] = s;
        rsum[w][row_l][1] = q;
      }
    }
  __syncthreads();

#pragma unroll
  for (int fm = 0; fm < 2; ++fm)
#pragma unroll
    for (int r = 0; r < 4; ++r) {
      int row_l = fm * 16 + g4 * 4 + r;
      float s = rsum[0][row_l][0] + rsum[1][row_l][0] + rsum[2][row_l][0] + rsum[3][row_l][0];
      float q = rsum[0][row_l][1] + rsum[1][row_l][1] + rsum[2][row_l][1] + rsum[3][row_l][1];
      float mu = s * (1.0f / 256.0f);
      float rstd = rsqrtf(q * (1.0f / 256.0f) - mu * mu + 1e-5f);
#pragma unroll
      for (int fn = 0; fn < 4; ++fn) {
        int col = w * 64 + fn * 16 + ln;
        Tt[col][row_l] = (vals[fm][fn][r] - mu) * rstd * lg[col] + lb[col];
      }
    }
  __syncthreads();

  const int bimg = m0 >> 10, nn0 = m0 & 1023;
#pragma unroll
  for (int i = 0; i < 8; ++i) {
    int c = i * 32 + (tid >> 3);
    int ng = (tid & 7) * 4;
    float4 o = make_float4(Tt[c][ng], Tt[c][ng + 1], Tt[c][ng + 2], Tt[c][ng + 3]);
    *(float4*)&out[((size_t)bimg * 256 + c) * 1024 + nn0 + ng] = o;
  }
}

// ---------------- host launcher ----------------
extern "C" void kernel_launch(void* const* d_in, const int* in_sizes, int n_in,
                              void* d_out, int out_size, void* d_ws, size_t ws_size,
                              hipStream_t stream) {
  const float* x     = (const float*)d_in[0];
  const float* Wk    = (const float*)d_in[1];
  const float* bk    = (const float*)d_in[2];
  const float* Wq    = (const float*)d_in[3];
  const float* bq    = (const float*)d_in[4];
  const float* Wv    = (const float*)d_in[5];
  const float* bv    = (const float*)d_in[6];
  const float* Wproj = (const float*)d_in[7];
  const float* bproj = (const float*)d_in[8];
  const float* ln_g  = (const float*)d_in[9];
  const float* ln_b  = (const float*)d_in[10];
  const float* W1    = (const float*)d_in[11];
  const float* b1    = (const float*)d_in[12];
  const float* W2    = (const float*)d_in[13];
  const float* b2    = (const float*)d_in[14];

  char* ws = (char*)d_ws;
  constexpr size_t OFF_XPTB  = 0;                                    // bf16 [8192][256]
  constexpr size_t OFF_XPTF  = OFF_XPTB  + (size_t)8192 * 256 * 2;   // f32  [8192][256]
  constexpr size_t OFF_WPACK = OFF_XPTF  + (size_t)8192 * 256 * 4;   // bf16 [1536][2304]
  constexpr size_t OFF_BIAS  = OFF_WPACK + (size_t)1536 * 2304 * 2;  // f32  [1536]
  constexpr size_t OFF_WPROJ = OFF_BIAS  + (size_t)1536 * 4;         // bf16 [256][1024] (dup K)
  constexpr size_t OFF_W1B   = OFF_WPROJ + (size_t)256 * 1024 * 2;   // bf16 [256][256]
  constexpr size_t OFF_W2B   = OFF_W1B   + (size_t)256 * 256 * 2;    // bf16 [256][256]
  constexpr size_t OFF_PET   = OFF_W2B   + (size_t)256 * 256 * 2;    // f32  [256][32]
  constexpr size_t OFF_ZERO  = OFF_PET   + (size_t)256 * 32 * 4;     // f32  [256] zeros (1KB)
  constexpr size_t OFF_KQV   = OFF_ZERO  + 1024;                     // bf16 [8192][1536]
  constexpr size_t OFF_PART  = OFF_KQV   + (size_t)8192 * 1536 * 2;  // bf16 [2][8192][512]
  constexpr size_t OFF_ADDNF = OFF_PART  + (size_t)2 * 8192 * 512 * 2; // f32
  constexpr size_t OFF_ADDNB = OFF_ADDNF + (size_t)8192 * 256 * 4;   // bf16
  constexpr size_t OFF_H1    = OFF_ADDNB + (size_t)8192 * 256 * 2;   // bf16

  (void)in_sizes; (void)n_in; (void)out_size; (void)ws_size;

  const char* zp = (const char*)(ws + OFF_ZERO);

  k_petab<<<1, 256, 0, stream>>>((float*)(ws + OFF_PET), (float*)(ws + OFF_ZERO));
  k_xpt<<<dim3(8, 32, 8), 256, 0, stream>>>(x, (const float*)(ws + OFF_PET),
                                            (unsigned short*)(ws + OFF_XPTB),
                                            (float*)(ws + OFF_XPTF));
  k_packall<<<14336, 256, 0, stream>>>(Wk, Wq, Wv, bk, bq, bv, Wproj, W1, W2,
                                       (unsigned short*)(ws + OFF_WPACK),
                                       (float*)(ws + OFF_BIAS),
                                       (unsigned short*)(ws + OFF_WPROJ),
                                       (unsigned short*)(ws + OFF_W1B),
                                       (unsigned short*)(ws + OFF_W2B));
  // merged conv K+Q+V -> kqv[8192][1536]  (tile 128x192, 512 blocks = 2/CU balanced)
  k_gemm_conv<<<dim3(64, 8), 256, 0, stream>>>(
      (const unsigned short*)(ws + OFF_XPTB), (const unsigned short*)(ws + OFF_WPACK),
      (unsigned short*)(ws + OFF_KQV), (const float*)(ws + OFF_BIAS), zp);
  // fused attention -> partials [2][8192][512]
  k_attn<<<dim3(512), 512, 0, stream>>>((const unsigned short*)(ws + OFF_KQV),
                                        (unsigned short*)(ws + OFF_PART));
  // attproj + bias + resid + LN (fused) -> addnf f32 + addnb bf16
  k_projln<<<256, 256, 0, stream>>>((const unsigned short*)(ws + OFF_PART),
                                    (const unsigned short*)(ws + OFF_WPROJ), bproj,
                                    (const float*)(ws + OFF_XPTF), ln_g, ln_b,
                                    (float*)(ws + OFF_ADDNF), (unsigned short*)(ws + OFF_ADDNB));
  // FFN1 + LeakyReLU
  k_ffn1<<<dim3(64, 4), 256, 0, stream>>>(
      (const unsigned short*)(ws + OFF_ADDNB), (const unsigned short*)(ws + OFF_W1B),
      (unsigned short*)(ws + OFF_H1), b1);
  // FFN2 + bias + resid + LN + transposed output
  k_ffn2out<<<256, 256, 0, stream>>>((const unsigned short*)(ws + OFF_H1),
                                     (const unsigned short*)(ws + OFF_W2B), b2,
                                     (const float*)(ws + OFF_ADDNF), ln_g, ln_b,
                                     (float*)d_out);
}

// Round 11
// 185.672 us; speedup vs baseline: 1.3406x; 1.0102x over previous
//
#include <hip/hip_runtime.h>
#include <stdint.h>

typedef __attribute__((ext_vector_type(8))) short short8;
typedef __attribute__((ext_vector_type(4))) short s16x4;
typedef __attribute__((ext_vector_type(4))) float f32x4;

#define DEVI __device__ __forceinline__

#if __has_builtin(__builtin_amdgcn_mfma_f32_16x16x16_bf16)
#define MFMA16(a, b, c) __builtin_amdgcn_mfma_f32_16x16x16_bf16(a, b, c, 0, 0, 0)
#else
#define MFMA16(a, b, c) __builtin_amdgcn_mfma_f32_16x16x16bf16_1k(a, b, c, 0, 0, 0)
#endif

DEVI unsigned short f2bf(float f) {
  union { float f; uint32_t u; } v; v.f = f;
  return (unsigned short)((v.u + 0x7fffu + ((v.u >> 16) & 1u)) >> 16);
}

DEVI float bf2f(uint32_t hi16) {
  union { uint32_t u; float f; } v; v.u = hi16;
  return v.f;
}

DEVI uint32_t pkbf(float a, float b) {  // fast RTN pack (positive values)
  union { float f; uint32_t u; } x, y; x.f = a; y.f = b;
  return ((x.u + 0x8000u) >> 16) | (((y.u + 0x8000u) >> 16) << 16);
}

DEVI void gload_lds16(const void* g, void* l) {
  __builtin_amdgcn_global_load_lds(
      (const __attribute__((address_space(1))) uint32_t*)g,
      (__attribute__((address_space(3))) uint32_t*)l, 16, 0, 0);
}

// ---------------- K0: positional encoding table T[256][32] + zero page (1KB) ----------------
__global__ void k_petab(float* __restrict__ T, float* __restrict__ zp) {
  int c = threadIdx.x;
  zp[c] = 0.0f;
  int idx = ((c >= 128) ? c - 128 : c) >> 1;
  float freq = expf(-(float)idx * (logf(10000.0f) / 64.0f));
  for (int p = 0; p < 32; ++p) {
    float ang = (float)p * freq;
    T[c * 32 + p] = (c & 1) ? cosf(ang) : sinf(ang);
  }
}

// ---------------- K1: xpT = (x + pe) transposed to [b*1024+n][256], f32 + bf16 ----------------
__global__ __launch_bounds__(256) void k_xpt(const float* __restrict__ x,
                                             const float* __restrict__ T,
                                             unsigned short* __restrict__ xpt_bf,
                                             float* __restrict__ xpt_f) {
  __shared__ __align__(16) float tile[32][36];
  const int b = blockIdx.z, c0 = blockIdx.x * 32, n0 = blockIdx.y * 32;
  const int t = threadIdx.x;
  {
    const int cl = t >> 3, ng = (t & 7) * 4;
    const int c = c0 + cl;
    float4 v = *(const float4*)(x + ((size_t)b * 256 + c) * 1024 + n0 + ng);
    float p0, p1, p2, p3;
    if (c < 128) {
      p0 = T[c * 32 + ng + 0]; p1 = T[c * 32 + ng + 1];
      p2 = T[c * 32 + ng + 2]; p3 = T[c * 32 + ng + 3];
    } else {
      p0 = p1 = p2 = p3 = T[c * 32 + (n0 >> 5)];
    }
    tile[ng + 0][cl] = v.x + p0;
    tile[ng + 1][cl] = v.y + p1;
    tile[ng + 2][cl] = v.z + p2;
    tile[ng + 3][cl] = v.w + p3;
  }
  __syncthreads();
  {
    const int nl = t >> 3, cg = (t & 7) * 4;
    float o0 = tile[nl][cg + 0], o1 = tile[nl][cg + 1];
    float o2 = tile[nl][cg + 2], o3 = tile[nl][cg + 3];
    size_t row = (size_t)b * 1024 + n0 + nl;
    *(float4*)(xpt_f + row * 256 + c0 + cg) = make_float4(o0, o1, o2, o3);
    uint32_t lo = (uint32_t)f2bf(o0) | ((uint32_t)f2bf(o1) << 16);
    uint32_t hi = (uint32_t)f2bf(o2) | ((uint32_t)f2bf(o3) << 16);
    *(uint2*)(xpt_bf + row * 256 + c0 + cg) = make_uint2(lo, hi);
  }
}

// ---------------- K2: all weight packs in one kernel ----------------
__global__ void k_packall(const float* __restrict__ Wk, const float* __restrict__ Wq,
                          const float* __restrict__ Wv, const float* __restrict__ bk,
                          const float* __restrict__ bq, const float* __restrict__ bv,
                          const float* __restrict__ Wproj, const float* __restrict__ W1,
                          const float* __restrict__ W2, unsigned short* __restrict__ Wpack,
                          float* __restrict__ bias_kqv, unsigned short* __restrict__ WprojP,
                          unsigned short* __restrict__ W1b, unsigned short* __restrict__ W2b) {
  int bid = blockIdx.x;
  if (bid < 13824) {
    int i = bid * 256 + threadIdx.x;
    if (i >= 1536 * 2304) return;
    int o = i / 2304, kn = i % 2304;
    int ci = kn & 255, khw = kn >> 8;
    const float* src = (o < 512) ? Wk : ((o < 1024) ? Wq : Wv);
    int oo = o & 511;
    Wpack[i] = f2bf(src[((size_t)oo * 256 + ci) * 9 + khw]);
  } else {
    int i = (bid - 13824) * 256 + threadIdx.x;  // [0, 131072)
    if (i < 1536)
      bias_kqv[i] = (i < 512) ? bk[i] : ((i < 1024) ? bq[i - 512] : bv[i - 1024]);
    {
      int j = i >> 9, f = i & 511;
      int h = f >> 6, c = f & 63;
      unsigned short v = f2bf(Wproj[(size_t)j * 512 + c * 8 + h]);
      WprojP[(size_t)j * 1024 + f] = v;        // K-chunk 0
      WprojP[(size_t)j * 1024 + 512 + f] = v;  // K-chunk 1 (duplicated: O = O0 + O1)
    }
    if (i < 65536) {
      W1b[i] = f2bf(W1[i]);
      W2b[i] = f2bf(W2[i]);
    }
  }
}

// ---------------- merged conv GEMM v4+XCD: kqv[8192][1536] = im2col(xpt).Wpack^T ----------------
// Tile 128m x 192n, 512 blocks = 2/CU. Bijective XCD remap: each XCD owns all 64 m-blocks
// of one n-slice -> its 885KB B-panel + 4MB xpt live in that XCD's private L2.
__global__ __launch_bounds__(256, 2) void k_gemm_conv(const unsigned short* __restrict__ xpt,
                                                      const unsigned short* __restrict__ Wp,
                                                      unsigned short* __restrict__ kqv,
                                                      const float* __restrict__ bias,
                                                      const char* __restrict__ zp) {
  __shared__ __align__(16) unsigned short As[2][128 * 64];  // 32KB
  __shared__ __align__(16) unsigned short Bs[2][192 * 64];  // 48KB
  const int tid = threadIdx.x, l = tid & 63, w = tid >> 6;
  const int wm = w >> 1, wn = w & 1, g = l >> 4, ln = l & 15;
  const int id = blockIdx.x + (blockIdx.y << 6);
  const int nid = ((id & 7) << 6) + (id >> 3);   // XCD-contiguous remap (512 = 8*64)
  const int m0 = (nid & 63) * 128, n0 = (nid >> 6) * 192;
  const int swz = (l & 7) ^ (l >> 3);

  const char* pAbase[4];
#pragma unroll
  for (int j = 0; j < 4; ++j) {
    int r = m0 + (w * 4 + j) * 8 + (l >> 3);
    pAbase[j] = (const char*)xpt + ((size_t)r * 256 + swz * 8) * 2;
  }
  const char* pB0 = (const char*)Wp +
                    ((size_t)(n0 + w * 48 + (l >> 3)) * 2304 + swz * 8) * 2;

  f32x4 acc[4][6] = {};
  int vmask = 0;
  int aoff = 0;

  auto setTap = [&](int tap) {
    int d3 = (tap * 11) >> 5;  // tap/3
    int dy = d3 - 1, dx = tap - d3 * 3 - 1;
    aoff = (dy * 32 + dx) * 512;
    int m = 0;
#pragma unroll
    for (int j = 0; j < 4; ++j) {
      int r = m0 + (w * 4 + j) * 8 + (l >> 3);
      int y = ((r >> 5) & 31) + dy;
      int x = (r & 31) + dx;
      if (((unsigned)y < 32u) && ((unsigned)x < 32u)) m |= (1 << j);
    }
    vmask = m;
  };

  auto STAGE = [&](int buf, int kb) {
#pragma unroll
    for (int j = 0; j < 4; ++j) {
      const char* a = (vmask & (1 << j)) ? (pAbase[j] + aoff) : zp;
      gload_lds16(a, (char*)As + buf * 16384 + (w * 4 + j) * 1024);
    }
#pragma unroll
    for (int j = 0; j < 6; ++j) {
      gload_lds16(pB0 + j * 36864 + kb, (char*)Bs + buf * 24576 + (w * 6 + j) * 1024);
    }
  };

  auto COMPUTE = [&](int buf) {
    const char* Ab2 = (const char*)As + buf * 16384;
    const char* Bb2 = (const char*)Bs + buf * 24576;
#pragma unroll
    for (int kk = 0; kk < 2; ++kk) {
      short8 af[4], bfr[6];
#pragma unroll
      for (int fm = 0; fm < 4; ++fm)
        af[fm] = *(const short8*)(Ab2 + (wm * 64 + fm * 16 + ln) * 128 +
                                  (((kk * 4 + g) ^ (ln & 7)) * 16));
#pragma unroll
      for (int fn = 0; fn < 6; ++fn)
        bfr[fn] = *(const short8*)(Bb2 + (wn * 96 + fn * 16 + ln) * 128 +
                                   (((kk * 4 + g) ^ (ln & 7)) * 16));
#pragma unroll
      for (int fm = 0; fm < 4; ++fm)
#pragma unroll
        for (int fn = 0; fn < 6; ++fn)
          acc[fm][fn] = __builtin_amdgcn_mfma_f32_16x16x32_bf16(af[fm], bfr[fn], acc[fm][fn], 0, 0, 0);
    }
  };

  setTap(0);
  STAGE(0, 0);
  aoff += 128;
  int kb = 128;
  for (int s = 0; s < 36; ++s) {
    const int buf = s & 1;
    if (s < 35) {
      if (((s + 1) & 3) == 0) setTap((s + 1) >> 2);
      STAGE(buf ^ 1, kb);
      kb += 128;
      aoff += 128;
      asm volatile("s_waitcnt vmcnt(10)" ::: "memory");
    } else {
      asm volatile("s_waitcnt vmcnt(0)" ::: "memory");
    }
    __builtin_amdgcn_s_barrier();
    __builtin_amdgcn_sched_barrier(0);
    COMPUTE(buf);
    asm volatile("s_waitcnt lgkmcnt(0)" ::: "memory");
    __builtin_amdgcn_s_barrier();
    __builtin_amdgcn_sched_barrier(0);
  }

#pragma unroll
  for (int fm = 0; fm < 4; ++fm)
#pragma unroll
    for (int fn = 0; fn < 6; ++fn) {
      int col = n0 + wn * 96 + fn * 16 + ln;
      float bb = bias[col];
#pragma unroll
      for (int r = 0; r < 4; ++r) {
        int row = m0 + wm * 64 + fm * 16 + g * 4 + r;
        kqv[(size_t)row * 1536 + col] = f2bf(acc[fm][fn][r] + bb);
      }
    }
}

// ---------------- GEMM BN=64 (FFN1): bf16 out, + bias[col], LeakyReLU(0.1) ----------------
__global__ __launch_bounds__(256) void k_ffn1(const unsigned short* __restrict__ A,
                                              const unsigned short* __restrict__ B,
                                              unsigned short* __restrict__ Cout,
                                              const float* __restrict__ bias) {
  __shared__ __align__(16) unsigned short As[128 * 64];
  __shared__ __align__(16) unsigned short Bs[64 * 64];
  const int tid = threadIdx.x, l = tid & 63, w = tid >> 6;
  const int g = l >> 4, ln = l & 15;
  const int m0 = blockIdx.x * 128, n0 = blockIdx.y * 64;
  const int swz = (l & 7) ^ (l >> 3);
  f32x4 acc[2][4] = {};

  for (int kt = 0; kt < 256; kt += 64) {
#pragma unroll
    for (int j = 0; j < 4; ++j) {
      int seg = w * 4 + j;
      int r8 = seg * 8 + (l >> 3);
      gload_lds16((const char*)A + ((size_t)(m0 + r8) * 256 + kt + swz * 8) * 2,
                  (char*)As + seg * 1024);
    }
#pragma unroll
    for (int j = 0; j < 2; ++j) {
      int seg = w * 2 + j;
      int r8 = seg * 8 + (l >> 3);
      gload_lds16((const char*)B + ((size_t)(n0 + r8) * 256 + kt + swz * 8) * 2,
                  (char*)Bs + seg * 1024);
    }
    __syncthreads();
#pragma unroll
    for (int kk = 0; kk < 2; ++kk) {
      short8 af[2], bfr[4];
#pragma unroll
      for (int fm = 0; fm < 2; ++fm)
        af[fm] = *(const short8*)((const char*)As + (w * 32 + fm * 16 + ln) * 128 +
                                  (((kk * 4 + g) ^ (ln & 7)) * 16));
#pragma unroll
      for (int fn = 0; fn < 4; ++fn)
        bfr[fn] = *(const short8*)((const char*)Bs + (fn * 16 + ln) * 128 +
                                   (((kk * 4 + g) ^ (ln & 7)) * 16));
#pragma unroll
      for (int fm = 0; fm < 2; ++fm)
#pragma unroll
        for (int fn = 0; fn < 4; ++fn)
          acc[fm][fn] = __builtin_amdgcn_mfma_f32_16x16x32_bf16(af[fm], bfr[fn], acc[fm][fn], 0, 0, 0);
    }
    __syncthreads();
  }

#pragma unroll
  for (int fm = 0; fm < 2; ++fm)
#pragma unroll
    for (int fn = 0; fn < 4; ++fn)
#pragma unroll
      for (int r = 0; r < 4; ++r) {
        int row = m0 + w * 32 + fm * 16 + g * 4 + r;
        int col = n0 + fn * 16 + ln;
        float v = acc[fm][fn][r] + bias[col];
        v = (v > 0.f) ? v : 0.1f * v;
        Cout[(size_t)row * 256 + col] = f2bf(v);
      }
}

// ---------------- K5: fused attention v8 — direct-to-subtile V, no transpose pass ----------------
// v7 reg-staged pipeline, but V registers are ds_written DIRECTLY into the tr-read subtile
// layout (each lane already holds one subtile slot). Subtiles padded to 544B (bank rotate).
// Vs double-buffered (tr_read(s) vs V-write(s+1) share a barrier interval). Vlin deleted.
// T5 setprio around both MFMA clusters.
__global__ __launch_bounds__(512, 4) void k_attn(const unsigned short* __restrict__ kqv,
                                                 unsigned short* __restrict__ part) {
  __shared__ __align__(16) unsigned short Qs[16][512];   // 16KB
  __shared__ __align__(16) char VsRaw[2][32 * 544];      // 34KB, [buf][cb] 544B-strided subtiles
  __shared__ __align__(16) float sums[4][2][64][4];      // 8KB
  const int tid = threadIdx.x, l = tid & 63, w = tid >> 6;
  const int g = l >> 4, ln = l & 15;
  const int nt = w & 1, hg = w >> 1;
  const int id = blockIdx.x;
  const int b = id & 7, ng = (id >> 3) & 31, ch = id >> 8;
  const int n0 = ng * 32 + nt * 16;
  const int m_base = ch * 512;
  const size_t rowBase = (size_t)b * 1024;
  const float SC = 1.0f / 1024.0f;

  short8 ak[2][2];
#pragma unroll
  for (int hl = 0; hl < 2; ++hl)
#pragma unroll
    for (int kk = 0; kk < 2; ++kk)
      ak[hl][kk] = *(const short8*)&kqv[(rowBase + n0 + ln) * 1536 +
                                        (hg * 2 + hl) * 64 + kk * 32 + g * 8];

  f32x4 acc[2][4] = {};

  // reg-staging: rows r0 = w*2, r1 = w*2+1; lane l carries 16B chunk l of Q and V.
  const int r0 = w * 2, r1 = w * 2 + 1;
  const char* pRow = (const char*)kqv +
                     (size_t)(rowBase + m_base + r0) * 3072 + 1024 + (size_t)l * 16;
  uint4 q0, q1, v0, v1;

  auto LOADREGS = [&]() {
    q0 = *(const uint4*)pRow;
    v0 = *(const uint4*)(pRow + 1024);
    q1 = *(const uint4*)(pRow + 3072);
    v1 = *(const uint4*)(pRow + 4096);
    pRow += 49152;  // 16 rows * 3072B
  };
  char* const dQ0 = (char*)Qs + r0 * 1024 + ((l ^ (r0 & 7)) * 16);
  char* const dQ1 = (char*)Qs + r1 * 1024 + ((l ^ (r1 & 7)) * 16);
  // V direct-to-subtile: lane l = V cols l*8..l*8+7 -> subtile l>>1, col-half l&1
  const uint32_t vOff = (uint32_t)(l >> 1) * 544 + (uint32_t)(l & 1) * 16;
  auto DSW = [&](int vbuf) {
    *(uint4*)dQ0 = q0;
    *(uint4*)dQ1 = q1;
    char* vb = VsRaw[vbuf];
    *(uint4*)(vb + vOff + r0 * 32) = v0;
    *(uint4*)(vb + vOff + r1 * 32) = v1;
  };

  // prologue: stage step 0 into buf 0
  LOADREGS();
  asm volatile("s_waitcnt vmcnt(0)" ::: "memory");
  DSW(0);
  asm volatile("s_waitcnt lgkmcnt(0)" ::: "memory");
  __builtin_amdgcn_s_barrier();
  __builtin_amdgcn_sched_barrier(0);

  for (int s = 0; s < 32; ++s) {
    const int buf = s & 1;
    if (s < 31) LOADREGS();  // issue loads for s+1; consumed at end of step

    // --- QK^T for this wave's 2 heads ---
    f32x4 sv[2] = {};
    __builtin_amdgcn_s_setprio(1);
#pragma unroll
    for (int kk = 0; kk < 2; ++kk)
#pragma unroll
      for (int hl = 0; hl < 2; ++hl) {
        int chq = (hg * 2 + hl) * 8 + kk * 4 + g;
        short8 qa = *(const short8*)((const char*)Qs + ln * 1024 +
                                     ((chq ^ (ln & 7)) * 16));
        sv[hl] = __builtin_amdgcn_mfma_f32_16x16x32_bf16(qa, ak[hl][kk], sv[hl], 0, 0, 0);
      }
    __builtin_amdgcn_s_setprio(0);

    // --- exp + partial sums ---
    f32x4 e0, e1, ps;
#pragma unroll
    for (int j = 0; j < 4; ++j) {
      e0[j] = __expf(sv[0][j] * SC);
      e1[j] = __expf(sv[1][j] * SC);
      ps[j] = e0[j] + e1[j];
    }
    *(f32x4*)&sums[hg][nt][l][0] = ps;
    asm volatile("s_waitcnt lgkmcnt(0)" ::: "memory");
    __builtin_amdgcn_s_barrier();  // B3: sums visible (Vs[buf] already valid since prev B1)
    __builtin_amdgcn_sched_barrier(0);

    // --- total over 8 heads; normalize ---
    f32x4 tot = ps;
#pragma unroll
    for (int d = 1; d < 4; ++d) {
      f32x4 o = *(const f32x4*)&sums[(hg + d) & 3][nt][l][0];
      tot[0] += o[0]; tot[1] += o[1]; tot[2] += o[2]; tot[3] += o[3];
    }
    f32x4 inv;
#pragma unroll
    for (int j = 0; j < 4; ++j) inv[j] = __builtin_amdgcn_rcpf(tot[j]);

    // --- PV: batched tr_reads from Vs[buf] + MFMA16 with P from registers ---
    const uint32_t vsB = (uint32_t)(uintptr_t)VsRaw[buf] + l * 8;
    s16x4 vf[8];
#pragma unroll
    for (int hl = 0; hl < 2; ++hl) {
      uint32_t ah = vsB + (hg * 2 + hl) * 2176;  // 4 subtiles * 544B per head
      asm volatile("ds_read_b64_tr_b16 %0, %1" : "=v"(vf[hl * 4 + 0]) : "v"(ah));
      asm volatile("ds_read_b64_tr_b16 %0, %1 offset:544" : "=v"(vf[hl * 4 + 1]) : "v"(ah));
      asm volatile("ds_read_b64_tr_b16 %0, %1 offset:1088" : "=v"(vf[hl * 4 + 2]) : "v"(ah));
      asm volatile("ds_read_b64_tr_b16 %0, %1 offset:1632" : "=v"(vf[hl * 4 + 3]) : "v"(ah));
    }
    asm volatile("s_waitcnt lgkmcnt(0)" ::: "memory");
    __builtin_amdgcn_sched_barrier(0);
    union { uint32_t u[2]; s16x4 v4; } pc0, pc1;
    pc0.u[0] = pkbf(e0[0] * inv[0], e0[1] * inv[1]);
    pc0.u[1] = pkbf(e0[2] * inv[2], e0[3] * inv[3]);
    pc1.u[0] = pkbf(e1[0] * inv[0], e1[1] * inv[1]);
    pc1.u[1] = pkbf(e1[2] * inv[2], e1[3] * inv[3]);
    __builtin_amdgcn_s_setprio(1);
#pragma unroll
    for (int cf = 0; cf < 4; ++cf) {
      acc[0][cf] = MFMA16(vf[cf], pc0.v4, acc[0][cf]);
      acc[1][cf] = MFMA16(vf[4 + cf], pc1.v4, acc[1][cf]);
    }
    __builtin_amdgcn_s_setprio(0);

    // --- write staged regs for s+1: Q into Qs, V directly into Vs[buf^1] ---
    if (s < 31) {
      asm volatile("s_waitcnt vmcnt(0)" ::: "memory");
      DSW(buf ^ 1);
    }
    asm volatile("s_waitcnt lgkmcnt(0)" ::: "memory");
    __builtin_amdgcn_s_barrier();  // B1: next step's Qs/Vs ready
    __builtin_amdgcn_sched_barrier(0);
  }

  const size_t outBase = (size_t)ch * 8192 * 512 + (rowBase + n0 + ln) * 512;
#pragma unroll
  for (int hl = 0; hl < 2; ++hl)
#pragma unroll
    for (int cf = 0; cf < 4; ++cf)
#pragma unroll
      for (int r2 = 0; r2 < 2; ++r2) {
        int c = (hg * 2 + hl) * 64 + cf * 16 + g * 4 + r2 * 2;
        uint32_t u = (uint32_t)f2bf(acc[hl][cf][2 * r2]) |
                     ((uint32_t)f2bf(acc[hl][cf][2 * r2 + 1]) << 16);
        *(uint32_t*)&part[outBase + c] = u;
      }
}

// ---------------- K6: fused attproj + bias + resid(x+pe) + LayerNorm ----------------
__global__ __launch_bounds__(256) void k_projln(const unsigned short* __restrict__ part,
                                                const unsigned short* __restrict__ Wp,
                                                const float* __restrict__ bias,
                                                const float* __restrict__ resid,
                                                const float* __restrict__ lg,
                                                const float* __restrict__ lb,
                                                float* __restrict__ out_f,
                                                unsigned short* __restrict__ out_b) {
  __shared__ __align__(16) unsigned short As[32 * 64];
  __shared__ __align__(16) unsigned short Bs[256 * 64];
  __shared__ float rsum[4][32][2];
  const int tid = threadIdx.x, l = tid & 63, w = tid >> 6;
  const int g4 = l >> 4, ln = l & 15;
  const int m0 = blockIdx.x * 32;
  const int swz = (l & 7) ^ (l >> 3);
  f32x4 acc[2][4] = {};

  for (int kt = 0; kt < 1024; kt += 64) {
    gload_lds16((const char*)part + (((size_t)(kt >> 9) * 8192 * 512) +
                                     (size_t)(m0 + w * 8 + (l >> 3)) * 512 +
                                     (kt & 511) + swz * 8) * 2,
                (char*)As + w * 1024);
#pragma unroll
    for (int j = 0; j < 8; ++j) {
      int seg = w * 8 + j;
      gload_lds16((const char*)Wp + ((size_t)(seg * 8 + (l >> 3)) * 1024 + kt + swz * 8) * 2,
                  (char*)Bs + seg * 1024);
    }
    __syncthreads();
#pragma unroll
    for (int kk = 0; kk < 2; ++kk) {
      short8 af[2], bfr[4];
#pragma unroll
      for (int fm = 0; fm < 2; ++fm)
        af[fm] = *(const short8*)((const char*)As + (fm * 16 + ln) * 128 +
                                  (((kk * 4 + g4) ^ (ln & 7)) * 16));
#pragma unroll
      for (int fn = 0; fn < 4; ++fn)
        bfr[fn] = *(const short8*)((const char*)Bs + (w * 64 + fn * 16 + ln) * 128 +
                                   (((kk * 4 + g4) ^ (ln & 7)) * 16));
#pragma unroll
      for (int fm = 0; fm < 2; ++fm)
#pragma unroll
        for (int fn = 0; fn < 4; ++fn)
          acc[fm][fn] = __builtin_amdgcn_mfma_f32_16x16x32_bf16(af[fm], bfr[fn], acc[fm][fn], 0, 0, 0);
    }
    __syncthreads();
  }

  float vals[2][4][4];
#pragma unroll
  for (int fm = 0; fm < 2; ++fm)
#pragma unroll
    for (int r = 0; r < 4; ++r) {
      int row_l = fm * 16 + g4 * 4 + r;
      float s = 0.f, q = 0.f;
#pragma unroll
      for (int fn = 0; fn < 4; ++fn) {
        int col = w * 64 + fn * 16 + ln;
        float v = acc[fm][fn][r] + bias[col] + resid[(size_t)(m0 + row_l) * 256 + col];
        vals[fm][fn][r] = v;
        s += v;
        q += v * v;
      }
#pragma unroll
      for (int o = 1; o < 16; o <<= 1) {
        s += __shfl_xor(s, o, 64);
        q += __shfl_xor(q, o, 64);
      }
      if (ln == 0) {
        rsum[w][row_l][0] = s;
        rsum[w][row_l][1] = q;
      }
    }
  __syncthreads();

#pragma unroll
  for (int fm = 0; fm < 2; ++fm)
#pragma unroll
    for (int r = 0; r < 4; ++r) {
      int row_l = fm * 16 + g4 * 4 + r;
      float s = rsum[0][row_l][0] + rsum[1][row_l][0] + rsum[2][row_l][0] + rsum[3][row_l][0];
      float q = rsum[0][row_l][1] + rsum[1][row_l][1] + rsum[2][row_l][1] + rsum[3][row_l][1];
      float mu = s * (1.0f / 256.0f);
      float rstd = rsqrtf(q * (1.0f / 256.0f) - mu * mu + 1e-5f);
      size_t rowOff = (size_t)(m0 + row_l) * 256;
#pragma unroll
      for (int fn = 0; fn < 4; ++fn) {
        int col = w * 64 + fn * 16 + ln;
        float o = (vals[fm][fn][r] - mu) * rstd * lg[col] + lb[col];
        out_f[rowOff + col] = o;
        out_b[rowOff + col] = f2bf(o);
      }
    }
}

// ---------------- K7: fused FFN2 + bias + resid + LayerNorm + transposed output ----------------
__global__ __launch_bounds__(256) void k_ffn2out(const unsigned short* __restrict__ h1,
                                                 const unsigned short* __restrict__ W2b,
                                                 const float* __restrict__ b2,
                                                 const float* __restrict__ addnf,
                                                 const float* __restrict__ lg,
                                                 const float* __restrict__ lb,
                                                 float* __restrict__ out) {
  __shared__ __align__(16) unsigned short As[32 * 64];
  __shared__ __align__(16) unsigned short Bs[256 * 64];
  __shared__ __align__(16) float Tt[256][33];
  __shared__ float rsum[4][32][2];
  const int tid = threadIdx.x, l = tid & 63, w = tid >> 6;
  const int g4 = l >> 4, ln = l & 15;
  const int m0 = blockIdx.x * 32;
  const int swz = (l & 7) ^ (l >> 3);
  f32x4 acc[2][4] = {};

  for (int kt = 0; kt < 256; kt += 64) {
    gload_lds16((const char*)h1 + ((size_t)(m0 + w * 8 + (l >> 3)) * 256 + kt + swz * 8) * 2,
                (char*)As + w * 1024);
#pragma unroll
    for (int j = 0; j < 8; ++j) {
      int seg = w * 8 + j;
      gload_lds16((const char*)W2b + ((size_t)(seg * 8 + (l >> 3)) * 256 + kt + swz * 8) * 2,
                  (char*)Bs + seg * 1024);
    }
    __syncthreads();
#pragma unroll
    for (int kk = 0; kk < 2; ++kk) {
      short8 af[2], bfr[4];
#pragma unroll
      for (int fm = 0; fm < 2; ++fm)
        af[fm] = *(const short8*)((const char*)As + (fm * 16 + ln) * 128 +
                                  (((kk * 4 + g4) ^ (ln & 7)) * 16));
#pragma unroll
      for (int fn = 0; fn < 4; ++fn)
        bfr[fn] = *(const short8*)((const char*)Bs + (w * 64 + fn * 16 + ln) * 128 +
                                   (((kk * 4 + g4) ^ (ln & 7)) * 16));
#pragma unroll
      for (int fm = 0; fm < 2; ++fm)
#pragma unroll
        for (int fn = 0; fn < 4; ++fn)
          acc[fm][fn] = __builtin_amdgcn_mfma_f32_16x16x32_bf16(af[fm], bfr[fn], acc[fm][fn], 0, 0, 0);
    }
    __syncthreads();
  }

  float vals[2][4][4];
#pragma unroll
  for (int fm = 0; fm < 2; ++fm)
#pragma unroll
    for (int r = 0; r < 4; ++r) {
      int row_l = fm * 16 + g4 * 4 + r;
      float s = 0.f, q = 0.f;
#pragma unroll
      for (int fn = 0; fn < 4; ++fn) {
        int col = w * 64 + fn * 16 + ln;
        float v = acc[fm][fn][r] + b2[col] + addnf[(size_t)(m0 + row_l) * 256 + col];
        vals[fm][fn][r] = v;
        s += v;
        q += v * v;
      }
#pragma unroll
      for (int o = 1; o < 16; o <<= 1) {
        s += __shfl_xor(s, o, 64);
        q += __shfl_xor(q, o, 64);
      }
      if (ln == 0) {
        rsum[w][row_l][0] = s;
        rsum[w][row_l][1] = q;
      }
    }
  __syncthreads();

#pragma unroll
  for (int fm = 0; fm < 2; ++fm)
#pragma unroll
    for (int r = 0; r < 4; ++r) {
      int row_l = fm * 16 + g4 * 4 + r;
      float s = rsum[0][row_l][0] + rsum[1][row_l][0] + rsum[2][row_l][0] + rsum[3][row_l][0];
      float q = rsum[0][row_l][1] + rsum[1][row_l][1] + rsum[2][row_l][1] + rsum[3][row_l][1];
      float mu = s * (1.0f / 256.0f);
      float rstd = rsqrtf(q * (1.0f / 256.0f) - mu * mu + 1e-5f);
#pragma unroll
      for (int fn = 0; fn < 4; ++fn) {
        int col = w * 64 + fn * 16 + ln;
        Tt[col][row_l] = (vals[fm][fn][r] - mu) * rstd * lg[col] + lb[col];
      }
    }
  __syncthreads();

  const int bimg = m0 >> 10, nn0 = m0 & 1023;
#pragma unroll
  for (int i = 0; i < 8; ++i) {
    int c = i * 32 + (tid >> 3);
    int ng = (tid & 7) * 4;
    float4 o = make_float4(Tt[c][ng], Tt[c][ng + 1], Tt[c][ng + 2], Tt[c][ng + 3]);
    *(float4*)&out[((size_t)bimg * 256 + c) * 1024 + nn0 + ng] = o;
  }
}

// ---------------- host launcher ----------------
extern "C" void kernel_launch(void* const* d_in, const int* in_sizes, int n_in,
                              void* d_out, int out_size, void* d_ws, size_t ws_size,
                              hipStream_t stream) {
  const float* x     = (const float*)d_in[0];
  const float* Wk    = (const float*)d_in[1];
  const float* bk    = (const float*)d_in[2];
  const float* Wq    = (const float*)d_in[3];
  const float* bq    = (const float*)d_in[4];
  const float* Wv    = (const float*)d_in[5];
  const float* bv    = (const float*)d_in[6];
  const float* Wproj = (const float*)d_in[7];
  const float* bproj = (const float*)d_in[8];
  const float* ln_g  = (const float*)d_in[9];
  const float* ln_b  = (const float*)d_in[10];
  const float* W1    = (const float*)d_in[11];
  const float* b1    = (const float*)d_in[12];
  const float* W2    = (const float*)d_in[13];
  const float* b2    = (const float*)d_in[14];

  char* ws = (char*)d_ws;
  constexpr size_t OFF_XPTB  = 0;                                    // bf16 [8192][256]
  constexpr size_t OFF_XPTF  = OFF_XPTB  + (size_t)8192 * 256 * 2;   // f32  [8192][256]
  constexpr size_t OFF_WPACK = OFF_XPTF  + (size_t)8192 * 256 * 4;   // bf16 [1536][2304]
  constexpr size_t OFF_BIAS  = OFF_WPACK + (size_t)1536 * 2304 * 2;  // f32  [1536]
  constexpr size_t OFF_WPROJ = OFF_BIAS  + (size_t)1536 * 4;         // bf16 [256][1024] (dup K)
  constexpr size_t OFF_W1B   = OFF_WPROJ + (size_t)256 * 1024 * 2;   // bf16 [256][256]
  constexpr size_t OFF_W2B   = OFF_W1B   + (size_t)256 * 256 * 2;    // bf16 [256][256]
  constexpr size_t OFF_PET   = OFF_W2B   + (size_t)256 * 256 * 2;    // f32  [256][32]
  constexpr size_t OFF_ZERO  = OFF_PET   + (size_t)256 * 32 * 4;     // f32  [256] zeros (1KB)
  constexpr size_t OFF_KQV   = OFF_ZERO  + 1024;                     // bf16 [8192][1536]
  constexpr size_t OFF_PART  = OFF_KQV   + (size_t)8192 * 1536 * 2;  // bf16 [2][8192][512]
  constexpr size_t OFF_ADDNF = OFF_PART  + (size_t)2 * 8192 * 512 * 2; // f32
  constexpr size_t OFF_ADDNB = OFF_ADDNF + (size_t)8192 * 256 * 4;   // bf16
  constexpr size_t OFF_H1    = OFF_ADDNB + (size_t)8192 * 256 * 2;   // bf16

  (void)in_sizes; (void)n_in; (void)out_size; (void)ws_size;

  const char* zp = (const char*)(ws + OFF_ZERO);

  k_petab<<<1, 256, 0, stream>>>((float*)(ws + OFF_PET), (float*)(ws + OFF_ZERO));
  k_xpt<<<dim3(8, 32, 8), 256, 0, stream>>>(x, (const float*)(ws + OFF_PET),
                                            (unsigned short*)(ws + OFF_XPTB),
                                            (float*)(ws + OFF_XPTF));
  k_packall<<<14336, 256, 0, stream>>>(Wk, Wq, Wv, bk, bq, bv, Wproj, W1, W2,
                                       (unsigned short*)(ws + OFF_WPACK),
                                       (float*)(ws + OFF_BIAS),
                                       (unsigned short*)(ws + OFF_WPROJ),
                                       (unsigned short*)(ws + OFF_W1B),
                                       (unsigned short*)(ws + OFF_W2B));
  // merged conv K+Q+V -> kqv[8192][1536]  (128x192 tile, XCD-contiguous remap)
  k_gemm_conv<<<dim3(64, 8), 256, 0, stream>>>(
      (const unsigned short*)(ws + OFF_XPTB), (const unsigned short*)(ws + OFF_WPACK),
      (unsigned short*)(ws + OFF_KQV), (const float*)(ws + OFF_BIAS), zp);
  // fused attention -> partials [2][8192][512]
  k_attn<<<dim3(512), 512, 0, stream>>>((const unsigned short*)(ws + OFF_KQV),
                                        (unsigned short*)(ws + OFF_PART));
  // attproj + bias + resid + LN (fused) -> addnf f32 + addnb bf16
  k_projln<<<256, 256, 0, stream>>>((const unsigned short*)(ws + OFF_PART),
                                    (const unsigned short*)(ws + OFF_WPROJ), bproj,
                                    (const float*)(ws + OFF_XPTF), ln_g, ln_b,
                                    (float*)(ws + OFF_ADDNF), (unsigned short*)(ws + OFF_ADDNB));
  // FFN1 + LeakyReLU
  k_ffn1<<<dim3(64, 4), 256, 0, stream>>>(
      (const unsigned short*)(ws + OFF_ADDNB), (const unsigned short*)(ws + OFF_W1B),
      (unsigned short*)(ws + OFF_H1), b1);
  // FFN2 + bias + resid + LN + transposed output
  k_ffn2out<<<256, 256, 0, stream>>>((const unsigned short*)(ws + OFF_H1),
                                     (const unsigned short*)(ws + OFF_W2B), b2,
                                     (const float*)(ws + OFF_ADDNF), ln_g, ln_b,
                                     (float*)d_out);
}

// Round 12
// 181.753 us; speedup vs baseline: 1.3695x; 1.0216x over previous
//
#include <hip/hip_runtime.h>
#include <stdint.h>

typedef __attribute__((ext_vector_type(8))) short short8;
typedef __attribute__((ext_vector_type(4))) short s16x4;
typedef __attribute__((ext_vector_type(4))) float f32x4;

#define DEVI __device__ __forceinline__

#if __has_builtin(__builtin_amdgcn_mfma_f32_16x16x16_bf16)
#define MFMA16(a, b, c) __builtin_amdgcn_mfma_f32_16x16x16_bf16(a, b, c, 0, 0, 0)
#else
#define MFMA16(a, b, c) __builtin_amdgcn_mfma_f32_16x16x16bf16_1k(a, b, c, 0, 0, 0)
#endif

DEVI unsigned short f2bf(float f) {
  union { float f; uint32_t u; } v; v.f = f;
  return (unsigned short)((v.u + 0x7fffu + ((v.u >> 16) & 1u)) >> 16);
}

DEVI float bf2f(uint32_t hi16) {
  union { uint32_t u; float f; } v; v.u = hi16;
  return v.f;
}

DEVI uint32_t pkbf(float a, float b) {  // fast RTN pack (positive values)
  union { float f; uint32_t u; } x, y; x.f = a; y.f = b;
  return ((x.u + 0x8000u) >> 16) | (((y.u + 0x8000u) >> 16) << 16);
}

DEVI void gload_lds16(const void* g, void* l) {
  __builtin_amdgcn_global_load_lds(
      (const __attribute__((address_space(1))) uint32_t*)g,
      (__attribute__((address_space(3))) uint32_t*)l, 16, 0, 0);
}

// ---------------- K1: xpT = (x + pe) transposed to [b*1024+n][256], f32 + bf16 ----------------
__global__ __launch_bounds__(256) void k_xpt(const float* __restrict__ x,
                                             const float* __restrict__ T,
                                             unsigned short* __restrict__ xpt_bf,
                                             float* __restrict__ xpt_f) {
  __shared__ __align__(16) float tile[32][36];
  const int b = blockIdx.z, c0 = blockIdx.x * 32, n0 = blockIdx.y * 32;
  const int t = threadIdx.x;
  {
    const int cl = t >> 3, ng = (t & 7) * 4;
    const int c = c0 + cl;
    float4 v = *(const float4*)(x + ((size_t)b * 256 + c) * 1024 + n0 + ng);
    float p0, p1, p2, p3;
    if (c < 128) {
      p0 = T[c * 32 + ng + 0]; p1 = T[c * 32 + ng + 1];
      p2 = T[c * 32 + ng + 2]; p3 = T[c * 32 + ng + 3];
    } else {
      p0 = p1 = p2 = p3 = T[c * 32 + (n0 >> 5)];
    }
    tile[ng + 0][cl] = v.x + p0;
    tile[ng + 1][cl] = v.y + p1;
    tile[ng + 2][cl] = v.z + p2;
    tile[ng + 3][cl] = v.w + p3;
  }
  __syncthreads();
  {
    const int nl = t >> 3, cg = (t & 7) * 4;
    float o0 = tile[nl][cg + 0], o1 = tile[nl][cg + 1];
    float o2 = tile[nl][cg + 2], o3 = tile[nl][cg + 3];
    size_t row = (size_t)b * 1024 + n0 + nl;
    *(float4*)(xpt_f + row * 256 + c0 + cg) = make_float4(o0, o1, o2, o3);
    uint32_t lo = (uint32_t)f2bf(o0) | ((uint32_t)f2bf(o1) << 16);
    uint32_t hi = (uint32_t)f2bf(o2) | ((uint32_t)f2bf(o3) << 16);
    *(uint2*)(xpt_bf + row * 256 + c0 + cg) = make_uint2(lo, hi);
  }
}

// ---------------- K2: all preprocessing in one kernel (packs + pe table + zero page) ------------
__global__ void k_prep(const float* __restrict__ Wk, const float* __restrict__ Wq,
                       const float* __restrict__ Wv, const float* __restrict__ bk,
                       const float* __restrict__ bq, const float* __restrict__ bv,
                       const float* __restrict__ Wproj, const float* __restrict__ W1,
                       const float* __restrict__ W2, unsigned short* __restrict__ Wpack,
                       float* __restrict__ bias_kqv, unsigned short* __restrict__ WprojP,
                       unsigned short* __restrict__ W1b, unsigned short* __restrict__ W2b,
                       float* __restrict__ T, float* __restrict__ zp) {
  int bid = blockIdx.x;
  if (bid < 13824) {
    int i = bid * 256 + threadIdx.x;
    if (i >= 1536 * 2304) return;
    int o = i / 2304, kn = i % 2304;
    int ci = kn & 255, khw = kn >> 8;
    const float* src = (o < 512) ? Wk : ((o < 1024) ? Wq : Wv);
    int oo = o & 511;
    Wpack[i] = f2bf(src[((size_t)oo * 256 + ci) * 9 + khw]);
  } else if (bid < 14336) {
    int i = (bid - 13824) * 256 + threadIdx.x;  // [0, 131072)
    if (i < 1536)
      bias_kqv[i] = (i < 512) ? bk[i] : ((i < 1024) ? bq[i - 512] : bv[i - 1024]);
    {
      int j = i >> 9, f = i & 511;
      int h = f >> 6, c = f & 63;
      unsigned short v = f2bf(Wproj[(size_t)j * 512 + c * 8 + h]);
      WprojP[(size_t)j * 1024 + f] = v;        // K-chunk 0
      WprojP[(size_t)j * 1024 + 512 + f] = v;  // K-chunk 1 (duplicated: O = O0 + O1)
    }
    if (i < 65536) {
      W1b[i] = f2bf(W1[i]);
      W2b[i] = f2bf(W2[i]);
    }
  } else {
    // pe table + zero page (one block)
    int c = threadIdx.x;
    zp[c] = 0.0f;
    int idx = ((c >= 128) ? c - 128 : c) >> 1;
    float freq = expf(-(float)idx * (logf(10000.0f) / 64.0f));
    for (int p = 0; p < 32; ++p) {
      float ang = (float)p * freq;
      T[c * 32 + p] = (c & 1) ? cosf(ang) : sinf(ang);
    }
  }
}

// ---------------- merged conv GEMM v4+XCD: kqv[8192][1536] = im2col(xpt).Wpack^T ----------------
__global__ __launch_bounds__(256, 2) void k_gemm_conv(const unsigned short* __restrict__ xpt,
                                                      const unsigned short* __restrict__ Wp,
                                                      unsigned short* __restrict__ kqv,
                                                      const float* __restrict__ bias,
                                                      const char* __restrict__ zp) {
  __shared__ __align__(16) unsigned short As[2][128 * 64];  // 32KB
  __shared__ __align__(16) unsigned short Bs[2][192 * 64];  // 48KB
  const int tid = threadIdx.x, l = tid & 63, w = tid >> 6;
  const int wm = w >> 1, wn = w & 1, g = l >> 4, ln = l & 15;
  const int id = blockIdx.x + (blockIdx.y << 6);
  const int nid = ((id & 7) << 6) + (id >> 3);   // XCD-contiguous remap (512 = 8*64)
  const int m0 = (nid & 63) * 128, n0 = (nid >> 6) * 192;
  const int swz = (l & 7) ^ (l >> 3);

  const char* pAbase[4];
#pragma unroll
  for (int j = 0; j < 4; ++j) {
    int r = m0 + (w * 4 + j) * 8 + (l >> 3);
    pAbase[j] = (const char*)xpt + ((size_t)r * 256 + swz * 8) * 2;
  }
  const char* pB0 = (const char*)Wp +
                    ((size_t)(n0 + w * 48 + (l >> 3)) * 2304 + swz * 8) * 2;

  f32x4 acc[4][6] = {};
  int vmask = 0;
  int aoff = 0;

  auto setTap = [&](int tap) {
    int d3 = (tap * 11) >> 5;  // tap/3
    int dy = d3 - 1, dx = tap - d3 * 3 - 1;
    aoff = (dy * 32 + dx) * 512;
    int m = 0;
#pragma unroll
    for (int j = 0; j < 4; ++j) {
      int r = m0 + (w * 4 + j) * 8 + (l >> 3);
      int y = ((r >> 5) & 31) + dy;
      int x = (r & 31) + dx;
      if (((unsigned)y < 32u) && ((unsigned)x < 32u)) m |= (1 << j);
    }
    vmask = m;
  };

  auto STAGE = [&](int buf, int kb) {
#pragma unroll
    for (int j = 0; j < 4; ++j) {
      const char* a = (vmask & (1 << j)) ? (pAbase[j] + aoff) : zp;
      gload_lds16(a, (char*)As + buf * 16384 + (w * 4 + j) * 1024);
    }
#pragma unroll
    for (int j = 0; j < 6; ++j) {
      gload_lds16(pB0 + j * 36864 + kb, (char*)Bs + buf * 24576 + (w * 6 + j) * 1024);
    }
  };

  auto COMPUTE = [&](int buf) {
    const char* Ab2 = (const char*)As + buf * 16384;
    const char* Bb2 = (const char*)Bs + buf * 24576;
#pragma unroll
    for (int kk = 0; kk < 2; ++kk) {
      short8 af[4], bfr[6];
#pragma unroll
      for (int fm = 0; fm < 4; ++fm)
        af[fm] = *(const short8*)(Ab2 + (wm * 64 + fm * 16 + ln) * 128 +
                                  (((kk * 4 + g) ^ (ln & 7)) * 16));
#pragma unroll
      for (int fn = 0; fn < 6; ++fn)
        bfr[fn] = *(const short8*)(Bb2 + (wn * 96 + fn * 16 + ln) * 128 +
                                   (((kk * 4 + g) ^ (ln & 7)) * 16));
#pragma unroll
      for (int fm = 0; fm < 4; ++fm)
#pragma unroll
        for (int fn = 0; fn < 6; ++fn)
          acc[fm][fn] = __builtin_amdgcn_mfma_f32_16x16x32_bf16(af[fm], bfr[fn], acc[fm][fn], 0, 0, 0);
    }
  };

  setTap(0);
  STAGE(0, 0);
  aoff += 128;
  int kb = 128;
  for (int s = 0; s < 36; ++s) {
    const int buf = s & 1;
    if (s < 35) {
      if (((s + 1) & 3) == 0) setTap((s + 1) >> 2);
      STAGE(buf ^ 1, kb);
      kb += 128;
      aoff += 128;
      asm volatile("s_waitcnt vmcnt(10)" ::: "memory");
    } else {
      asm volatile("s_waitcnt vmcnt(0)" ::: "memory");
    }
    __builtin_amdgcn_s_barrier();
    __builtin_amdgcn_sched_barrier(0);
    COMPUTE(buf);
    asm volatile("s_waitcnt lgkmcnt(0)" ::: "memory");
    __builtin_amdgcn_s_barrier();
    __builtin_amdgcn_sched_barrier(0);
  }

#pragma unroll
  for (int fm = 0; fm < 4; ++fm)
#pragma unroll
    for (int fn = 0; fn < 6; ++fn) {
      int col = n0 + wn * 96 + fn * 16 + ln;
      float bb = bias[col];
#pragma unroll
      for (int r = 0; r < 4; ++r) {
        int row = m0 + wm * 64 + fm * 16 + g * 4 + r;
        kqv[(size_t)row * 1536 + col] = f2bf(acc[fm][fn][r] + bb);
      }
    }
}

// ---------------- K5: fused attention v8 — direct-to-subtile V (unchanged from R11) ----------------
__global__ __launch_bounds__(512, 4) void k_attn(const unsigned short* __restrict__ kqv,
                                                 unsigned short* __restrict__ part) {
  __shared__ __align__(16) unsigned short Qs[16][512];   // 16KB
  __shared__ __align__(16) char VsRaw[2][32 * 544];      // 34KB
  __shared__ __align__(16) float sums[4][2][64][4];      // 8KB
  const int tid = threadIdx.x, l = tid & 63, w = tid >> 6;
  const int g = l >> 4, ln = l & 15;
  const int nt = w & 1, hg = w >> 1;
  const int id = blockIdx.x;
  const int b = id & 7, ng = (id >> 3) & 31, ch = id >> 8;
  const int n0 = ng * 32 + nt * 16;
  const int m_base = ch * 512;
  const size_t rowBase = (size_t)b * 1024;
  const float SC = 1.0f / 1024.0f;

  short8 ak[2][2];
#pragma unroll
  for (int hl = 0; hl < 2; ++hl)
#pragma unroll
    for (int kk = 0; kk < 2; ++kk)
      ak[hl][kk] = *(const short8*)&kqv[(rowBase + n0 + ln) * 1536 +
                                        (hg * 2 + hl) * 64 + kk * 32 + g * 8];

  f32x4 acc[2][4] = {};

  const int r0 = w * 2, r1 = w * 2 + 1;
  const char* pRow = (const char*)kqv +
                     (size_t)(rowBase + m_base + r0) * 3072 + 1024 + (size_t)l * 16;
  uint4 q0, q1, v0, v1;

  auto LOADREGS = [&]() {
    q0 = *(const uint4*)pRow;
    v0 = *(const uint4*)(pRow + 1024);
    q1 = *(const uint4*)(pRow + 3072);
    v1 = *(const uint4*)(pRow + 4096);
    pRow += 49152;
  };
  char* const dQ0 = (char*)Qs + r0 * 1024 + ((l ^ (r0 & 7)) * 16);
  char* const dQ1 = (char*)Qs + r1 * 1024 + ((l ^ (r1 & 7)) * 16);
  const uint32_t vOff = (uint32_t)(l >> 1) * 544 + (uint32_t)(l & 1) * 16;
  auto DSW = [&](int vbuf) {
    *(uint4*)dQ0 = q0;
    *(uint4*)dQ1 = q1;
    char* vb = VsRaw[vbuf];
    *(uint4*)(vb + vOff + r0 * 32) = v0;
    *(uint4*)(vb + vOff + r1 * 32) = v1;
  };

  LOADREGS();
  asm volatile("s_waitcnt vmcnt(0)" ::: "memory");
  DSW(0);
  asm volatile("s_waitcnt lgkmcnt(0)" ::: "memory");
  __builtin_amdgcn_s_barrier();
  __builtin_amdgcn_sched_barrier(0);

  for (int s = 0; s < 32; ++s) {
    const int buf = s & 1;
    if (s < 31) LOADREGS();

    f32x4 sv[2] = {};
    __builtin_amdgcn_s_setprio(1);
#pragma unroll
    for (int kk = 0; kk < 2; ++kk)
#pragma unroll
      for (int hl = 0; hl < 2; ++hl) {
        int chq = (hg * 2 + hl) * 8 + kk * 4 + g;
        short8 qa = *(const short8*)((const char*)Qs + ln * 1024 +
                                     ((chq ^ (ln & 7)) * 16));
        sv[hl] = __builtin_amdgcn_mfma_f32_16x16x32_bf16(qa, ak[hl][kk], sv[hl], 0, 0, 0);
      }
    __builtin_amdgcn_s_setprio(0);

    f32x4 e0, e1, ps;
#pragma unroll
    for (int j = 0; j < 4; ++j) {
      e0[j] = __expf(sv[0][j] * SC);
      e1[j] = __expf(sv[1][j] * SC);
      ps[j] = e0[j] + e1[j];
    }
    *(f32x4*)&sums[hg][nt][l][0] = ps;
    asm volatile("s_waitcnt lgkmcnt(0)" ::: "memory");
    __builtin_amdgcn_s_barrier();
    __builtin_amdgcn_sched_barrier(0);

    f32x4 tot = ps;
#pragma unroll
    for (int d = 1; d < 4; ++d) {
      f32x4 o = *(const f32x4*)&sums[(hg + d) & 3][nt][l][0];
      tot[0] += o[0]; tot[1] += o[1]; tot[2] += o[2]; tot[3] += o[3];
    }
    f32x4 inv;
#pragma unroll
    for (int j = 0; j < 4; ++j) inv[j] = __builtin_amdgcn_rcpf(tot[j]);

    const uint32_t vsB = (uint32_t)(uintptr_t)VsRaw[buf] + l * 8;
    s16x4 vf[8];
#pragma unroll
    for (int hl = 0; hl < 2; ++hl) {
      uint32_t ah = vsB + (hg * 2 + hl) * 2176;
      asm volatile("ds_read_b64_tr_b16 %0, %1" : "=v"(vf[hl * 4 + 0]) : "v"(ah));
      asm volatile("ds_read_b64_tr_b16 %0, %1 offset:544" : "=v"(vf[hl * 4 + 1]) : "v"(ah));
      asm volatile("ds_read_b64_tr_b16 %0, %1 offset:1088" : "=v"(vf[hl * 4 + 2]) : "v"(ah));
      asm volatile("ds_read_b64_tr_b16 %0, %1 offset:1632" : "=v"(vf[hl * 4 + 3]) : "v"(ah));
    }
    asm volatile("s_waitcnt lgkmcnt(0)" ::: "memory");
    __builtin_amdgcn_sched_barrier(0);
    union { uint32_t u[2]; s16x4 v4; } pc0, pc1;
    pc0.u[0] = pkbf(e0[0] * inv[0], e0[1] * inv[1]);
    pc0.u[1] = pkbf(e0[2] * inv[2], e0[3] * inv[3]);
    pc1.u[0] = pkbf(e1[0] * inv[0], e1[1] * inv[1]);
    pc1.u[1] = pkbf(e1[2] * inv[2], e1[3] * inv[3]);
    __builtin_amdgcn_s_setprio(1);
#pragma unroll
    for (int cf = 0; cf < 4; ++cf) {
      acc[0][cf] = MFMA16(vf[cf], pc0.v4, acc[0][cf]);
      acc[1][cf] = MFMA16(vf[4 + cf], pc1.v4, acc[1][cf]);
    }
    __builtin_amdgcn_s_setprio(0);

    if (s < 31) {
      asm volatile("s_waitcnt vmcnt(0)" ::: "memory");
      DSW(buf ^ 1);
    }
    asm volatile("s_waitcnt lgkmcnt(0)" ::: "memory");
    __builtin_amdgcn_s_barrier();
    __builtin_amdgcn_sched_barrier(0);
  }

  const size_t outBase = (size_t)ch * 8192 * 512 + (rowBase + n0 + ln) * 512;
#pragma unroll
  for (int hl = 0; hl < 2; ++hl)
#pragma unroll
    for (int cf = 0; cf < 4; ++cf)
#pragma unroll
      for (int r2 = 0; r2 < 2; ++r2) {
        int c = (hg * 2 + hl) * 64 + cf * 16 + g * 4 + r2 * 2;
        uint32_t u = (uint32_t)f2bf(acc[hl][cf][2 * r2]) |
                     ((uint32_t)f2bf(acc[hl][cf][2 * r2 + 1]) << 16);
        *(uint32_t*)&part[outBase + c] = u;
      }
}

// ---------------- K6: fused attproj + bias + resid + LayerNorm + FFN1(LeakyReLU) ----------------
// Phase 1: y = part @ WprojP^T (K=1024) + bias + resid; LN -> addnf f32 + LN'd bf16 rows kept
//          in a chunk-swizzled LDS A-tile (As2[32][256]).
// Phase 2: h1 = leaky(As2 @ W1^T + b1), K=256 in 4 chunks staged through Bs.
__global__ __launch_bounds__(256) void k_projffn1(const unsigned short* __restrict__ part,
                                                  const unsigned short* __restrict__ Wp,
                                                  const float* __restrict__ bias,
                                                  const float* __restrict__ resid,
                                                  const float* __restrict__ lg,
                                                  const float* __restrict__ lb,
                                                  float* __restrict__ addnf,
                                                  const unsigned short* __restrict__ W1b,
                                                  const float* __restrict__ b1,
                                                  unsigned short* __restrict__ h1) {
  __shared__ __align__(16) unsigned short As[32 * 64];    // 4KB  (phase-1 A staging)
  __shared__ __align__(16) unsigned short Bs[256 * 64];   // 32KB (B staging, both phases)
  __shared__ __align__(16) unsigned short As2[32 * 256];  // 16KB (LN'd rows, chunk-swizzled)
  __shared__ float rsum[4][32][2];
  const int tid = threadIdx.x, l = tid & 63, w = tid >> 6;
  const int g4 = l >> 4, ln = l & 15;
  const int m0 = blockIdx.x * 32;
  const int swz = (l & 7) ^ (l >> 3);
  f32x4 acc[2][4] = {};

  // ---- phase 1: attproj GEMM (K=1024 over split partials) ----
  for (int kt = 0; kt < 1024; kt += 64) {
    gload_lds16((const char*)part + (((size_t)(kt >> 9) * 8192 * 512) +
                                     (size_t)(m0 + w * 8 + (l >> 3)) * 512 +
                                     (kt & 511) + swz * 8) * 2,
                (char*)As + w * 1024);
#pragma unroll
    for (int j = 0; j < 8; ++j) {
      int seg = w * 8 + j;
      gload_lds16((const char*)Wp + ((size_t)(seg * 8 + (l >> 3)) * 1024 + kt + swz * 8) * 2,
                  (char*)Bs + seg * 1024);
    }
    __syncthreads();
#pragma unroll
    for (int kk = 0; kk < 2; ++kk) {
      short8 af[2], bfr[4];
#pragma unroll
      for (int fm = 0; fm < 2; ++fm)
        af[fm] = *(const short8*)((const char*)As + (fm * 16 + ln) * 128 +
                                  (((kk * 4 + g4) ^ (ln & 7)) * 16));
#pragma unroll
      for (int fn = 0; fn < 4; ++fn)
        bfr[fn] = *(const short8*)((const char*)Bs + (w * 64 + fn * 16 + ln) * 128 +
                                   (((kk * 4 + g4) ^ (ln & 7)) * 16));
#pragma unroll
      for (int fm = 0; fm < 2; ++fm)
#pragma unroll
        for (int fn = 0; fn < 4; ++fn)
          acc[fm][fn] = __builtin_amdgcn_mfma_f32_16x16x32_bf16(af[fm], bfr[fn], acc[fm][fn], 0, 0, 0);
    }
    __syncthreads();
  }

  // ---- bias + residual + LN stats ----
  float vals[2][4][4];
#pragma unroll
  for (int fm = 0; fm < 2; ++fm)
#pragma unroll
    for (int r = 0; r < 4; ++r) {
      int row_l = fm * 16 + g4 * 4 + r;
      float s = 0.f, q = 0.f;
#pragma unroll
      for (int fn = 0; fn < 4; ++fn) {
        int col = w * 64 + fn * 16 + ln;
        float v = acc[fm][fn][r] + bias[col] + resid[(size_t)(m0 + row_l) * 256 + col];
        vals[fm][fn][r] = v;
        s += v;
        q += v * v;
      }
#pragma unroll
      for (int o = 1; o < 16; o <<= 1) {
        s += __shfl_xor(s, o, 64);
        q += __shfl_xor(q, o, 64);
      }
      if (ln == 0) {
        rsum[w][row_l][0] = s;
        rsum[w][row_l][1] = q;
      }
    }
  __syncthreads();

  // ---- LN -> addnf (f32) + As2 (bf16, chunk-swizzled: slot = chunk ^ (row&7)) ----
#pragma unroll
  for (int fm = 0; fm < 2; ++fm)
#pragma unroll
    for (int r = 0; r < 4; ++r) {
      int row_l = fm * 16 + g4 * 4 + r;
      float s = rsum[0][row_l][0] + rsum[1][row_l][0] + rsum[2][row_l][0] + rsum[3][row_l][0];
      float q = rsum[0][row_l][1] + rsum[1][row_l][1] + rsum[2][row_l][1] + rsum[3][row_l][1];
      float mu = s * (1.0f / 256.0f);
      float rstd = rsqrtf(q * (1.0f / 256.0f) - mu * mu + 1e-5f);
      size_t rowOff = (size_t)(m0 + row_l) * 256;
#pragma unroll
      for (int fn = 0; fn < 4; ++fn) {
        int col = w * 64 + fn * 16 + ln;
        float o = (vals[fm][fn][r] - mu) * rstd * lg[col] + lb[col];
        addnf[rowOff + col] = o;
        int chunk = col >> 3;
        int slot = chunk ^ (row_l & 7);
        *(unsigned short*)((char*)As2 + row_l * 512 + slot * 16 + (col & 7) * 2) = f2bf(o);
      }
    }
  __syncthreads();

  // ---- phase 2: FFN1 GEMM h1 = leaky(As2 @ W1^T + b1), K=256 ----
  f32x4 acc2[2][4] = {};
  for (int kt = 0; kt < 256; kt += 64) {
#pragma unroll
    for (int j = 0; j < 8; ++j) {
      int seg = w * 8 + j;
      gload_lds16((const char*)W1b + ((size_t)(seg * 8 + (l >> 3)) * 256 + kt + swz * 8) * 2,
                  (char*)Bs + seg * 1024);
    }
    __syncthreads();
#pragma unroll
    for (int kk = 0; kk < 2; ++kk) {
      short8 af[2], bfr[4];
#pragma unroll
      for (int fm = 0; fm < 2; ++fm) {
        int row = fm * 16 + ln;
        int chunk = (kt >> 3) + kk * 4 + g4;
        af[fm] = *(const short8*)((const char*)As2 + row * 512 +
                                  ((chunk ^ (row & 7)) * 16));
      }
#pragma unroll
      for (int fn = 0; fn < 4; ++fn)
        bfr[fn] = *(const short8*)((const char*)Bs + (w * 64 + fn * 16 + ln) * 128 +
                                   (((kk * 4 + g4) ^ (ln & 7)) * 16));
#pragma unroll
      for (int fm = 0; fm < 2; ++fm)
#pragma unroll
        for (int fn = 0; fn < 4; ++fn)
          acc2[fm][fn] = __builtin_amdgcn_mfma_f32_16x16x32_bf16(af[fm], bfr[fn], acc2[fm][fn], 0, 0, 0);
    }
    __syncthreads();
  }

#pragma unroll
  for (int fm = 0; fm < 2; ++fm)
#pragma unroll
    for (int fn = 0; fn < 4; ++fn)
#pragma unroll
      for (int r = 0; r < 4; ++r) {
        int row = m0 + fm * 16 + g4 * 4 + r;
        int col = w * 64 + fn * 16 + ln;
        float v = acc2[fm][fn][r] + b1[col];
        v = (v > 0.f) ? v : 0.1f * v;
        h1[(size_t)row * 256 + col] = f2bf(v);
      }
}

// ---------------- K7: fused FFN2 + bias + resid + LayerNorm + transposed output ----------------
__global__ __launch_bounds__(256) void k_ffn2out(const unsigned short* __restrict__ h1,
                                                 const unsigned short* __restrict__ W2b,
                                                 const float* __restrict__ b2,
                                                 const float* __restrict__ addnf,
                                                 const float* __restrict__ lg,
                                                 const float* __restrict__ lb,
                                                 float* __restrict__ out) {
  __shared__ __align__(16) unsigned short As[32 * 64];
  __shared__ __align__(16) unsigned short Bs[256 * 64];
  __shared__ __align__(16) float Tt[256][33];
  __shared__ float rsum[4][32][2];
  const int tid = threadIdx.x, l = tid & 63, w = tid >> 6;
  const int g4 = l >> 4, ln = l & 15;
  const int m0 = blockIdx.x * 32;
  const int swz = (l & 7) ^ (l >> 3);
  f32x4 acc[2][4] = {};

  for (int kt = 0; kt < 256; kt += 64) {
    gload_lds16((const char*)h1 + ((size_t)(m0 + w * 8 + (l >> 3)) * 256 + kt + swz * 8) * 2,
                (char*)As + w * 1024);
#pragma unroll
    for (int j = 0; j < 8; ++j) {
      int seg = w * 8 + j;
      gload_lds16((const char*)W2b + ((size_t)(seg * 8 + (l >> 3)) * 256 + kt + swz * 8) * 2,
                  (char*)Bs + seg * 1024);
    }
    __syncthreads();
#pragma unroll
    for (int kk = 0; kk < 2; ++kk) {
      short8 af[2], bfr[4];
#pragma unroll
      for (int fm = 0; fm < 2; ++fm)
        af[fm] = *(const short8*)((const char*)As + (fm * 16 + ln) * 128 +
                                  (((kk * 4 + g4) ^ (ln & 7)) * 16));
#pragma unroll
      for (int fn = 0; fn < 4; ++fn)
        bfr[fn] = *(const short8*)((const char*)Bs + (w * 64 + fn * 16 + ln) * 128 +
                                   (((kk * 4 + g4) ^ (ln & 7)) * 16));
#pragma unroll
      for (int fm = 0; fm < 2; ++fm)
#pragma unroll
        for (int fn = 0; fn < 4; ++fn)
          acc[fm][fn] = __builtin_amdgcn_mfma_f32_16x16x32_bf16(af[fm], bfr[fn], acc[fm][fn], 0, 0, 0);
    }
    __syncthreads();
  }

  float vals[2][4][4];
#pragma unroll
  for (int fm = 0; fm < 2; ++fm)
#pragma unroll
    for (int r = 0; r < 4; ++r) {
      int row_l = fm * 16 + g4 * 4 + r;
      float s = 0.f, q = 0.f;
#pragma unroll
      for (int fn = 0; fn < 4; ++fn) {
        int col = w * 64 + fn * 16 + ln;
        float v = acc[fm][fn][r] + b2[col] + addnf[(size_t)(m0 + row_l) * 256 + col];
        vals[fm][fn][r] = v;
        s += v;
        q += v * v;
      }
#pragma unroll
      for (int o = 1; o < 16; o <<= 1) {
        s += __shfl_xor(s, o, 64);
        q += __shfl_xor(q, o, 64);
      }
      if (ln == 0) {
        rsum[w][row_l][0] = s;
        rsum[w][row_l][1] = q;
      }
    }
  __syncthreads();

#pragma unroll
  for (int fm = 0; fm < 2; ++fm)
#pragma unroll
    for (int r = 0; r < 4; ++r) {
      int row_l = fm * 16 + g4 * 4 + r;
      float s = rsum[0][row_l][0] + rsum[1][row_l][0] + rsum[2][row_l][0] + rsum[3][row_l][0];
      float q = rsum[0][row_l][1] + rsum[1][row_l][1] + rsum[2][row_l][1] + rsum[3][row_l][1];
      float mu = s * (1.0f / 256.0f);
      float rstd = rsqrtf(q * (1.0f / 256.0f) - mu * mu + 1e-5f);
#pragma unroll
      for (int fn = 0; fn < 4; ++fn) {
        int col = w * 64 + fn * 16 + ln;
        Tt[col][row_l] = (vals[fm][fn][r] - mu) * rstd * lg[col] + lb[col];
      }
    }
  __syncthreads();

  const int bimg = m0 >> 10, nn0 = m0 & 1023;
#pragma unroll
  for (int i = 0; i < 8; ++i) {
    int c = i * 32 + (tid >> 3);
    int ng = (tid & 7) * 4;
    float4 o = make_float4(Tt[c][ng], Tt[c][ng + 1], Tt[c][ng + 2], Tt[c][ng + 3]);
    *(float4*)&out[((size_t)bimg * 256 + c) * 1024 + nn0 + ng] = o;
  }
}

// ---------------- host launcher ----------------
extern "C" void kernel_launch(void* const* d_in, const int* in_sizes, int n_in,
                              void* d_out, int out_size, void* d_ws, size_t ws_size,
                              hipStream_t stream) {
  const float* x     = (const float*)d_in[0];
  const float* Wk    = (const float*)d_in[1];
  const float* bk    = (const float*)d_in[2];
  const float* Wq    = (const float*)d_in[3];
  const float* bq    = (const float*)d_in[4];
  const float* Wv    = (const float*)d_in[5];
  const float* bv    = (const float*)d_in[6];
  const float* Wproj = (const float*)d_in[7];
  const float* bproj = (const float*)d_in[8];
  const float* ln_g  = (const float*)d_in[9];
  const float* ln_b  = (const float*)d_in[10];
  const float* W1    = (const float*)d_in[11];
  const float* b1    = (const float*)d_in[12];
  const float* W2    = (const float*)d_in[13];
  const float* b2    = (const float*)d_in[14];

  char* ws = (char*)d_ws;
  constexpr size_t OFF_XPTB  = 0;                                    // bf16 [8192][256]
  constexpr size_t OFF_XPTF  = OFF_XPTB  + (size_t)8192 * 256 * 2;   // f32  [8192][256]
  constexpr size_t OFF_WPACK = OFF_XPTF  + (size_t)8192 * 256 * 4;   // bf16 [1536][2304]
  constexpr size_t OFF_BIAS  = OFF_WPACK + (size_t)1536 * 2304 * 2;  // f32  [1536]
  constexpr size_t OFF_WPROJ = OFF_BIAS  + (size_t)1536 * 4;         // bf16 [256][1024] (dup K)
  constexpr size_t OFF_W1B   = OFF_WPROJ + (size_t)256 * 1024 * 2;   // bf16 [256][256]
  constexpr size_t OFF_W2B   = OFF_W1B   + (size_t)256 * 256 * 2;    // bf16 [256][256]
  constexpr size_t OFF_PET   = OFF_W2B   + (size_t)256 * 256 * 2;    // f32  [256][32]
  constexpr size_t OFF_ZERO  = OFF_PET   + (size_t)256 * 32 * 4;     // f32  [256] zeros (1KB)
  constexpr size_t OFF_KQV   = OFF_ZERO  + 1024;                     // bf16 [8192][1536]
  constexpr size_t OFF_PART  = OFF_KQV   + (size_t)8192 * 1536 * 2;  // bf16 [2][8192][512]
  constexpr size_t OFF_ADDNF = OFF_PART  + (size_t)2 * 8192 * 512 * 2; // f32
  constexpr size_t OFF_H1    = OFF_ADDNF + (size_t)8192 * 256 * 4;   // bf16

  (void)in_sizes; (void)n_in; (void)out_size; (void)ws_size;

  const char* zp = (const char*)(ws + OFF_ZERO);

  k_prep<<<14337, 256, 0, stream>>>(Wk, Wq, Wv, bk, bq, bv, Wproj, W1, W2,
                                    (unsigned short*)(ws + OFF_WPACK),
                                    (float*)(ws + OFF_BIAS),
                                    (unsigned short*)(ws + OFF_WPROJ),
                                    (unsigned short*)(ws + OFF_W1B),
                                    (unsigned short*)(ws + OFF_W2B),
                                    (float*)(ws + OFF_PET), (float*)(ws + OFF_ZERO));
  k_xpt<<<dim3(8, 32, 8), 256, 0, stream>>>(x, (const float*)(ws + OFF_PET),
                                            (unsigned short*)(ws + OFF_XPTB),
                                            (float*)(ws + OFF_XPTF));
  // merged conv K+Q+V -> kqv[8192][1536]  (128x192 tile, XCD-contiguous remap)
  k_gemm_conv<<<dim3(64, 8), 256, 0, stream>>>(
      (const unsigned short*)(ws + OFF_XPTB), (const unsigned short*)(ws + OFF_WPACK),
      (unsigned short*)(ws + OFF_KQV), (const float*)(ws + OFF_BIAS), zp);
  // fused attention -> partials [2][8192][512]
  k_attn<<<dim3(512), 512, 0, stream>>>((const unsigned short*)(ws + OFF_KQV),
                                        (unsigned short*)(ws + OFF_PART));
  // attproj + bias + resid + LN + FFN1 (fused) -> addnf f32 + h1 bf16
  k_projffn1<<<256, 256, 0, stream>>>((const unsigned short*)(ws + OFF_PART),
                                      (const unsigned short*)(ws + OFF_WPROJ), bproj,
                                      (const float*)(ws + OFF_XPTF), ln_g, ln_b,
                                      (float*)(ws + OFF_ADDNF),
                                      (const unsigned short*)(ws + OFF_W1B), b1,
                                      (unsigned short*)(ws + OFF_H1));
  // FFN2 + bias + resid + LN + transposed output
  k_ffn2out<<<256, 256, 0, stream>>>((const unsigned short*)(ws + OFF_H1),
                                     (const unsigned short*)(ws + OFF_W2B), b2,
                                     (const float*)(ws + OFF_ADDNF), ln_g, ln_b,
                                     (float*)d_out);
}

// Round 13
// 173.102 us; speedup vs baseline: 1.4379x; 1.0500x over previous
//
#include <hip/hip_runtime.h>
#include <stdint.h>

typedef __attribute__((ext_vector_type(8))) short short8;
typedef __attribute__((ext_vector_type(4))) short s16x4;
typedef __attribute__((ext_vector_type(4))) float f32x4;

#define DEVI __device__ __forceinline__

#if __has_builtin(__builtin_amdgcn_mfma_f32_16x16x16_bf16)
#define MFMA16(a, b, c) __builtin_amdgcn_mfma_f32_16x16x16_bf16(a, b, c, 0, 0, 0)
#else
#define MFMA16(a, b, c) __builtin_amdgcn_mfma_f32_16x16x16bf16_1k(a, b, c, 0, 0, 0)
#endif

DEVI unsigned short f2bf(float f) {
  union { float f; uint32_t u; } v; v.f = f;
  return (unsigned short)((v.u + 0x7fffu + ((v.u >> 16) & 1u)) >> 16);
}

DEVI float bf2f(uint32_t hi16) {
  union { uint32_t u; float f; } v; v.u = hi16;
  return v.f;
}

DEVI uint32_t pkbf(float a, float b) {  // fast RTN pack (positive values)
  union { float f; uint32_t u; } x, y; x.f = a; y.f = b;
  return ((x.u + 0x8000u) >> 16) | (((y.u + 0x8000u) >> 16) << 16);
}

DEVI void gload_lds16(const void* g, void* l) {
  __builtin_amdgcn_global_load_lds(
      (const __attribute__((address_space(1))) uint32_t*)g,
      (__attribute__((address_space(3))) uint32_t*)l, 16, 0, 0);
}

// ---------------- K1: xpT = (x + pe) transposed to [b*1024+n][256], f32 + bf16 ----------------
__global__ __launch_bounds__(256) void k_xpt(const float* __restrict__ x,
                                             const float* __restrict__ T,
                                             unsigned short* __restrict__ xpt_bf,
                                             float* __restrict__ xpt_f) {
  __shared__ __align__(16) float tile[32][36];
  const int b = blockIdx.z, c0 = blockIdx.x * 32, n0 = blockIdx.y * 32;
  const int t = threadIdx.x;
  {
    const int cl = t >> 3, ng = (t & 7) * 4;
    const int c = c0 + cl;
    float4 v = *(const float4*)(x + ((size_t)b * 256 + c) * 1024 + n0 + ng);
    float p0, p1, p2, p3;
    if (c < 128) {
      p0 = T[c * 32 + ng + 0]; p1 = T[c * 32 + ng + 1];
      p2 = T[c * 32 + ng + 2]; p3 = T[c * 32 + ng + 3];
    } else {
      p0 = p1 = p2 = p3 = T[c * 32 + (n0 >> 5)];
    }
    tile[ng + 0][cl] = v.x + p0;
    tile[ng + 1][cl] = v.y + p1;
    tile[ng + 2][cl] = v.z + p2;
    tile[ng + 3][cl] = v.w + p3;
  }
  __syncthreads();
  {
    const int nl = t >> 3, cg = (t & 7) * 4;
    float o0 = tile[nl][cg + 0], o1 = tile[nl][cg + 1];
    float o2 = tile[nl][cg + 2], o3 = tile[nl][cg + 3];
    size_t row = (size_t)b * 1024 + n0 + nl;
    *(float4*)(xpt_f + row * 256 + c0 + cg) = make_float4(o0, o1, o2, o3);
    uint32_t lo = (uint32_t)f2bf(o0) | ((uint32_t)f2bf(o1) << 16);
    uint32_t hi = (uint32_t)f2bf(o2) | ((uint32_t)f2bf(o3) << 16);
    *(uint2*)(xpt_bf + row * 256 + c0 + cg) = make_uint2(lo, hi);
  }
}

// ---------------- K2: all preprocessing in one kernel (packs + pe table + zero page) ------------
__global__ void k_prep(const float* __restrict__ Wk, const float* __restrict__ Wq,
                       const float* __restrict__ Wv, const float* __restrict__ bk,
                       const float* __restrict__ bq, const float* __restrict__ bv,
                       const float* __restrict__ Wproj, const float* __restrict__ W1,
                       const float* __restrict__ W2, unsigned short* __restrict__ Wpack,
                       float* __restrict__ bias_kqv, unsigned short* __restrict__ WprojP,
                       unsigned short* __restrict__ W1b, unsigned short* __restrict__ W2b,
                       float* __restrict__ T, float* __restrict__ zp) {
  int bid = blockIdx.x;
  if (bid < 13824) {
    int i = bid * 256 + threadIdx.x;
    if (i >= 1536 * 2304) return;
    int o = i / 2304, kn = i % 2304;
    int ci = kn & 255, khw = kn >> 8;
    const float* src = (o < 512) ? Wk : ((o < 1024) ? Wq : Wv);
    int oo = o & 511;
    Wpack[i] = f2bf(src[((size_t)oo * 256 + ci) * 9 + khw]);
  } else if (bid < 14336) {
    int i = (bid - 13824) * 256 + threadIdx.x;  // [0, 131072)
    if (i < 1536)
      bias_kqv[i] = (i < 512) ? bk[i] : ((i < 1024) ? bq[i - 512] : bv[i - 1024]);
    {
      int j = i >> 9, f = i & 511;
      int h = f >> 6, c = f & 63;
      unsigned short v = f2bf(Wproj[(size_t)j * 512 + c * 8 + h]);
      WprojP[(size_t)j * 1024 + f] = v;        // K-chunk 0
      WprojP[(size_t)j * 1024 + 512 + f] = v;  // K-chunk 1 (duplicated: O = O0 + O1)
    }
    if (i < 65536) {
      W1b[i] = f2bf(W1[i]);
      W2b[i] = f2bf(W2[i]);
    }
  } else {
    int c = threadIdx.x;
    zp[c] = 0.0f;
    int idx = ((c >= 128) ? c - 128 : c) >> 1;
    float freq = expf(-(float)idx * (logf(10000.0f) / 64.0f));
    for (int p = 0; p < 32; ++p) {
      float ang = (float)p * freq;
      T[c * 32 + p] = (c & 1) ? cosf(ang) : sinf(ang);
    }
  }
}

// ---------------- merged conv GEMM v4+XCD: kqv[8192][1536] = im2col(xpt).Wpack^T ----------------
__global__ __launch_bounds__(256, 2) void k_gemm_conv(const unsigned short* __restrict__ xpt,
                                                      const unsigned short* __restrict__ Wp,
                                                      unsigned short* __restrict__ kqv,
                                                      const float* __restrict__ bias,
                                                      const char* __restrict__ zp) {
  __shared__ __align__(16) unsigned short As[2][128 * 64];  // 32KB
  __shared__ __align__(16) unsigned short Bs[2][192 * 64];  // 48KB
  const int tid = threadIdx.x, l = tid & 63, w = tid >> 6;
  const int wm = w >> 1, wn = w & 1, g = l >> 4, ln = l & 15;
  const int id = blockIdx.x + (blockIdx.y << 6);
  const int nid = ((id & 7) << 6) + (id >> 3);   // XCD-contiguous remap (512 = 8*64)
  const int m0 = (nid & 63) * 128, n0 = (nid >> 6) * 192;
  const int swz = (l & 7) ^ (l >> 3);

  const char* pAbase[4];
#pragma unroll
  for (int j = 0; j < 4; ++j) {
    int r = m0 + (w * 4 + j) * 8 + (l >> 3);
    pAbase[j] = (const char*)xpt + ((size_t)r * 256 + swz * 8) * 2;
  }
  const char* pB0 = (const char*)Wp +
                    ((size_t)(n0 + w * 48 + (l >> 3)) * 2304 + swz * 8) * 2;

  f32x4 acc[4][6] = {};
  int vmask = 0;
  int aoff = 0;

  auto setTap = [&](int tap) {
    int d3 = (tap * 11) >> 5;  // tap/3
    int dy = d3 - 1, dx = tap - d3 * 3 - 1;
    aoff = (dy * 32 + dx) * 512;
    int m = 0;
#pragma unroll
    for (int j = 0; j < 4; ++j) {
      int r = m0 + (w * 4 + j) * 8 + (l >> 3);
      int y = ((r >> 5) & 31) + dy;
      int x = (r & 31) + dx;
      if (((unsigned)y < 32u) && ((unsigned)x < 32u)) m |= (1 << j);
    }
    vmask = m;
  };

  auto STAGE = [&](int buf, int kb) {
#pragma unroll
    for (int j = 0; j < 4; ++j) {
      const char* a = (vmask & (1 << j)) ? (pAbase[j] + aoff) : zp;
      gload_lds16(a, (char*)As + buf * 16384 + (w * 4 + j) * 1024);
    }
#pragma unroll
    for (int j = 0; j < 6; ++j) {
      gload_lds16(pB0 + j * 36864 + kb, (char*)Bs + buf * 24576 + (w * 6 + j) * 1024);
    }
  };

  auto COMPUTE = [&](int buf) {
    const char* Ab2 = (const char*)As + buf * 16384;
    const char* Bb2 = (const char*)Bs + buf * 24576;
    __builtin_amdgcn_s_setprio(1);
#pragma unroll
    for (int kk = 0; kk < 2; ++kk) {
      short8 af[4], bfr[6];
#pragma unroll
      for (int fm = 0; fm < 4; ++fm)
        af[fm] = *(const short8*)(Ab2 + (wm * 64 + fm * 16 + ln) * 128 +
                                  (((kk * 4 + g) ^ (ln & 7)) * 16));
#pragma unroll
      for (int fn = 0; fn < 6; ++fn)
        bfr[fn] = *(const short8*)(Bb2 + (wn * 96 + fn * 16 + ln) * 128 +
                                   (((kk * 4 + g) ^ (ln & 7)) * 16));
#pragma unroll
      for (int fm = 0; fm < 4; ++fm)
#pragma unroll
        for (int fn = 0; fn < 6; ++fn)
          acc[fm][fn] = __builtin_amdgcn_mfma_f32_16x16x32_bf16(af[fm], bfr[fn], acc[fm][fn], 0, 0, 0);
    }
    __builtin_amdgcn_s_setprio(0);
  };

  setTap(0);
  STAGE(0, 0);
  aoff += 128;
  int kb = 128;
  for (int s = 0; s < 36; ++s) {
    const int buf = s & 1;
    if (s < 35) {
      if (((s + 1) & 3) == 0) setTap((s + 1) >> 2);
      STAGE(buf ^ 1, kb);
      kb += 128;
      aoff += 128;
      asm volatile("s_waitcnt vmcnt(10)" ::: "memory");
    } else {
      asm volatile("s_waitcnt vmcnt(0)" ::: "memory");
    }
    __builtin_amdgcn_s_barrier();
    __builtin_amdgcn_sched_barrier(0);
    COMPUTE(buf);
    asm volatile("s_waitcnt lgkmcnt(0)" ::: "memory");
    __builtin_amdgcn_s_barrier();
    __builtin_amdgcn_sched_barrier(0);
  }

#pragma unroll
  for (int fm = 0; fm < 4; ++fm)
#pragma unroll
    for (int fn = 0; fn < 6; ++fn) {
      int col = n0 + wn * 96 + fn * 16 + ln;
      float bb = bias[col];
#pragma unroll
      for (int r = 0; r < 4; ++r) {
        int row = m0 + wm * 64 + fm * 16 + g * 4 + r;
        kqv[(size_t)row * 1536 + col] = f2bf(acc[fm][fn][r] + bb);
      }
    }
}

// ---------------- K5: fused attention v8.1 — tr_read issue hoisted over softmax-total ----------
__global__ __launch_bounds__(512, 4) void k_attn(const unsigned short* __restrict__ kqv,
                                                 unsigned short* __restrict__ part) {
  __shared__ __align__(16) unsigned short Qs[16][512];   // 16KB
  __shared__ __align__(16) char VsRaw[2][32 * 544];      // 34KB
  __shared__ __align__(16) float sums[4][2][64][4];      // 8KB
  const int tid = threadIdx.x, l = tid & 63, w = tid >> 6;
  const int g = l >> 4, ln = l & 15;
  const int nt = w & 1, hg = w >> 1;
  const int id = blockIdx.x;
  const int b = id & 7, ng = (id >> 3) & 31, ch = id >> 8;
  const int n0 = ng * 32 + nt * 16;
  const int m_base = ch * 512;
  const size_t rowBase = (size_t)b * 1024;
  const float SC = 1.0f / 1024.0f;

  short8 ak[2][2];
#pragma unroll
  for (int hl = 0; hl < 2; ++hl)
#pragma unroll
    for (int kk = 0; kk < 2; ++kk)
      ak[hl][kk] = *(const short8*)&kqv[(rowBase + n0 + ln) * 1536 +
                                        (hg * 2 + hl) * 64 + kk * 32 + g * 8];

  f32x4 acc[2][4] = {};

  const int r0 = w * 2, r1 = w * 2 + 1;
  const char* pRow = (const char*)kqv +
                     (size_t)(rowBase + m_base + r0) * 3072 + 1024 + (size_t)l * 16;
  uint4 q0, q1, v0, v1;

  auto LOADREGS = [&]() {
    q0 = *(const uint4*)pRow;
    v0 = *(const uint4*)(pRow + 1024);
    q1 = *(const uint4*)(pRow + 3072);
    v1 = *(const uint4*)(pRow + 4096);
    pRow += 49152;
  };
  char* const dQ0 = (char*)Qs + r0 * 1024 + ((l ^ (r0 & 7)) * 16);
  char* const dQ1 = (char*)Qs + r1 * 1024 + ((l ^ (r1 & 7)) * 16);
  const uint32_t vOff = (uint32_t)(l >> 1) * 544 + (uint32_t)(l & 1) * 16;
  auto DSW = [&](int vbuf) {
    *(uint4*)dQ0 = q0;
    *(uint4*)dQ1 = q1;
    char* vb = VsRaw[vbuf];
    *(uint4*)(vb + vOff + r0 * 32) = v0;
    *(uint4*)(vb + vOff + r1 * 32) = v1;
  };

  LOADREGS();
  asm volatile("s_waitcnt vmcnt(0)" ::: "memory");
  DSW(0);
  asm volatile("s_waitcnt lgkmcnt(0)" ::: "memory");
  __builtin_amdgcn_s_barrier();
  __builtin_amdgcn_sched_barrier(0);

  for (int s = 0; s < 32; ++s) {
    const int buf = s & 1;
    if (s < 31) LOADREGS();

    f32x4 sv[2] = {};
    __builtin_amdgcn_s_setprio(1);
#pragma unroll
    for (int kk = 0; kk < 2; ++kk)
#pragma unroll
      for (int hl = 0; hl < 2; ++hl) {
        int chq = (hg * 2 + hl) * 8 + kk * 4 + g;
        short8 qa = *(const short8*)((const char*)Qs + ln * 1024 +
                                     ((chq ^ (ln & 7)) * 16));
        sv[hl] = __builtin_amdgcn_mfma_f32_16x16x32_bf16(qa, ak[hl][kk], sv[hl], 0, 0, 0);
      }
    __builtin_amdgcn_s_setprio(0);

    f32x4 e0, e1, ps;
#pragma unroll
    for (int j = 0; j < 4; ++j) {
      e0[j] = __expf(sv[0][j] * SC);
      e1[j] = __expf(sv[1][j] * SC);
      ps[j] = e0[j] + e1[j];
    }
    *(f32x4*)&sums[hg][nt][l][0] = ps;
    asm volatile("s_waitcnt lgkmcnt(0)" ::: "memory");
    __builtin_amdgcn_s_barrier();  // B3: sums visible
    __builtin_amdgcn_sched_barrier(0);

    // --- issue tr_reads EARLY (Vs[buf] valid since last B1); latency hides under tot/inv ---
    const uint32_t vsB = (uint32_t)(uintptr_t)VsRaw[buf] + l * 8;
    s16x4 vf[8];
#pragma unroll
    for (int hl = 0; hl < 2; ++hl) {
      uint32_t ah = vsB + (hg * 2 + hl) * 2176;
      asm volatile("ds_read_b64_tr_b16 %0, %1" : "=v"(vf[hl * 4 + 0]) : "v"(ah));
      asm volatile("ds_read_b64_tr_b16 %0, %1 offset:544" : "=v"(vf[hl * 4 + 1]) : "v"(ah));
      asm volatile("ds_read_b64_tr_b16 %0, %1 offset:1088" : "=v"(vf[hl * 4 + 2]) : "v"(ah));
      asm volatile("ds_read_b64_tr_b16 %0, %1 offset:1632" : "=v"(vf[hl * 4 + 3]) : "v"(ah));
    }

    f32x4 tot = ps;
#pragma unroll
    for (int d = 1; d < 4; ++d) {
      f32x4 o = *(const f32x4*)&sums[(hg + d) & 3][nt][l][0];
      tot[0] += o[0]; tot[1] += o[1]; tot[2] += o[2]; tot[3] += o[3];
    }
    f32x4 inv;
#pragma unroll
    for (int j = 0; j < 4; ++j) inv[j] = __builtin_amdgcn_rcpf(tot[j]);

    asm volatile("s_waitcnt lgkmcnt(0)" ::: "memory");
    __builtin_amdgcn_sched_barrier(0);
    union { uint32_t u[2]; s16x4 v4; } pc0, pc1;
    pc0.u[0] = pkbf(e0[0] * inv[0], e0[1] * inv[1]);
    pc0.u[1] = pkbf(e0[2] * inv[2], e0[3] * inv[3]);
    pc1.u[0] = pkbf(e1[0] * inv[0], e1[1] * inv[1]);
    pc1.u[1] = pkbf(e1[2] * inv[2], e1[3] * inv[3]);
    __builtin_amdgcn_s_setprio(1);
#pragma unroll
    for (int cf = 0; cf < 4; ++cf) {
      acc[0][cf] = MFMA16(vf[cf], pc0.v4, acc[0][cf]);
      acc[1][cf] = MFMA16(vf[4 + cf], pc1.v4, acc[1][cf]);
    }
    __builtin_amdgcn_s_setprio(0);

    if (s < 31) {
      asm volatile("s_waitcnt vmcnt(0)" ::: "memory");
      DSW(buf ^ 1);
    }
    asm volatile("s_waitcnt lgkmcnt(0)" ::: "memory");
    __builtin_amdgcn_s_barrier();  // B1
    __builtin_amdgcn_sched_barrier(0);
  }

  const size_t outBase = (size_t)ch * 8192 * 512 + (rowBase + n0 + ln) * 512;
#pragma unroll
  for (int hl = 0; hl < 2; ++hl)
#pragma unroll
    for (int cf = 0; cf < 4; ++cf)
#pragma unroll
      for (int r2 = 0; r2 < 2; ++r2) {
        int c = (hg * 2 + hl) * 64 + cf * 16 + g * 4 + r2 * 2;
        uint32_t u = (uint32_t)f2bf(acc[hl][cf][2 * r2]) |
                     ((uint32_t)f2bf(acc[hl][cf][2 * r2 + 1]) << 16);
        *(uint32_t*)&part[outBase + c] = u;
      }
}

// ---------------- K6: fused tail — attproj+LN1+FFN1+FFN2+LN2+transposed output ----------------
// 32 rows/block, 256 blocks. addn (LN1 output) lives in registers; h1 only in LDS;
// Tt (f32 output staging) aliases the Bs staging buffer after its last read.
__global__ __launch_bounds__(256) void k_tail(const unsigned short* __restrict__ part,
                                              const unsigned short* __restrict__ Wp,
                                              const float* __restrict__ bproj,
                                              const float* __restrict__ resid,
                                              const float* __restrict__ lg,
                                              const float* __restrict__ lb,
                                              const unsigned short* __restrict__ W1b,
                                              const float* __restrict__ b1,
                                              const unsigned short* __restrict__ W2b,
                                              const float* __restrict__ b2,
                                              float* __restrict__ out) {
  __shared__ __align__(16) unsigned short As[32 * 64];        // 4KB  (phase-1 A staging)
  __shared__ __align__(16) char BsTt[33792];                  // 33KB (Bs staging / Tt union)
  __shared__ __align__(16) unsigned short As2[32 * 256];      // 16KB (LN1 rows, chunk-swz)
  __shared__ __align__(16) unsigned short H1s[32 * 256];      // 16KB (h1 rows, chunk-swz)
  __shared__ float rsum[4][32][2];
  unsigned short* const Bs = (unsigned short*)BsTt;
  float(* const Tt)[33] = (float(*)[33])BsTt;
  const int tid = threadIdx.x, l = tid & 63, w = tid >> 6;
  const int g4 = l >> 4, ln = l & 15;
  const int m0 = blockIdx.x * 32;
  const int swz = (l & 7) ^ (l >> 3);

  // ---- phase 1: attproj GEMM (K=1024 over split partials) ----
  f32x4 acc[2][4] = {};
  for (int kt = 0; kt < 1024; kt += 64) {
    gload_lds16((const char*)part + (((size_t)(kt >> 9) * 8192 * 512) +
                                     (size_t)(m0 + w * 8 + (l >> 3)) * 512 +
                                     (kt & 511) + swz * 8) * 2,
                (char*)As + w * 1024);
#pragma unroll
    for (int j = 0; j < 8; ++j) {
      int seg = w * 8 + j;
      gload_lds16((const char*)Wp + ((size_t)(seg * 8 + (l >> 3)) * 1024 + kt + swz * 8) * 2,
                  (char*)Bs + seg * 1024);
    }
    __syncthreads();
#pragma unroll
    for (int kk = 0; kk < 2; ++kk) {
      short8 af[2], bfr[4];
#pragma unroll
      for (int fm = 0; fm < 2; ++fm)
        af[fm] = *(const short8*)((const char*)As + (fm * 16 + ln) * 128 +
                                  (((kk * 4 + g4) ^ (ln & 7)) * 16));
#pragma unroll
      for (int fn = 0; fn < 4; ++fn)
        bfr[fn] = *(const short8*)((const char*)Bs + (w * 64 + fn * 16 + ln) * 128 +
                                   (((kk * 4 + g4) ^ (ln & 7)) * 16));
#pragma unroll
      for (int fm = 0; fm < 2; ++fm)
#pragma unroll
        for (int fn = 0; fn < 4; ++fn)
          acc[fm][fn] = __builtin_amdgcn_mfma_f32_16x16x32_bf16(af[fm], bfr[fn], acc[fm][fn], 0, 0, 0);
    }
    __syncthreads();
  }

  // ---- LN1 stats (bias + resid) ----
  float vals[2][4][4];
#pragma unroll
  for (int fm = 0; fm < 2; ++fm)
#pragma unroll
    for (int r = 0; r < 4; ++r) {
      int row_l = fm * 16 + g4 * 4 + r;
      float s = 0.f, q = 0.f;
#pragma unroll
      for (int fn = 0; fn < 4; ++fn) {
        int col = w * 64 + fn * 16 + ln;
        float v = acc[fm][fn][r] + bproj[col] + resid[(size_t)(m0 + row_l) * 256 + col];
        vals[fm][fn][r] = v;
        s += v;
        q += v * v;
      }
#pragma unroll
      for (int o = 1; o < 16; o <<= 1) {
        s += __shfl_xor(s, o, 64);
        q += __shfl_xor(q, o, 64);
      }
      if (ln == 0) {
        rsum[w][row_l][0] = s;
        rsum[w][row_l][1] = q;
      }
    }
  __syncthreads();

  // ---- LN1: vals := addn (kept in regs) + As2 bf16 (chunk-swizzled) ----
#pragma unroll
  for (int fm = 0; fm < 2; ++fm)
#pragma unroll
    for (int r = 0; r < 4; ++r) {
      int row_l = fm * 16 + g4 * 4 + r;
      float s = rsum[0][row_l][0] + rsum[1][row_l][0] + rsum[2][row_l][0] + rsum[3][row_l][0];
      float q = rsum[0][row_l][1] + rsum[1][row_l][1] + rsum[2][row_l][1] + rsum[3][row_l][1];
      float mu = s * (1.0f / 256.0f);
      float rstd = rsqrtf(q * (1.0f / 256.0f) - mu * mu + 1e-5f);
#pragma unroll
      for (int fn = 0; fn < 4; ++fn) {
        int col = w * 64 + fn * 16 + ln;
        float o = (vals[fm][fn][r] - mu) * rstd * lg[col] + lb[col];
        vals[fm][fn][r] = o;  // addn, reused as FFN2 residual
        int slot = (col >> 3) ^ (row_l & 7);
        *(unsigned short*)((char*)As2 + row_l * 512 + slot * 16 + (col & 7) * 2) = f2bf(o);
      }
    }
  __syncthreads();

  // ---- phase 2: FFN1 h1 = leaky(As2 @ W1^T + b1) -> H1s (chunk-swizzled) ----
  f32x4 acc2[2][4] = {};
  for (int kt = 0; kt < 256; kt += 64) {
#pragma unroll
    for (int j = 0; j < 8; ++j) {
      int seg = w * 8 + j;
      gload_lds16((const char*)W1b + ((size_t)(seg * 8 + (l >> 3)) * 256 + kt + swz * 8) * 2,
                  (char*)Bs + seg * 1024);
    }
    __syncthreads();
#pragma unroll
    for (int kk = 0; kk < 2; ++kk) {
      short8 af[2], bfr[4];
#pragma unroll
      for (int fm = 0; fm < 2; ++fm) {
        int row = fm * 16 + ln;
        int chunk = (kt >> 3) + kk * 4 + g4;
        af[fm] = *(const short8*)((const char*)As2 + row * 512 + ((chunk ^ (row & 7)) * 16));
      }
#pragma unroll
      for (int fn = 0; fn < 4; ++fn)
        bfr[fn] = *(const short8*)((const char*)Bs + (w * 64 + fn * 16 + ln) * 128 +
                                   (((kk * 4 + g4) ^ (ln & 7)) * 16));
#pragma unroll
      for (int fm = 0; fm < 2; ++fm)
#pragma unroll
        for (int fn = 0; fn < 4; ++fn)
          acc2[fm][fn] = __builtin_amdgcn_mfma_f32_16x16x32_bf16(af[fm], bfr[fn], acc2[fm][fn], 0, 0, 0);
    }
    __syncthreads();
  }
#pragma unroll
  for (int fm = 0; fm < 2; ++fm)
#pragma unroll
    for (int fn = 0; fn < 4; ++fn)
#pragma unroll
      for (int r = 0; r < 4; ++r) {
        int row_l = fm * 16 + g4 * 4 + r;
        int col = w * 64 + fn * 16 + ln;
        float v = acc2[fm][fn][r] + b1[col];
        v = (v > 0.f) ? v : 0.1f * v;
        int slot = (col >> 3) ^ (row_l & 7);
        *(unsigned short*)((char*)H1s + row_l * 512 + slot * 16 + (col & 7) * 2) = f2bf(v);
      }
  __syncthreads();

  // ---- phase 3: FFN2 h2 = H1s @ W2^T + b2 + addn(regs); LN2 -> Tt -> transposed out ----
  f32x4 acc3[2][4] = {};
  for (int kt = 0; kt < 256; kt += 64) {
#pragma unroll
    for (int j = 0; j < 8; ++j) {
      int seg = w * 8 + j;
      gload_lds16((const char*)W2b + ((size_t)(seg * 8 + (l >> 3)) * 256 + kt + swz * 8) * 2,
                  (char*)Bs + seg * 1024);
    }
    __syncthreads();
#pragma unroll
    for (int kk = 0; kk < 2; ++kk) {
      short8 af[2], bfr[4];
#pragma unroll
      for (int fm = 0; fm < 2; ++fm) {
        int row = fm * 16 + ln;
        int chunk = (kt >> 3) + kk * 4 + g4;
        af[fm] = *(const short8*)((const char*)H1s + row * 512 + ((chunk ^ (row & 7)) * 16));
      }
#pragma unroll
      for (int fn = 0; fn < 4; ++fn)
        bfr[fn] = *(const short8*)((const char*)Bs + (w * 64 + fn * 16 + ln) * 128 +
                                   (((kk * 4 + g4) ^ (ln & 7)) * 16));
#pragma unroll
      for (int fm = 0; fm < 2; ++fm)
#pragma unroll
        for (int fn = 0; fn < 4; ++fn)
          acc3[fm][fn] = __builtin_amdgcn_mfma_f32_16x16x32_bf16(af[fm], bfr[fn], acc3[fm][fn], 0, 0, 0);
    }
    __syncthreads();
  }

  // h2 = acc3 + b2 + addn; LN2 stats
#pragma unroll
  for (int fm = 0; fm < 2; ++fm)
#pragma unroll
    for (int r = 0; r < 4; ++r) {
      int row_l = fm * 16 + g4 * 4 + r;
      float s = 0.f, q = 0.f;
#pragma unroll
      for (int fn = 0; fn < 4; ++fn) {
        int col = w * 64 + fn * 16 + ln;
        float v = acc3[fm][fn][r] + b2[col] + vals[fm][fn][r];
        vals[fm][fn][r] = v;
        s += v;
        q += v * v;
      }
#pragma unroll
      for (int o = 1; o < 16; o <<= 1) {
        s += __shfl_xor(s, o, 64);
        q += __shfl_xor(q, o, 64);
      }
      if (ln == 0) {
        rsum[w][row_l][0] = s;
        rsum[w][row_l][1] = q;
      }
    }
  __syncthreads();  // also drains last Bs reads before Tt overwrites the union

#pragma unroll
  for (int fm = 0; fm < 2; ++fm)
#pragma unroll
    for (int r = 0; r < 4; ++r) {
      int row_l = fm * 16 + g4 * 4 + r;
      float s = rsum[0][row_l][0] + rsum[1][row_l][0] + rsum[2][row_l][0] + rsum[3][row_l][0];
      float q = rsum[0][row_l][1] + rsum[1][row_l][1] + rsum[2][row_l][1] + rsum[3][row_l][1];
      float mu = s * (1.0f / 256.0f);
      float rstd = rsqrtf(q * (1.0f / 256.0f) - mu * mu + 1e-5f);
#pragma unroll
      for (int fn = 0; fn < 4; ++fn) {
        int col = w * 64 + fn * 16 + ln;
        Tt[col][row_l] = (vals[fm][fn][r] - mu) * rstd * lg[col] + lb[col];
      }
    }
  __syncthreads();

  const int bimg = m0 >> 10, nn0 = m0 & 1023;
#pragma unroll
  for (int i = 0; i < 8; ++i) {
    int c = i * 32 + (tid >> 3);
    int ng = (tid & 7) * 4;
    float4 o = make_float4(Tt[c][ng], Tt[c][ng + 1], Tt[c][ng + 2], Tt[c][ng + 3]);
    *(float4*)&out[((size_t)bimg * 256 + c) * 1024 + nn0 + ng] = o;
  }
}

// ---------------- host launcher ----------------
extern "C" void kernel_launch(void* const* d_in, const int* in_sizes, int n_in,
                              void* d_out, int out_size, void* d_ws, size_t ws_size,
                              hipStream_t stream) {
  const float* x     = (const float*)d_in[0];
  const float* Wk    = (const float*)d_in[1];
  const float* bk    = (const float*)d_in[2];
  const float* Wq    = (const float*)d_in[3];
  const float* bq    = (const float*)d_in[4];
  const float* Wv    = (const float*)d_in[5];
  const float* bv    = (const float*)d_in[6];
  const float* Wproj = (const float*)d_in[7];
  const float* bproj = (const float*)d_in[8];
  const float* ln_g  = (const float*)d_in[9];
  const float* ln_b  = (const float*)d_in[10];
  const float* W1    = (const float*)d_in[11];
  const float* b1    = (const float*)d_in[12];
  const float* W2    = (const float*)d_in[13];
  const float* b2    = (const float*)d_in[14];

  char* ws = (char*)d_ws;
  constexpr size_t OFF_XPTB  = 0;                                    // bf16 [8192][256]
  constexpr size_t OFF_XPTF  = OFF_XPTB  + (size_t)8192 * 256 * 2;   // f32  [8192][256]
  constexpr size_t OFF_WPACK = OFF_XPTF  + (size_t)8192 * 256 * 4;   // bf16 [1536][2304]
  constexpr size_t OFF_BIAS  = OFF_WPACK + (size_t)1536 * 2304 * 2;  // f32  [1536]
  constexpr size_t OFF_WPROJ = OFF_BIAS  + (size_t)1536 * 4;         // bf16 [256][1024] (dup K)
  constexpr size_t OFF_W1B   = OFF_WPROJ + (size_t)256 * 1024 * 2;   // bf16 [256][256]
  constexpr size_t OFF_W2B   = OFF_W1B   + (size_t)256 * 256 * 2;    // bf16 [256][256]
  constexpr size_t OFF_PET   = OFF_W2B   + (size_t)256 * 256 * 2;    // f32  [256][32]
  constexpr size_t OFF_ZERO  = OFF_PET   + (size_t)256 * 32 * 4;     // f32  [256] zeros (1KB)
  constexpr size_t OFF_KQV   = OFF_ZERO  + 1024;                     // bf16 [8192][1536]
  constexpr size_t OFF_PART  = OFF_KQV   + (size_t)8192 * 1536 * 2;  // bf16 [2][8192][512]

  (void)in_sizes; (void)n_in; (void)out_size; (void)ws_size;

  const char* zp = (const char*)(ws + OFF_ZERO);

  k_prep<<<14337, 256, 0, stream>>>(Wk, Wq, Wv, bk, bq, bv, Wproj, W1, W2,
                                    (unsigned short*)(ws + OFF_WPACK),
                                    (float*)(ws + OFF_BIAS),
                                    (unsigned short*)(ws + OFF_WPROJ),
                                    (unsigned short*)(ws + OFF_W1B),
                                    (unsigned short*)(ws + OFF_W2B),
                                    (float*)(ws + OFF_PET), (float*)(ws + OFF_ZERO));
  k_xpt<<<dim3(8, 32, 8), 256, 0, stream>>>(x, (const float*)(ws + OFF_PET),
                                            (unsigned short*)(ws + OFF_XPTB),
                                            (float*)(ws + OFF_XPTF));
  // merged conv K+Q+V -> kqv[8192][1536]
  k_gemm_conv<<<dim3(64, 8), 256, 0, stream>>>(
      (const unsigned short*)(ws + OFF_XPTB), (const unsigned short*)(ws + OFF_WPACK),
      (unsigned short*)(ws + OFF_KQV), (const float*)(ws + OFF_BIAS), zp);
  // fused attention -> partials [2][8192][512]
  k_attn<<<dim3(512), 512, 0, stream>>>((const unsigned short*)(ws + OFF_KQV),
                                        (unsigned short*)(ws + OFF_PART));
  // fused tail: attproj + LN1 + FFN1 + FFN2 + LN2 + transposed output
  k_tail<<<256, 256, 0, stream>>>((const unsigned short*)(ws + OFF_PART),
                                  (const unsigned short*)(ws + OFF_WPROJ), bproj,
                                  (const float*)(ws + OFF_XPTF), ln_g, ln_b,
                                  (const unsigned short*)(ws + OFF_W1B), b1,
                                  (const unsigned short*)(ws + OFF_W2B), b2,
                                  (float*)d_out);
}